// Round 6
// baseline (1282.134 us; speedup 1.0000x reference)
//
#include <hip/hip_runtime.h>
#include <hip/hip_bf16.h>

// DHHT round 13: zero-LDS, zero-barrier projection GEMMs.
//  - proj_phi/proj_mfma/xm: both MFMA operands read DIRECTLY from global into
//    fragments (A: 2x f32x4 + in-reg cvt to bf16x8; B: one aligned 16B load
//    from the [col][288] bf16 weight layout). No LDS staging, no barriers in
//    the K-loop -> waves schedule independently, 1-step reg prefetch + 12
//    waves/CU hide L2 latency. Epilogues (phi reduce, transpose store)
//    unchanged, barriers only there.
//  - ktv/final/prologue unchanged from round 12.
// W2T bf16 [256][4096]: cols 0..2047 = W2u (ktv@F^T). G lives in G32 (f32).

#define EPSF 1e-6f

typedef __attribute__((ext_vector_type(8))) short bf16x8;
typedef __attribute__((ext_vector_type(8))) unsigned short u16x8;
typedef __attribute__((ext_vector_type(4))) float f32x4;
typedef float f32x4a __attribute__((ext_vector_type(4), aligned(4)));

__device__ __forceinline__ float b2f(unsigned short u) {
    union { unsigned int i; float f; } c;
    c.i = ((unsigned int)u) << 16;
    return c.f;
}
__device__ __forceinline__ unsigned short f2b(float f) {
    __hip_bfloat16 h = __float2bfloat16(f);
    union { __hip_bfloat16 h; unsigned short u; } c;
    c.h = h;
    return c.u;
}
__device__ __forceinline__ bf16x8 cvt8(f32x4a a, f32x4a b) {
    u16x8 r;
    r[0] = f2b(a[0]); r[1] = f2b(a[1]); r[2] = f2b(a[2]); r[3] = f2b(a[3]);
    r[4] = f2b(b[0]); r[5] = f2b(b[1]); r[6] = f2b(b[2]); r[7] = f2b(b[3]);
    union { u16x8 u; bf16x8 s; } c; c.u = r;
    return c.s;
}

__global__ void zero_kernel(float* __restrict__ p, int n) {
    int i = blockIdx.x * 256 + threadIdx.x;
    if (i < n) p[i] = 0.f;
}

// ---------------- weight convert: Wbf [6144][288] bf16 + biasAll[6144] ----------------
__global__ __launch_bounds__(256) void wconv_kernel(
    const float* __restrict__ Wq, const float* __restrict__ Wk, const float* __restrict__ Wv,
    const float* __restrict__ Bq, const float* __restrict__ Bk, const float* __restrict__ Bv,
    unsigned short* __restrict__ Wbf, float* __restrict__ biasAll)
{
    const int t = threadIdx.x;
    const int b = blockIdx.x;
    if (b < 6144) {
        const int mat = b >> 11, lr = b & 2047;
        const float* Ws = (mat == 0 ? Wq : mat == 1 ? Wk : Wv) + (size_t)lr * 257;
        Wbf[(size_t)b * 288 + t] = f2b(Ws[t]);
        if (t < 32) {
            float v = (t == 0) ? Ws[256] : 0.f;
            Wbf[(size_t)b * 288 + 256 + t] = f2b(v);
        }
    } else {
        const int e = (b - 6144) * 256 + t;
        const int mat = e >> 11, r = e & 2047;
        biasAll[e] = (mat == 0 ? Bq : mat == 1 ? Bk : Bv)[r];
    }
}

// ---------------- G32[o][hk] = sum_dd vmw[dd][i] fw[o][h*256+dd] (f32) ----------------
__global__ __launch_bounds__(256) void w2g_kernel(
    const float* __restrict__ vmw,
    const float* __restrict__ fw,
    float* __restrict__ G32)
{
    const int t = threadIdx.x;
    const int h = blockIdx.x >> 3;
    const int i0 = (blockIdx.x & 7) * 32;

    __shared__ __align__(16) float xlds[16][40];
    __shared__ float wlds[256][17];

    float acc[32];
#pragma unroll
    for (int r = 0; r < 32; ++r) acc[r] = 0.f;

    const int ar = t >> 3;
    const int ak = (t & 7) * 2;
    const int wk = t & 15;
    const int wo = (t >> 4) * 16;

    for (int d0 = 0; d0 < 256; d0 += 16) {
        xlds[ak][ar]     = vmw[(size_t)(d0 + ak) * 256 + i0 + ar];
        xlds[ak + 1][ar] = vmw[(size_t)(d0 + ak + 1) * 256 + i0 + ar];
#pragma unroll
        for (int j = 0; j < 16; ++j)
            wlds[wo + j][wk] = fw[(size_t)(wo + j) * 2048 + h * 256 + d0 + wk];
        __syncthreads();
#pragma unroll
        for (int kk = 0; kk < 16; ++kk) {
            float bv = wlds[t][kk];
            const float4* xr = (const float4*)(&xlds[kk][0]);
#pragma unroll
            for (int g = 0; g < 8; ++g) {
                float4 xv = xr[g];
                acc[g * 4 + 0] = fmaf(xv.x, bv, acc[g * 4 + 0]);
                acc[g * 4 + 1] = fmaf(xv.y, bv, acc[g * 4 + 1]);
                acc[g * 4 + 2] = fmaf(xv.z, bv, acc[g * 4 + 2]);
                acc[g * 4 + 3] = fmaf(xv.w, bv, acc[g * 4 + 3]);
            }
        }
        __syncthreads();
    }
#pragma unroll
    for (int r = 0; r < 32; ++r)
        G32[(size_t)t * 2048 + h * 256 + i0 + r] = acc[r];
}

// ---------------- bias2[o] = fb[o] + sum_j vmb[j&255]*fw[o][j] + sum_k Bv[k]*G32[o][k] ----------------
__global__ __launch_bounds__(256) void bias2_kernel(
    const float* __restrict__ vmb, const float* __restrict__ fw,
    const float* __restrict__ fb, const float* __restrict__ Bv,
    const float* __restrict__ G32, float* __restrict__ bias2)
{
    const int o = blockIdx.x;
    const int t = threadIdx.x;
    float s = 0.f, sb = 0.f;
#pragma unroll
    for (int i = 0; i < 8; ++i) {
        const int j = t + i * 256;
        s += fw[(size_t)o * 2048 + j];
        sb += Bv[j] * G32[(size_t)o * 2048 + j];
    }
    s = s * vmb[t] + sb;
#pragma unroll
    for (int off = 32; off > 0; off >>= 1) s += __shfl_down(s, off, 64);
    __shared__ float r4[4];
    if ((t & 63) == 0) r4[t >> 6] = s;
    __syncthreads();
    if (t == 0) bias2[o] = fb[o] + r4[0] + r4[1] + r4[2] + r4[3];
}

// ---------------- Mf32[o][i] += sum_k G32[o][k] Wv[k][i] (split-K, atomic) ----------------
__global__ __launch_bounds__(256) void gm_kernel(
    const float* __restrict__ Wv, const float* __restrict__ G32,
    float* __restrict__ Mf32)
{
    __shared__ float Gt[64][33];
    __shared__ float Wt[32][33];
    const int t = threadIdx.x;
    const int o0 = blockIdx.x * 64, i0 = blockIdx.y * 32, k0 = blockIdx.z * 256;
    const int ii = t & 31, og = t >> 5;
    float acc[8] = {};
    for (int kk0 = k0; kk0 < k0 + 256; kk0 += 32) {
#pragma unroll
        for (int r = 0; r < 8; ++r) {
            const int e = t + r * 256;
            Gt[e >> 5][e & 31] = G32[(size_t)(o0 + (e >> 5)) * 2048 + kk0 + (e & 31)];
        }
#pragma unroll
        for (int r = 0; r < 4; ++r) {
            const int e = t + r * 256;
            const int kk = e >> 5, i = i0 + (e & 31);
            Wt[kk][e & 31] = (i < 257) ? Wv[(size_t)(kk0 + kk) * 257 + i] : 0.f;
        }
        __syncthreads();
#pragma unroll
        for (int kk = 0; kk < 32; ++kk) {
            float wv_ = Wt[kk][ii];
#pragma unroll
            for (int r = 0; r < 8; ++r)
                acc[r] = fmaf(Gt[og * 8 + r][kk], wv_, acc[r]);
        }
        __syncthreads();
    }
#pragma unroll
    for (int r = 0; r < 8; ++r)
        atomicAdd(&Mf32[(size_t)(o0 + og * 8 + r) * 288 + i0 + ii], acc[r]);
}

__global__ void gmcvt_kernel(const float* __restrict__ Mf32, unsigned short* __restrict__ Mbf) {
    const int i = blockIdx.x * 256 + threadIdx.x;
    Mbf[i] = f2b(Mf32[i]);
}

// ================= zero-LDS GEMM core macro-pattern =================
// 64 rows (m0), 256 cols (cbase + wn + j*16 + l15), K=256 in 8 steps.
// A: X f32 direct fragment loads + in-reg cvt. B: bf16 [col][288] direct.

// ---------------- projection (V): writes vsT only; direct-fragment GEMM ----------------
__global__ __launch_bounds__(256) void proj_mfma(
    const float* __restrict__ X,
    const unsigned short* __restrict__ Wbase,
    const float* __restrict__ biasBase,
    unsigned short* __restrict__ outT,    // transposed [2048][CH]
    int CH)
{
    __shared__ __align__(16) unsigned short smem[16384]; // [256 col][64 n] swizzled
    __shared__ float rowx[64];
    const int t = threadIdx.x;
    const int m0 = blockIdx.x * 64;
    const int c0 = blockIdx.y * 256;
    const int lane = t & 63, w = t >> 6;
    const int wn = w * 64;
    const int l15 = lane & 15, q = lane >> 4;

    const float* xp = X + (size_t)(m0 + l15) * 257 + q * 8;
    const unsigned short* wp = Wbase + (size_t)(c0 + wn + l15) * 288 + q * 8;

    f32x4 acc[4][4] = {};
    bf16x8 af[4], bw[4];
    f32x4a xr[4][2];
    bf16x8 wr[4];

#pragma unroll
    for (int i = 0; i < 4; ++i) {
        xr[i][0] = *(const f32x4a*)(xp + (size_t)i * 16 * 257);
        xr[i][1] = *(const f32x4a*)(xp + (size_t)i * 16 * 257 + 4);
    }
#pragma unroll
    for (int j = 0; j < 4; ++j)
        wr[j] = *(const bf16x8*)(wp + (size_t)j * 16 * 288);
#pragma unroll
    for (int i = 0; i < 4; ++i) af[i] = cvt8(xr[i][0], xr[i][1]);
#pragma unroll
    for (int j = 0; j < 4; ++j) bw[j] = wr[j];

    for (int ks = 0; ks < 8; ++ks) {
        if (ks < 7) {
            const int k1 = (ks + 1) * 32;
#pragma unroll
            for (int i = 0; i < 4; ++i) {
                xr[i][0] = *(const f32x4a*)(xp + (size_t)i * 16 * 257 + k1);
                xr[i][1] = *(const f32x4a*)(xp + (size_t)i * 16 * 257 + k1 + 4);
            }
#pragma unroll
            for (int j = 0; j < 4; ++j)
                wr[j] = *(const bf16x8*)(wp + (size_t)j * 16 * 288 + k1);
        }
#pragma unroll
        for (int i = 0; i < 4; ++i)
#pragma unroll
            for (int j = 0; j < 4; ++j)
                acc[i][j] = __builtin_amdgcn_mfma_f32_16x16x32_bf16(af[i], bw[j], acc[i][j], 0, 0, 0);
        if (ks < 7) {
#pragma unroll
            for (int i = 0; i < 4; ++i) af[i] = cvt8(xr[i][0], xr[i][1]);
#pragma unroll
            for (int j = 0; j < 4; ++j) bw[j] = wr[j];
        }
    }

    if (t < 64) rowx[t] = b2f(f2b(X[(size_t)(m0 + t) * 257 + 256]));
    __syncthreads();

    // rank-1 Lorentz column + bias
#pragma unroll
    for (int j = 0; j < 4; ++j) {
        const int cg = c0 + wn + j * 16 + l15;
        const float w256 = b2f(Wbase[(size_t)cg * 288 + 256]);
        const float bias = biasBase[cg];
#pragma unroll
        for (int i = 0; i < 4; ++i)
#pragma unroll
            for (int r = 0; r < 4; ++r)
                acc[i][j][r] += rowx[i * 16 + q * 4 + r] * w256 + bias;
    }

    // transposed store via swizzled LDS [256 col][64 n]
#pragma unroll
    for (int i = 0; i < 4; ++i)
#pragma unroll
        for (int j = 0; j < 4; ++j) {
            const int cl = wn + j * 16 + l15;
#pragma unroll
            for (int r2 = 0; r2 < 4; r2 += 2) {
                const int nl = i * 16 + q * 4 + r2;
                const unsigned int pk =
                    (unsigned int)f2b(acc[i][j][r2]) |
                    ((unsigned int)f2b(acc[i][j][r2 + 1]) << 16);
                *(unsigned int*)(&smem[cl * 64 + (((nl >> 3) ^ (cl & 7)) << 3) + (nl & 7)]) = pk;
            }
        }
    __syncthreads();
#pragma unroll
    for (int k = 0; k < 8; ++k) {
        const int task = k * 256 + t;
        const int cl = task >> 3, nq = task & 7;
        *(u16x8*)(outT + (size_t)(c0 + cl) * CH + m0 + nq * 8) =
            *(const u16x8*)(&smem[cl * 64 + ((nq ^ (cl & 7)) << 3)]);
    }
}

// ---------------- xm: out[n][1+o] = sum_i Xs[n][i] M[o][i] (f32 out, direct-fragment) ----------------
__global__ __launch_bounds__(256) void xm_mfma(
    const float* __restrict__ X,
    const unsigned short* __restrict__ Mbf,
    float* __restrict__ outp)
{
    __shared__ float rowx[64];
    const int t = threadIdx.x;
    const int m0 = blockIdx.x * 64;
    const int lane = t & 63, w = t >> 6;
    const int wn = w * 64;
    const int l15 = lane & 15, q = lane >> 4;

    const float* xp = X + (size_t)(m0 + l15) * 257 + q * 8;
    const unsigned short* wp = Mbf + (size_t)(wn + l15) * 288 + q * 8;

    f32x4 acc[4][4] = {};
    bf16x8 af[4], bw[4];
    f32x4a xr[4][2];
    bf16x8 wr[4];

#pragma unroll
    for (int i = 0; i < 4; ++i) {
        xr[i][0] = *(const f32x4a*)(xp + (size_t)i * 16 * 257);
        xr[i][1] = *(const f32x4a*)(xp + (size_t)i * 16 * 257 + 4);
    }
#pragma unroll
    for (int j = 0; j < 4; ++j)
        wr[j] = *(const bf16x8*)(wp + (size_t)j * 16 * 288);
#pragma unroll
    for (int i = 0; i < 4; ++i) af[i] = cvt8(xr[i][0], xr[i][1]);
#pragma unroll
    for (int j = 0; j < 4; ++j) bw[j] = wr[j];

    for (int ks = 0; ks < 8; ++ks) {
        if (ks < 7) {
            const int k1 = (ks + 1) * 32;
#pragma unroll
            for (int i = 0; i < 4; ++i) {
                xr[i][0] = *(const f32x4a*)(xp + (size_t)i * 16 * 257 + k1);
                xr[i][1] = *(const f32x4a*)(xp + (size_t)i * 16 * 257 + k1 + 4);
            }
#pragma unroll
            for (int j = 0; j < 4; ++j)
                wr[j] = *(const bf16x8*)(wp + (size_t)j * 16 * 288 + k1);
        }
#pragma unroll
        for (int i = 0; i < 4; ++i)
#pragma unroll
            for (int j = 0; j < 4; ++j)
                acc[i][j] = __builtin_amdgcn_mfma_f32_16x16x32_bf16(af[i], bw[j], acc[i][j], 0, 0, 0);
        if (ks < 7) {
#pragma unroll
            for (int i = 0; i < 4; ++i) af[i] = cvt8(xr[i][0], xr[i][1]);
#pragma unroll
            for (int j = 0; j < 4; ++j) bw[j] = wr[j];
        }
    }

    if (t < 64) rowx[t] = b2f(f2b(X[(size_t)(m0 + t) * 257 + 256]));
    __syncthreads();

#pragma unroll
    for (int j = 0; j < 4; ++j) {
        const int cg = wn + j * 16 + l15;
        const float w256 = b2f(Mbf[(size_t)cg * 288 + 256]);
#pragma unroll
        for (int i = 0; i < 4; ++i)
#pragma unroll
            for (int r = 0; r < 4; ++r) {
                const int n = m0 + i * 16 + q * 4 + r;
                outp[(size_t)n * 257 + 1 + cg] =
                    acc[i][j][r] + rowx[i * 16 + q * 4 + r] * w256;
            }
    }
}

// ---------------- projection + fused phi (direct-fragment GEMM, barrier-free K-loop) ----------------
// mode 0 (K): write phi TRANSPOSED to [2048][CH] + colsum replica atomics.
// mode 1 (Q): write phi * invden row-major [CH][2048].
__global__ __launch_bounds__(256) void proj_phi(
    const float* __restrict__ X,
    const unsigned short* __restrict__ Wbase,
    const float* __restrict__ biasBase,
    unsigned short* __restrict__ outbuf,
    const float* __restrict__ nsc,
    const float* __restrict__ colsum_in,
    float* __restrict__ colsum_rep,
    int mode, int CH)
{
    __shared__ __align__(16) unsigned short smem[16384];
    __shared__ float reds2[4][64];
    __shared__ float reds4[4][64];
    __shared__ float rowv[64];
    __shared__ float rowx[64];

    const int t = threadIdx.x;
    const int m0 = blockIdx.x * 64;
    const int h  = blockIdx.y;
    const int lane = t & 63, w = t >> 6;
    const int wn = w * 64;
    const int l15 = lane & 15, q = lane >> 4;

    const float* xp = X + (size_t)(m0 + l15) * 257 + q * 8;
    const unsigned short* wp = Wbase + (size_t)(h * 256 + wn + l15) * 288 + q * 8;

    f32x4 acc[4][4] = {};
    bf16x8 af[4], bw[4];
    f32x4a xr[4][2];
    bf16x8 wr[4];

#pragma unroll
    for (int i = 0; i < 4; ++i) {
        xr[i][0] = *(const f32x4a*)(xp + (size_t)i * 16 * 257);
        xr[i][1] = *(const f32x4a*)(xp + (size_t)i * 16 * 257 + 4);
    }
#pragma unroll
    for (int j = 0; j < 4; ++j)
        wr[j] = *(const bf16x8*)(wp + (size_t)j * 16 * 288);
#pragma unroll
    for (int i = 0; i < 4; ++i) af[i] = cvt8(xr[i][0], xr[i][1]);
#pragma unroll
    for (int j = 0; j < 4; ++j) bw[j] = wr[j];

    for (int ks = 0; ks < 8; ++ks) {
        if (ks < 7) {
            const int k1 = (ks + 1) * 32;
#pragma unroll
            for (int i = 0; i < 4; ++i) {
                xr[i][0] = *(const f32x4a*)(xp + (size_t)i * 16 * 257 + k1);
                xr[i][1] = *(const f32x4a*)(xp + (size_t)i * 16 * 257 + k1 + 4);
            }
#pragma unroll
            for (int j = 0; j < 4; ++j)
                wr[j] = *(const bf16x8*)(wp + (size_t)j * 16 * 288 + k1);
        }
#pragma unroll
        for (int i = 0; i < 4; ++i)
#pragma unroll
            for (int j = 0; j < 4; ++j)
                acc[i][j] = __builtin_amdgcn_mfma_f32_16x16x32_bf16(af[i], bw[j], acc[i][j], 0, 0, 0);
        if (ks < 7) {
#pragma unroll
            for (int i = 0; i < 4; ++i) af[i] = cvt8(xr[i][0], xr[i][1]);
#pragma unroll
            for (int j = 0; j < 4; ++j) bw[j] = wr[j];
        }
    }

    if (t < 64) rowx[t] = b2f(f2b(X[(size_t)(m0 + t) * 257 + 256]));
    __syncthreads();

    // rank-1 Lorentz column
    {
        float w256[4];
#pragma unroll
        for (int j = 0; j < 4; ++j)
            w256[j] = b2f(Wbase[(size_t)(h * 256 + wn + j * 16 + l15) * 288 + 256]);
#pragma unroll
        for (int i = 0; i < 4; ++i)
#pragma unroll
            for (int r = 0; r < 4; ++r) {
                const float xv = rowx[i * 16 + q * 4 + r];
#pragma unroll
                for (int j = 0; j < 4; ++j)
                    acc[i][j][r] += xv * w256[j];
            }
    }

    // ---- fused phi epilogue ----
    const float c = fabsf(nsc[0]) + EPSF;
    float bias[4];
#pragma unroll
    for (int j = 0; j < 4; ++j) bias[j] = biasBase[h * 256 + wn + j * 16 + l15];

    float a2[4][4], a4[4][4];
#pragma unroll
    for (int i = 0; i < 4; ++i)
#pragma unroll
        for (int r = 0; r < 4; ++r) { a2[i][r] = 0.f; a4[i][r] = 0.f; }
#pragma unroll
    for (int i = 0; i < 4; ++i)
#pragma unroll
        for (int j = 0; j < 4; ++j)
#pragma unroll
            for (int r = 0; r < 4; ++r) {
                float uu = fmaxf(acc[i][j][r] + bias[j], 0.f) + EPSF;
                float q2 = uu * uu;
                acc[i][j][r] = q2;
                a2[i][r] += q2;
                a4[i][r] += q2 * q2;
            }
#pragma unroll
    for (int m = 1; m <= 8; m <<= 1) {
#pragma unroll
        for (int i = 0; i < 4; ++i)
#pragma unroll
            for (int r = 0; r < 4; ++r) {
                a2[i][r] += __shfl_xor(a2[i][r], m, 64);
                a4[i][r] += __shfl_xor(a4[i][r], m, 64);
            }
    }
    if (l15 == 0) {
#pragma unroll
        for (int i = 0; i < 4; ++i)
#pragma unroll
            for (int r = 0; r < 4; ++r) {
                reds2[w][i * 16 + q * 4 + r] = a2[i][r];
                reds4[w][i * 16 + q * 4 + r] = a4[i][r];
            }
    }
    __syncthreads();
    if (t < 64) {
        float s2t = reds2[0][t] + reds2[1][t] + reds2[2][t] + reds2[3][t];
        float s4t = reds4[0][t] + reds4[1][t] + reds4[2][t] + reds4[3][t];
        rowv[t] = sqrtf(s2t) / (c * sqrtf(s4t));
    }
    __syncthreads();
    float sc_[4][4];
#pragma unroll
    for (int i = 0; i < 4; ++i)
#pragma unroll
        for (int r = 0; r < 4; ++r) sc_[i][r] = rowv[i * 16 + q * 4 + r];

    if (mode == 0) {
        float colp[4];
#pragma unroll
        for (int j = 0; j < 4; ++j) colp[j] = 0.f;
#pragma unroll
        for (int i = 0; i < 4; ++i)
#pragma unroll
            for (int j = 0; j < 4; ++j)
#pragma unroll
                for (int r = 0; r < 4; ++r) {
                    float ph = acc[i][j][r] * sc_[i][r];
                    acc[i][j][r] = ph;
                    colp[j] += ph;
                }
        // transposed store via swizzled LDS [256 col][64 n]
#pragma unroll
        for (int i = 0; i < 4; ++i)
#pragma unroll
            for (int j = 0; j < 4; ++j) {
                const int cl = wn + j * 16 + l15;
#pragma unroll
                for (int r2 = 0; r2 < 4; r2 += 2) {
                    const int nl = i * 16 + q * 4 + r2;
                    const unsigned int pk =
                        (unsigned int)f2b(acc[i][j][r2]) |
                        ((unsigned int)f2b(acc[i][j][r2 + 1]) << 16);
                    *(unsigned int*)(&smem[cl * 64 + (((nl >> 3) ^ (cl & 7)) << 3) + (nl & 7)]) = pk;
                }
            }
        __syncthreads();
#pragma unroll
        for (int k = 0; k < 8; ++k) {
            const int task = k * 256 + t;
            const int cl = task >> 3, nq = task & 7;
            *(u16x8*)(outbuf + (size_t)(h * 256 + cl) * CH + m0 + nq * 8) =
                *(const u16x8*)(&smem[cl * 64 + ((nq ^ (cl & 7)) << 3)]);
        }
        // colsum replicas
#pragma unroll
        for (int j = 0; j < 4; ++j) {
            colp[j] += __shfl_xor(colp[j], 16, 64);
            colp[j] += __shfl_xor(colp[j], 32, 64);
        }
        if (q == 0) {
            float* dst = colsum_rep + (size_t)(blockIdx.x & 7) * 2048;
#pragma unroll
            for (int j = 0; j < 4; ++j)
                atomicAdd(&dst[h * 256 + wn + j * 16 + l15], colp[j]);
        }
    } else {
        float cs[4];
#pragma unroll
        for (int j = 0; j < 4; ++j) cs[j] = colsum_in[h * 256 + wn + j * 16 + l15];
        float dp[4][4];
#pragma unroll
        for (int i = 0; i < 4; ++i)
#pragma unroll
            for (int r = 0; r < 4; ++r) dp[i][r] = 0.f;
#pragma unroll
        for (int i = 0; i < 4; ++i)
#pragma unroll
            for (int j = 0; j < 4; ++j)
#pragma unroll
                for (int r = 0; r < 4; ++r) {
                    float ph = acc[i][j][r] * sc_[i][r];
                    acc[i][j][r] = ph;
                    dp[i][r] += ph * cs[j];
                }
#pragma unroll
        for (int m = 1; m <= 8; m <<= 1) {
#pragma unroll
            for (int i = 0; i < 4; ++i)
#pragma unroll
                for (int r = 0; r < 4; ++r)
                    dp[i][r] += __shfl_xor(dp[i][r], m, 64);
        }
        if (l15 == 0) {
#pragma unroll
            for (int i = 0; i < 4; ++i)
#pragma unroll
                for (int r = 0; r < 4; ++r)
                    reds2[w][i * 16 + q * 4 + r] = dp[i][r];
        }
        __syncthreads();
        if (t < 64) {
            float dt = reds2[0][t] + reds2[1][t] + reds2[2][t] + reds2[3][t];
            rowv[t] = 1.f / (dt + EPSF);
        }
        __syncthreads();
#pragma unroll
        for (int i = 0; i < 4; ++i)
#pragma unroll
            for (int r = 0; r < 4; ++r) sc_[i][r] = rowv[i * 16 + q * 4 + r];
#pragma unroll
        for (int i = 0; i < 4; ++i)
#pragma unroll
            for (int j = 0; j < 4; ++j)
#pragma unroll
                for (int r = 0; r < 4; ++r) {
                    const int n = m0 + i * 16 + q * 4 + r;
                    outbuf[(size_t)n * 2048 + h * 256 + wn + j * 16 + l15] =
                        f2b(acc[i][j][r] * sc_[i][r]);
                }
    }
}

// ---------------- merge colsum replicas ----------------
__global__ __launch_bounds__(256) void merge_colsum(
    const float* __restrict__ rep, float* __restrict__ out)
{
    const int cidx = blockIdx.x * 256 + threadIdx.x;
    float s = 0.f;
#pragma unroll
    for (int r = 0; r < 8; ++r) s += rep[(size_t)r * 2048 + cidx];
    out[cidx] = s;
}

// ---------------- ktv MFMA: ktv[h] += phiK_h^T @ vs_h (transposed inputs, prefetched) ----------------
__global__ __launch_bounds__(256) void ktv_mfma(
    const unsigned short* __restrict__ phiT,   // [2048][CH]
    const unsigned short* __restrict__ vsT,    // [2048][CH]
    float* __restrict__ ktv, int CH)
{
    __shared__ __align__(16) unsigned short lAT[128 * 64];
    __shared__ __align__(16) unsigned short lBT[128 * 64];
    const int t = threadIdx.x;
    const int h = blockIdx.y;
    const int split = blockIdx.x >> 2;
    const int tile = blockIdx.x & 3;
    const int m0 = (tile >> 1) * 128, d0 = (tile & 1) * 128;
    const int chh = h * 256;
    const int lane = t & 63, w = t >> 6;
    const int wm = (w >> 1) * 64, wn = (w & 1) * 64;
    const int l15 = lane & 15, q = lane >> 4;
    const int sl7 = l15 & 7;

    const int scg  = t >> 3;
    const int snq  = t & 7;
    const int sbase = scg * 64 + ((snq ^ (scg & 7)) << 3);

    f32x4 acc[4][4] = {};
    const int nb0 = split * 512;

    const unsigned short* pA = phiT + (size_t)(chh + m0 + scg) * CH + snq * 8;
    const unsigned short* pB = vsT  + (size_t)(chh + d0 + scg) * CH + snq * 8;

    u16x8 cA[4], cB[4], nA[4], nB[4];
#pragma unroll
    for (int k = 0; k < 4; ++k) {
        cA[k] = *(const u16x8*)(pA + (size_t)(k * 32) * CH + nb0);
        cB[k] = *(const u16x8*)(pB + (size_t)(k * 32) * CH + nb0);
    }

    for (int it = 0; it < 8; ++it) {
#pragma unroll
        for (int k = 0; k < 4; ++k) {
            *(u16x8*)(&lAT[k * 2048 + sbase]) = cA[k];
            *(u16x8*)(&lBT[k * 2048 + sbase]) = cB[k];
        }
        if (it < 7) {
            const int nb = nb0 + (it + 1) * 64;
#pragma unroll
            for (int k = 0; k < 4; ++k) {
                nA[k] = *(const u16x8*)(pA + (size_t)(k * 32) * CH + nb);
                nB[k] = *(const u16x8*)(pB + (size_t)(k * 32) * CH + nb);
            }
        }
        __syncthreads();
#pragma unroll
        for (int sub = 0; sub < 2; ++sub) {
            const int slot = ((sub * 4 + q) ^ sl7) << 3;
            bf16x8 af[4], bfr[4];
#pragma unroll
            for (int i = 0; i < 4; ++i)
                af[i] = *(const bf16x8*)(&lAT[(wm + i * 16 + l15) * 64 + slot]);
#pragma unroll
            for (int j = 0; j < 4; ++j)
                bfr[j] = *(const bf16x8*)(&lBT[(wn + j * 16 + l15) * 64 + slot]);
#pragma unroll
            for (int i = 0; i < 4; ++i)
#pragma unroll
                for (int j = 0; j < 4; ++j)
                    acc[i][j] = __builtin_amdgcn_mfma_f32_16x16x32_bf16(af[i], bfr[j], acc[i][j], 0, 0, 0);
        }
        __syncthreads();
        if (it < 7) {
#pragma unroll
            for (int k = 0; k < 4; ++k) { cA[k] = nA[k]; cB[k] = nB[k]; }
        }
    }
#pragma unroll
    for (int i = 0; i < 4; ++i)
#pragma unroll
        for (int j = 0; j < 4; ++j)
#pragma unroll
            for (int r = 0; r < 4; ++r) {
                const int m = m0 + wm + i * 16 + q * 4 + r;
                const int d = d0 + wn + j * 16 + l15;
                atomicAdd(&ktv[((size_t)chh + m) * 256 + d], acc[i][j][r]);
            }
}

// ---------------- final staging load ----------------
__device__ __forceinline__ void fin_load(
    const unsigned short* __restrict__ Abuf, const unsigned short* __restrict__ W2T,
    int n0, int d0, int t, int k0,
    u16x8& A0, u16x8& A1, u16x8& B)
{
    {
        const int row = t >> 2, kg = (t & 3) * 8;
        A0 = *(const u16x8*)(Abuf + (size_t)(n0 + row) * 2048 + ((k0 + kg) & 2047));
    }
    {
        const int e = t + 256;
        const int row = e >> 2, kg = (e & 3) * 8;
        A1 = *(const u16x8*)(Abuf + (size_t)(n0 + row) * 2048 + ((k0 + kg) & 2047));
    }
    {
        const int row = t >> 2, kg = (t & 3) * 8;
        B = *(const u16x8*)(W2T + (size_t)(d0 + row) * 4096 + k0 + kg);
    }
}

// ---------------- final MFMA GEMM 128x64 (reg-prefetch, split-K x2, atomic) ----------------
__global__ __launch_bounds__(256) void final_mfma(
    const unsigned short* __restrict__ Abuf,
    const unsigned short* __restrict__ W2T,
    int kbeg, int kend,
    float* __restrict__ outp)
{
    __shared__ __align__(16) unsigned short lA[128 * 40];
    __shared__ __align__(16) unsigned short lB[64 * 40];
    const int t = threadIdx.x;
    const int n0 = blockIdx.x * 128;
    const int d0 = blockIdx.y * 64;
    const int khalf = (kend - kbeg) >> 1;
    const int kb = kbeg + blockIdx.z * khalf;
    const int ke = kb + khalf;
    const int lane = t & 63, w = t >> 6;
    const int wm = w * 32;
    const int l15 = lane & 15, q = lane >> 4;

    f32x4 acc[2][4] = {};
    u16x8 cA0, cA1, cB, nA0, nA1, nB;
    fin_load(Abuf, W2T, n0, d0, t, kb, cA0, cA1, cB);

    for (int k0 = kb; k0 < ke; k0 += 32) {
        {
            const int row = t >> 2, kg = (t & 3) * 8;
            *(u16x8*)(&lA[row * 40 + kg]) = cA0;
            *(u16x8*)(&lB[row * 40 + kg]) = cB;
        }
        {
            const int e = t + 256;
            const int row = e >> 2, kg = (e & 3) * 8;
            *(u16x8*)(&lA[row * 40 + kg]) = cA1;
        }
        if (k0 + 32 < ke)
            fin_load(Abuf, W2T, n0, d0, t, k0 + 32, nA0, nA1, nB);
        __syncthreads();
        bf16x8 af[2], bfr[4];
#pragma unroll
        for (int i = 0; i < 2; ++i)
            af[i] = *(const bf16x8*)(&lA[(wm + i * 16 + l15) * 40 + q * 8]);
#pragma unroll
        for (int j = 0; j < 4; ++j)
            bfr[j] = *(const bf16x8*)(&lB[(j * 16 + l15) * 40 + q * 8]);
#pragma unroll
        for (int i = 0; i < 2; ++i)
#pragma unroll
            for (int j = 0; j < 4; ++j)
                acc[i][j] = __builtin_amdgcn_mfma_f32_16x16x32_bf16(af[i], bfr[j], acc[i][j], 0, 0, 0);
        __syncthreads();
        if (k0 + 32 < ke) { cA0 = nA0; cA1 = nA1; cB = nB; }
    }
#pragma unroll
    for (int i = 0; i < 2; ++i)
#pragma unroll
        for (int j = 0; j < 4; ++j)
#pragma unroll
            for (int r = 0; r < 4; ++r) {
                const int n = n0 + wm + i * 16 + q * 4 + r;
                const int d = d0 + j * 16 + l15;
                atomicAdd(&outp[(size_t)n * 257 + 1 + d], acc[i][j][r]);
            }
}

// ---------------- W2T upper = ktv_h @ F_h^T (bf16) ----------------
__global__ __launch_bounds__(256) void w2u_kernel(
    const float* __restrict__ ktv,
    const float* __restrict__ fw,
    unsigned short* __restrict__ W2T)
{
    const int t = threadIdx.x;
    const int h = blockIdx.x >> 3;
    const int m0 = (blockIdx.x & 7) * 32;

    __shared__ __align__(16) float xlds[16][40];
    __shared__ float wlds[256][17];

    float acc[32];
#pragma unroll
    for (int r = 0; r < 32; ++r) acc[r] = 0.f;

    const int ar = t >> 3;
    const int ak = (t & 7) * 2;
    const int wk = t & 15;
    const int wo = (t >> 4) * 16;

    for (int d0 = 0; d0 < 256; d0 += 16) {
        {
            const float* src = ktv + (size_t)(h * 256 + m0 + ar) * 256 + d0 + ak;
            xlds[ak][ar]     = src[0];
            xlds[ak + 1][ar] = src[1];
        }
#pragma unroll
        for (int j = 0; j < 16; ++j)
            wlds[wo + j][wk] = fw[(size_t)(wo + j) * 2048 + h * 256 + d0 + wk];
        __syncthreads();
#pragma unroll
        for (int kk = 0; kk < 16; ++kk) {
            float bv = wlds[t][kk];
            const float4* xr = (const float4*)(&xlds[kk][0]);
#pragma unroll
            for (int g = 0; g < 8; ++g) {
                float4 xv = xr[g];
                acc[g * 4 + 0] = fmaf(xv.x, bv, acc[g * 4 + 0]);
                acc[g * 4 + 1] = fmaf(xv.y, bv, acc[g * 4 + 1]);
                acc[g * 4 + 2] = fmaf(xv.z, bv, acc[g * 4 + 2]);
                acc[g * 4 + 3] = fmaf(xv.w, bv, acc[g * 4 + 3]);
            }
        }
        __syncthreads();
    }
#pragma unroll
    for (int r = 0; r < 32; ++r)
        W2T[(size_t)t * 4096 + h * 256 + m0 + r] = f2b(acc[r]);
}

// ---------------- epilogue: bias + Lorentz lift ----------------
__global__ __launch_bounds__(256) void lift_kernel(
    const float* __restrict__ bias2, float* __restrict__ outp)
{
    const int t = threadIdx.x;
    const int lane = t & 63;
    const int w = t >> 6;
    const int n0 = blockIdx.x * 64 + w * 16;
    float b[4];
#pragma unroll
    for (int j = 0; j < 4; ++j) b[j] = bias2[lane + j * 64];
    for (int r = 0; r < 16; ++r) {
        float* row = outp + (size_t)(n0 + r) * 257;
        float v[4];
        float s = 0.f;
#pragma unroll
        for (int j = 0; j < 4; ++j) {
            v[j] = row[1 + lane + j * 64] + b[j];
            s = fmaf(v[j], v[j], s);
        }
#pragma unroll
        for (int off = 32; off > 0; off >>= 1) s += __shfl_down(s, off, 64);
#pragma unroll
        for (int j = 0; j < 4; ++j) row[1 + lane + j * 64] = v[j];
        if (lane == 0) row[0] = sqrtf(s + 1.0f);
    }
}

extern "C" void kernel_launch(void* const* d_in, const int* in_sizes, int n_in,
                              void* d_out, int out_size, void* d_ws, size_t ws_size,
                              hipStream_t stream)
{
    const float* xq  = (const float*)d_in[0];
    const float* xs  = (const float*)d_in[1];
    const float* Wq  = (const float*)d_in[2];
    const float* Bq  = (const float*)d_in[3];
    const float* Wk  = (const float*)d_in[4];
    const float* Bk  = (const float*)d_in[5];
    const float* Wv  = (const float*)d_in[6];
    const float* Bv  = (const float*)d_in[7];
    const float* nsc = (const float*)d_in[8];
    const float* vmw = (const float*)d_in[9];
    const float* vmb = (const float*)d_in[10];
    const float* fw  = (const float*)d_in[11];
    const float* fb  = (const float*)d_in[12];
    float* outp = (float*)d_out;

    char* ws = (char*)d_ws;
    float* ktv          = (float*)(ws + 0);                 // 2,097,152
    float* colrep       = (float*)(ws + 2097152);           //    65,536
    float* Mf32         = (float*)(ws + 2162688);           //   294,912 (256x288 f32)
    float* colsum       = (float*)(ws + 2457600);           //     8,192
    float* bias2        = (float*)(ws + 2465792);           //     1,024
    float* biasAll      = (float*)(ws + 2466816);           //    24,576
    unsigned short* W2T = (unsigned short*)(ws + 2491392);  // 2,097,152
    unsigned short* Wbf = (unsigned short*)(ws + 4588544);  // 3,538,944
    float* G32          = (float*)(ws + 8127488);           // 2,097,152
    unsigned short* Mbf = (unsigned short*)(ws + 10224640); //   147,456
    const size_t fixedBytes = 10372096;

    int CH = 2048;
    if (ws_size >= fixedBytes + (size_t)8192 * 8192) CH = 8192;
    else if (ws_size >= fixedBytes + (size_t)4096 * 8192) CH = 4096;
    const int NCHK = 32768 / CH;
    unsigned short* phibuf = (unsigned short*)(ws + fixedBytes);                       // phiT (A) / phiQ rows (B)
    unsigned short* vsT    = (unsigned short*)(ws + fixedBytes + (size_t)CH * 4096);   // vs transposed

    // zero ktv + colrep + Mf32 (contiguous 614400 floats)
    zero_kernel<<<dim3(2400), 256, 0, stream>>>(ktv, 614400);
    wconv_kernel<<<dim3(6168), 256, 0, stream>>>(Wq, Wk, Wv, Bq, Bk, Bv, Wbf, biasAll);
    w2g_kernel<<<dim3(64), 256, 0, stream>>>(vmw, fw, G32);
    bias2_kernel<<<dim3(256), 256, 0, stream>>>(vmb, fw, fb, Bv, G32, bias2);
    gm_kernel<<<dim3(4, 9, 8), 256, 0, stream>>>(Wv, G32, Mf32);
    gmcvt_kernel<<<dim3(288), 256, 0, stream>>>(Mf32, Mbf);

    // Pass A: K/V chunks -> phiT (fused+transposed), colsum replicas, ktv, out = Xs@M
    for (int c = 0; c < NCHK; ++c) {
        const float* xs_c = xs + (size_t)c * CH * 257;
        float* out_c = outp + (size_t)c * CH * 257;
        proj_phi<<<dim3(CH / 64, 8), 256, 0, stream>>>(
            xs_c, Wbf + (size_t)2048 * 288, biasAll + 2048, phibuf,
            nsc, nullptr, colrep, 0, CH);
        proj_mfma<<<dim3(CH / 64, 8), 256, 0, stream>>>(
            xs_c, Wbf + (size_t)4096 * 288, biasAll + 4096, vsT, CH);
        xm_mfma<<<dim3(CH / 64), 256, 0, stream>>>(xs_c, Mbf, out_c);
        ktv_mfma<<<dim3((CH / 512) * 4, 8), 256, 0, stream>>>(phibuf, vsT, ktv, CH);
    }

    // merge colsum replicas; ktv-dependent weights
    merge_colsum<<<dim3(8), 256, 0, stream>>>(colrep, colsum);
    w2u_kernel<<<dim3(64), 256, 0, stream>>>(ktv, fw, W2T);

    // Pass B: Q chunks -> phiQ*invden (fused, row-major), out += phiQs @ W2u (split-K)
    for (int c = 0; c < NCHK; ++c) {
        const float* xq_c = xq + (size_t)c * CH * 257;
        float* out_c = outp + (size_t)c * CH * 257;
        proj_phi<<<dim3(CH / 64, 8), 256, 0, stream>>>(
            xq_c, Wbf, biasAll, phibuf,
            nsc, colsum, nullptr, 1, CH);
        final_mfma<<<dim3(CH / 128, 4, 2), 256, 0, stream>>>(phibuf, W2T, 0, 2048, out_c);
    }

    // bias + Lorentz lift
    lift_kernel<<<dim3(512), 256, 0, stream>>>(bias2, outp);
}

// Round 7
// 1166.077 us; speedup vs baseline: 1.0995x; 1.0995x over previous
//
#include <hip/hip_runtime.h>
#include <hip/hip_bf16.h>

// DHHT round 14: revert to round-12 base (1045us; round-13 direct-fragment
// loads were uncoalesced, 16-64 lines/instr -> regression), then:
//  - double-buffered LDS K-loop: ONE barrier per K-step (was 2). Write of
//    step k+1 targets buf[(k+1)&1] while reads hit buf[k&1] -> race-free.
//  - proj_all: Pass A's 3 GEMMs (phiK / V / xm) merged into one dispatch,
//    grid y=17 (8 K-heads, 8 V-heads, 1 xm). Modes share the dbuf GEMM core;
//    co-resident heterogeneous blocks overlap barrier stalls.
//  - final_mfma: dbuf + split-K 4 (4 blocks/CU).
// W2T bf16 [256][4096]: cols 0..2047 = W2u (ktv@F^T). G lives in G32 (f32).

#define EPSF 1e-6f

typedef __attribute__((ext_vector_type(8))) short bf16x8;
typedef __attribute__((ext_vector_type(8))) unsigned short u16x8;
typedef __attribute__((ext_vector_type(4))) float f32x4;
typedef float f32x4a __attribute__((ext_vector_type(4), aligned(4)));

__device__ __forceinline__ float b2f(unsigned short u) {
    union { unsigned int i; float f; } c;
    c.i = ((unsigned int)u) << 16;
    return c.f;
}
__device__ __forceinline__ unsigned short f2b(float f) {
    __hip_bfloat16 h = __float2bfloat16(f);
    union { __hip_bfloat16 h; unsigned short u; } c;
    c.h = h;
    return c.u;
}

__global__ void zero_kernel(float* __restrict__ p, int n) {
    int i = blockIdx.x * 256 + threadIdx.x;
    if (i < n) p[i] = 0.f;
}

// ---------------- weight convert: Wbf [6144][288] bf16 + biasAll[6144] ----------------
__global__ __launch_bounds__(256) void wconv_kernel(
    const float* __restrict__ Wq, const float* __restrict__ Wk, const float* __restrict__ Wv,
    const float* __restrict__ Bq, const float* __restrict__ Bk, const float* __restrict__ Bv,
    unsigned short* __restrict__ Wbf, float* __restrict__ biasAll)
{
    const int t = threadIdx.x;
    const int b = blockIdx.x;
    if (b < 6144) {
        const int mat = b >> 11, lr = b & 2047;
        const float* Ws = (mat == 0 ? Wq : mat == 1 ? Wk : Wv) + (size_t)lr * 257;
        Wbf[(size_t)b * 288 + t] = f2b(Ws[t]);
        if (t < 32) {
            float v = (t == 0) ? Ws[256] : 0.f;
            Wbf[(size_t)b * 288 + 256 + t] = f2b(v);
        }
    } else {
        const int e = (b - 6144) * 256 + t;
        const int mat = e >> 11, r = e & 2047;
        biasAll[e] = (mat == 0 ? Bq : mat == 1 ? Bk : Bv)[r];
    }
}

// ---------------- G32[o][hk] ----------------
__global__ __launch_bounds__(256) void w2g_kernel(
    const float* __restrict__ vmw,
    const float* __restrict__ fw,
    float* __restrict__ G32)
{
    const int t = threadIdx.x;
    const int h = blockIdx.x >> 3;
    const int i0 = (blockIdx.x & 7) * 32;

    __shared__ __align__(16) float xlds[16][40];
    __shared__ float wlds[256][17];

    float acc[32];
#pragma unroll
    for (int r = 0; r < 32; ++r) acc[r] = 0.f;

    const int ar = t >> 3;
    const int ak = (t & 7) * 2;
    const int wk = t & 15;
    const int wo = (t >> 4) * 16;

    for (int d0 = 0; d0 < 256; d0 += 16) {
        xlds[ak][ar]     = vmw[(size_t)(d0 + ak) * 256 + i0 + ar];
        xlds[ak + 1][ar] = vmw[(size_t)(d0 + ak + 1) * 256 + i0 + ar];
#pragma unroll
        for (int j = 0; j < 16; ++j)
            wlds[wo + j][wk] = fw[(size_t)(wo + j) * 2048 + h * 256 + d0 + wk];
        __syncthreads();
#pragma unroll
        for (int kk = 0; kk < 16; ++kk) {
            float bv = wlds[t][kk];
            const float4* xr = (const float4*)(&xlds[kk][0]);
#pragma unroll
            for (int g = 0; g < 8; ++g) {
                float4 xv = xr[g];
                acc[g * 4 + 0] = fmaf(xv.x, bv, acc[g * 4 + 0]);
                acc[g * 4 + 1] = fmaf(xv.y, bv, acc[g * 4 + 1]);
                acc[g * 4 + 2] = fmaf(xv.z, bv, acc[g * 4 + 2]);
                acc[g * 4 + 3] = fmaf(xv.w, bv, acc[g * 4 + 3]);
            }
        }
        __syncthreads();
    }
#pragma unroll
    for (int r = 0; r < 32; ++r)
        G32[(size_t)t * 2048 + h * 256 + i0 + r] = acc[r];
}

// ---------------- bias2 ----------------
__global__ __launch_bounds__(256) void bias2_kernel(
    const float* __restrict__ vmb, const float* __restrict__ fw,
    const float* __restrict__ fb, const float* __restrict__ Bv,
    const float* __restrict__ G32, float* __restrict__ bias2)
{
    const int o = blockIdx.x;
    const int t = threadIdx.x;
    float s = 0.f, sb = 0.f;
#pragma unroll
    for (int i = 0; i < 8; ++i) {
        const int j = t + i * 256;
        s += fw[(size_t)o * 2048 + j];
        sb += Bv[j] * G32[(size_t)o * 2048 + j];
    }
    s = s * vmb[t] + sb;
#pragma unroll
    for (int off = 32; off > 0; off >>= 1) s += __shfl_down(s, off, 64);
    __shared__ float r4[4];
    if ((t & 63) == 0) r4[t >> 6] = s;
    __syncthreads();
    if (t == 0) bias2[o] = fb[o] + r4[0] + r4[1] + r4[2] + r4[3];
}

// ---------------- Mf32[o][i] += sum_k G32[o][k] Wv[k][i] ----------------
__global__ __launch_bounds__(256) void gm_kernel(
    const float* __restrict__ Wv, const float* __restrict__ G32,
    float* __restrict__ Mf32)
{
    __shared__ float Gt[64][33];
    __shared__ float Wt[32][33];
    const int t = threadIdx.x;
    const int o0 = blockIdx.x * 64, i0 = blockIdx.y * 32, k0 = blockIdx.z * 256;
    const int ii = t & 31, og = t >> 5;
    float acc[8] = {};
    for (int kk0 = k0; kk0 < k0 + 256; kk0 += 32) {
#pragma unroll
        for (int r = 0; r < 8; ++r) {
            const int e = t + r * 256;
            Gt[e >> 5][e & 31] = G32[(size_t)(o0 + (e >> 5)) * 2048 + kk0 + (e & 31)];
        }
#pragma unroll
        for (int r = 0; r < 4; ++r) {
            const int e = t + r * 256;
            const int kk = e >> 5, i = i0 + (e & 31);
            Wt[kk][e & 31] = (i < 257) ? Wv[(size_t)(kk0 + kk) * 257 + i] : 0.f;
        }
        __syncthreads();
#pragma unroll
        for (int kk = 0; kk < 32; ++kk) {
            float wv_ = Wt[kk][ii];
#pragma unroll
            for (int r = 0; r < 8; ++r)
                acc[r] = fmaf(Gt[og * 8 + r][kk], wv_, acc[r]);
        }
        __syncthreads();
    }
#pragma unroll
    for (int r = 0; r < 8; ++r)
        atomicAdd(&Mf32[(size_t)(o0 + og * 8 + r) * 288 + i0 + ii], acc[r]);
}

__global__ void gmcvt_kernel(const float* __restrict__ Mf32, unsigned short* __restrict__ Mbf) {
    const int i = blockIdx.x * 256 + threadIdx.x;
    Mbf[i] = f2b(Mf32[i]);
}

// ---------------- staging helpers for proj_all ----------------
__device__ __forceinline__ void stage_load(
    const float* __restrict__ XA, const unsigned short* __restrict__ WB, int k,
    f32x4a& cx0, f32x4a& cx1, u16x8 cw[4])
{
    cx0 = *(const f32x4a*)(XA + k);
    cx1 = *(const f32x4a*)(XA + k + 4);
#pragma unroll
    for (int qq = 0; qq < 4; ++qq)
        cw[qq] = *(const u16x8*)(WB + (size_t)qq * 64 * 288 + k);
}

__device__ __forceinline__ void stage_write(
    unsigned short* __restrict__ la, unsigned short* __restrict__ lb,
    int ar, int akg, f32x4a cx0, f32x4a cx1, const u16x8 cw[4])
{
    u16x8 pk;
    pk[0] = f2b(cx0[0]); pk[1] = f2b(cx0[1]); pk[2] = f2b(cx0[2]); pk[3] = f2b(cx0[3]);
    pk[4] = f2b(cx1[0]); pk[5] = f2b(cx1[1]); pk[6] = f2b(cx1[2]); pk[7] = f2b(cx1[3]);
    *(u16x8*)(&la[ar * 40 + akg]) = pk;
#pragma unroll
    for (int qq = 0; qq < 4; ++qq)
        *(u16x8*)(&lb[(ar + qq * 64) * 40 + akg]) = cw[qq];
}

// transposed store via swizzled LDS [256 col][64 n]
__device__ __forceinline__ void tstore(
    unsigned short* __restrict__ smem, const f32x4 acc[4][4],
    unsigned short* __restrict__ outT, int cbase, int m0, int CH,
    int wn, int l15, int q, int t)
{
#pragma unroll
    for (int i = 0; i < 4; ++i)
#pragma unroll
        for (int j = 0; j < 4; ++j) {
            const int cl = wn + j * 16 + l15;
#pragma unroll
            for (int r2 = 0; r2 < 4; r2 += 2) {
                const int nl = i * 16 + q * 4 + r2;
                const unsigned int pk =
                    (unsigned int)f2b(acc[i][j][r2]) |
                    ((unsigned int)f2b(acc[i][j][r2 + 1]) << 16);
                *(unsigned int*)(&smem[cl * 64 + (((nl >> 3) ^ (cl & 7)) << 3) + (nl & 7)]) = pk;
            }
        }
    __syncthreads();
#pragma unroll
    for (int k = 0; k < 8; ++k) {
        const int task = k * 256 + t;
        const int cl = task >> 3, nq = task & 7;
        *(u16x8*)(outT + (size_t)(cbase + cl) * CH + m0 + nq * 8) =
            *(const u16x8*)(&smem[cl * 64 + ((nq ^ (cl & 7)) << 3)]);
    }
}

// ---------------- merged projection kernel (dbuf, 1 barrier/K-step) ----------------
// pass 0 (A): y<8 -> K-head (phiT + colrep); y<16 -> V-head (vsT); y==16 -> xm (f32 rows).
// pass 1 (B): y<8 -> Q-head (phi*invden, row-major into phiOut).
__global__ __launch_bounds__(256, 3) void proj_all(
    int pass,
    const float* __restrict__ X,
    const unsigned short* __restrict__ Wbf,
    const unsigned short* __restrict__ Mbf,
    const float* __restrict__ biasAll,
    unsigned short* __restrict__ phiOut,
    unsigned short* __restrict__ vsOut,
    float* __restrict__ xOut,
    const float* __restrict__ nsc,
    const float* __restrict__ colsum_in,
    float* __restrict__ colrep,
    int CH)
{
    __shared__ __align__(16) unsigned short smem[27008];
    // lA bufs: 0,2560 (64x40) ; lB bufs: 5120,15360 (256x40); reds overlay at 25600
    float* reds2 = (float*)(smem + 25600);   // [4*64]
    float* reds4 = reds2 + 256;
    float* rowv  = reds4 + 256;
    float* rowx  = rowv + 64;

    const int t = threadIdx.x;
    const int m0 = blockIdx.x * 64;
    const int y  = blockIdx.y;
    const int lane = t & 63, w = t >> 6;
    const int wn = w * 64;
    const int l15 = lane & 15, q = lane >> 4;
    const int ar = t >> 2, akg = (t & 3) * 8;

    // mode: 0=K 1=V 2=X 3=Q
    int mode, hcol;
    const unsigned short* Wb;
    const float* bb;
    if (pass == 1)   { mode = 3; hcol = y * 256; Wb = Wbf + (size_t)hcol * 288;          bb = biasAll + hcol; }
    else if (y < 8)  { mode = 0; hcol = y * 256; Wb = Wbf + (size_t)(2048 + hcol) * 288; bb = biasAll + 2048 + hcol; }
    else if (y < 16) { mode = 1; hcol = (y - 8) * 256; Wb = Wbf + (size_t)(4096 + hcol) * 288; bb = biasAll + 4096 + hcol; }
    else             { mode = 2; hcol = 0; Wb = Mbf; bb = nullptr; }

    const float* XA = X + (size_t)(m0 + ar) * 257 + akg;
    const unsigned short* WB = Wb + (size_t)ar * 288 + akg;

    f32x4 acc[4][4] = {};
    f32x4a cx0, cx1;
    u16x8 cw[4];

    stage_load(XA, WB, 0, cx0, cx1, cw);
    stage_write(smem, smem + 5120, ar, akg, cx0, cx1, cw);
    stage_load(XA, WB, 32, cx0, cx1, cw);
    __syncthreads();

#pragma unroll
    for (int ks = 0; ks < 8; ++ks) {
        const int b = ks & 1;
        unsigned short* la = smem + (b ? 2560 : 0);
        unsigned short* lb = smem + (b ? 15360 : 5120);
        bf16x8 af[4], bfr[4];
#pragma unroll
        for (int i = 0; i < 4; ++i)
            af[i] = *(const bf16x8*)(&la[(i * 16 + l15) * 40 + q * 8]);
#pragma unroll
        for (int j = 0; j < 4; ++j)
            bfr[j] = *(const bf16x8*)(&lb[(wn + j * 16 + l15) * 40 + q * 8]);
#pragma unroll
        for (int i = 0; i < 4; ++i)
#pragma unroll
            for (int j = 0; j < 4; ++j)
                acc[i][j] = __builtin_amdgcn_mfma_f32_16x16x32_bf16(af[i], bfr[j], acc[i][j], 0, 0, 0);
        if (ks < 7) {
            unsigned short* la2 = smem + (b ? 0 : 2560);
            unsigned short* lb2 = smem + (b ? 5120 : 15360);
            stage_write(la2, lb2, ar, akg, cx0, cx1, cw);
            if (ks < 6) stage_load(XA, WB, (ks + 2) * 32, cx0, cx1, cw);
        }
        __syncthreads();
    }

    if (t < 64) rowx[t] = b2f(f2b(X[(size_t)(m0 + t) * 257 + 256]));
    __syncthreads();

    // rank-1 Lorentz column
    {
        float w256[4];
#pragma unroll
        for (int j = 0; j < 4; ++j)
            w256[j] = b2f(Wb[(size_t)(wn + j * 16 + l15) * 288 + 256]);
#pragma unroll
        for (int i = 0; i < 4; ++i)
#pragma unroll
            for (int r = 0; r < 4; ++r) {
                const float xv = rowx[i * 16 + q * 4 + r];
#pragma unroll
                for (int j = 0; j < 4; ++j)
                    acc[i][j][r] += xv * w256[j];
            }
    }

    if (mode == 2) {
        // xm: f32 row store
#pragma unroll
        for (int j = 0; j < 4; ++j) {
            const int cg = wn + j * 16 + l15;
#pragma unroll
            for (int i = 0; i < 4; ++i)
#pragma unroll
                for (int r = 0; r < 4; ++r) {
                    const int n = m0 + i * 16 + q * 4 + r;
                    xOut[(size_t)n * 257 + 1 + cg] = acc[i][j][r];
                }
        }
        return;
    }
    if (mode == 1) {
        // V: bias + transposed store
#pragma unroll
        for (int j = 0; j < 4; ++j) {
            const float bias = bb[wn + j * 16 + l15];
#pragma unroll
            for (int i = 0; i < 4; ++i)
#pragma unroll
                for (int r = 0; r < 4; ++r)
                    acc[i][j][r] += bias;
        }
        tstore(smem, acc, vsOut, hcol, m0, CH, wn, l15, q, t);
        return;
    }

    // K or Q: fused phi
    const float c = fabsf(nsc[0]) + EPSF;
    float bias[4];
#pragma unroll
    for (int j = 0; j < 4; ++j) bias[j] = bb[wn + j * 16 + l15];

    float a2[4][4], a4[4][4];
#pragma unroll
    for (int i = 0; i < 4; ++i)
#pragma unroll
        for (int r = 0; r < 4; ++r) { a2[i][r] = 0.f; a4[i][r] = 0.f; }
#pragma unroll
    for (int i = 0; i < 4; ++i)
#pragma unroll
        for (int j = 0; j < 4; ++j)
#pragma unroll
            for (int r = 0; r < 4; ++r) {
                float uu = fmaxf(acc[i][j][r] + bias[j], 0.f) + EPSF;
                float q2 = uu * uu;
                acc[i][j][r] = q2;
                a2[i][r] += q2;
                a4[i][r] += q2 * q2;
            }
#pragma unroll
    for (int m = 1; m <= 8; m <<= 1) {
#pragma unroll
        for (int i = 0; i < 4; ++i)
#pragma unroll
            for (int r = 0; r < 4; ++r) {
                a2[i][r] += __shfl_xor(a2[i][r], m, 64);
                a4[i][r] += __shfl_xor(a4[i][r], m, 64);
            }
    }
    if (l15 == 0) {
#pragma unroll
        for (int i = 0; i < 4; ++i)
#pragma unroll
            for (int r = 0; r < 4; ++r) {
                reds2[w * 64 + i * 16 + q * 4 + r] = a2[i][r];
                reds4[w * 64 + i * 16 + q * 4 + r] = a4[i][r];
            }
    }
    __syncthreads();
    if (t < 64) {
        float s2t = reds2[t] + reds2[64 + t] + reds2[128 + t] + reds2[192 + t];
        float s4t = reds4[t] + reds4[64 + t] + reds4[128 + t] + reds4[192 + t];
        rowv[t] = sqrtf(s2t) / (c * sqrtf(s4t));
    }
    __syncthreads();
    float sc_[4][4];
#pragma unroll
    for (int i = 0; i < 4; ++i)
#pragma unroll
        for (int r = 0; r < 4; ++r) sc_[i][r] = rowv[i * 16 + q * 4 + r];

    if (mode == 0) {
        float colp[4];
#pragma unroll
        for (int j = 0; j < 4; ++j) colp[j] = 0.f;
#pragma unroll
        for (int i = 0; i < 4; ++i)
#pragma unroll
            for (int j = 0; j < 4; ++j)
#pragma unroll
                for (int r = 0; r < 4; ++r) {
                    float ph = acc[i][j][r] * sc_[i][r];
                    acc[i][j][r] = ph;
                    colp[j] += ph;
                }
        tstore(smem, acc, phiOut, hcol, m0, CH, wn, l15, q, t);
#pragma unroll
        for (int j = 0; j < 4; ++j) {
            colp[j] += __shfl_xor(colp[j], 16, 64);
            colp[j] += __shfl_xor(colp[j], 32, 64);
        }
        if (q == 0) {
            float* dst = colrep + (size_t)(blockIdx.x & 7) * 2048;
#pragma unroll
            for (int j = 0; j < 4; ++j)
                atomicAdd(&dst[hcol + wn + j * 16 + l15], colp[j]);
        }
    } else {
        // Q
        float cs[4];
#pragma unroll
        for (int j = 0; j < 4; ++j) cs[j] = colsum_in[hcol + wn + j * 16 + l15];
        float dp[4][4];
#pragma unroll
        for (int i = 0; i < 4; ++i)
#pragma unroll
            for (int r = 0; r < 4; ++r) dp[i][r] = 0.f;
#pragma unroll
        for (int i = 0; i < 4; ++i)
#pragma unroll
            for (int j = 0; j < 4; ++j)
#pragma unroll
                for (int r = 0; r < 4; ++r) {
                    float ph = acc[i][j][r] * sc_[i][r];
                    acc[i][j][r] = ph;
                    dp[i][r] += ph * cs[j];
                }
#pragma unroll
        for (int m = 1; m <= 8; m <<= 1) {
#pragma unroll
            for (int i = 0; i < 4; ++i)
#pragma unroll
                for (int r = 0; r < 4; ++r)
                    dp[i][r] += __shfl_xor(dp[i][r], m, 64);
        }
        if (l15 == 0) {
#pragma unroll
            for (int i = 0; i < 4; ++i)
#pragma unroll
                for (int r = 0; r < 4; ++r)
                    reds2[w * 64 + i * 16 + q * 4 + r] = dp[i][r];
        }
        __syncthreads();
        if (t < 64) {
            float dt = reds2[t] + reds2[64 + t] + reds2[128 + t] + reds2[192 + t];
            rowv[t] = 1.f / (dt + EPSF);
        }
        __syncthreads();
#pragma unroll
        for (int i = 0; i < 4; ++i)
#pragma unroll
            for (int r = 0; r < 4; ++r) sc_[i][r] = rowv[i * 16 + q * 4 + r];
#pragma unroll
        for (int i = 0; i < 4; ++i)
#pragma unroll
            for (int j = 0; j < 4; ++j)
#pragma unroll
                for (int r = 0; r < 4; ++r) {
                    const int n = m0 + i * 16 + q * 4 + r;
                    phiOut[(size_t)n * 2048 + hcol + wn + j * 16 + l15] =
                        f2b(acc[i][j][r] * sc_[i][r]);
                }
    }
}

// ---------------- merge colsum replicas ----------------
__global__ __launch_bounds__(256) void merge_colsum(
    const float* __restrict__ rep, float* __restrict__ out)
{
    const int cidx = blockIdx.x * 256 + threadIdx.x;
    float s = 0.f;
#pragma unroll
    for (int r = 0; r < 8; ++r) s += rep[(size_t)r * 2048 + cidx];
    out[cidx] = s;
}

// ---------------- ktv MFMA (unchanged from round 12) ----------------
__global__ __launch_bounds__(256) void ktv_mfma(
    const unsigned short* __restrict__ phiT,
    const unsigned short* __restrict__ vsT,
    float* __restrict__ ktv, int CH)
{
    __shared__ __align__(16) unsigned short lAT[128 * 64];
    __shared__ __align__(16) unsigned short lBT[128 * 64];
    const int t = threadIdx.x;
    const int h = blockIdx.y;
    const int split = blockIdx.x >> 2;
    const int tile = blockIdx.x & 3;
    const int m0 = (tile >> 1) * 128, d0 = (tile & 1) * 128;
    const int chh = h * 256;
    const int lane = t & 63, w = t >> 6;
    const int wm = (w >> 1) * 64, wn = (w & 1) * 64;
    const int l15 = lane & 15, q = lane >> 4;
    const int sl7 = l15 & 7;

    const int scg  = t >> 3;
    const int snq  = t & 7;
    const int sbase = scg * 64 + ((snq ^ (scg & 7)) << 3);

    f32x4 acc[4][4] = {};
    const int nb0 = split * 512;

    const unsigned short* pA = phiT + (size_t)(chh + m0 + scg) * CH + snq * 8;
    const unsigned short* pB = vsT  + (size_t)(chh + d0 + scg) * CH + snq * 8;

    u16x8 cA[4], cB[4], nA[4], nB[4];
#pragma unroll
    for (int k = 0; k < 4; ++k) {
        cA[k] = *(const u16x8*)(pA + (size_t)(k * 32) * CH + nb0);
        cB[k] = *(const u16x8*)(pB + (size_t)(k * 32) * CH + nb0);
    }

    for (int it = 0; it < 8; ++it) {
#pragma unroll
        for (int k = 0; k < 4; ++k) {
            *(u16x8*)(&lAT[k * 2048 + sbase]) = cA[k];
            *(u16x8*)(&lBT[k * 2048 + sbase]) = cB[k];
        }
        if (it < 7) {
            const int nb = nb0 + (it + 1) * 64;
#pragma unroll
            for (int k = 0; k < 4; ++k) {
                nA[k] = *(const u16x8*)(pA + (size_t)(k * 32) * CH + nb);
                nB[k] = *(const u16x8*)(pB + (size_t)(k * 32) * CH + nb);
            }
        }
        __syncthreads();
#pragma unroll
        for (int sub = 0; sub < 2; ++sub) {
            const int slot = ((sub * 4 + q) ^ sl7) << 3;
            bf16x8 af[4], bfr[4];
#pragma unroll
            for (int i = 0; i < 4; ++i)
                af[i] = *(const bf16x8*)(&lAT[(wm + i * 16 + l15) * 64 + slot]);
#pragma unroll
            for (int j = 0; j < 4; ++j)
                bfr[j] = *(const bf16x8*)(&lBT[(wn + j * 16 + l15) * 64 + slot]);
#pragma unroll
            for (int i = 0; i < 4; ++i)
#pragma unroll
                for (int j = 0; j < 4; ++j)
                    acc[i][j] = __builtin_amdgcn_mfma_f32_16x16x32_bf16(af[i], bfr[j], acc[i][j], 0, 0, 0);
        }
        __syncthreads();
        if (it < 7) {
#pragma unroll
            for (int k = 0; k < 4; ++k) { cA[k] = nA[k]; cB[k] = nB[k]; }
        }
    }
#pragma unroll
    for (int i = 0; i < 4; ++i)
#pragma unroll
        for (int j = 0; j < 4; ++j)
#pragma unroll
            for (int r = 0; r < 4; ++r) {
                const int m = m0 + wm + i * 16 + q * 4 + r;
                const int d = d0 + wn + j * 16 + l15;
                atomicAdd(&ktv[((size_t)chh + m) * 256 + d], acc[i][j][r]);
            }
}

// ---------------- final staging load ----------------
__device__ __forceinline__ void fin_load(
    const unsigned short* __restrict__ Abuf, const unsigned short* __restrict__ W2T,
    int n0, int d0, int t, int k0,
    u16x8& A0, u16x8& A1, u16x8& B)
{
    {
        const int row = t >> 2, kg = (t & 3) * 8;
        A0 = *(const u16x8*)(Abuf + (size_t)(n0 + row) * 2048 + ((k0 + kg) & 2047));
    }
    {
        const int e = t + 256;
        const int row = e >> 2, kg = (e & 3) * 8;
        A1 = *(const u16x8*)(Abuf + (size_t)(n0 + row) * 2048 + ((k0 + kg) & 2047));
    }
    {
        const int row = t >> 2, kg = (t & 3) * 8;
        B = *(const u16x8*)(W2T + (size_t)(d0 + row) * 4096 + k0 + kg);
    }
}

// ---------------- final MFMA GEMM 128x64 (dbuf, split-K via gridDim.z, atomic) ----------------
__global__ __launch_bounds__(256) void final_mfma(
    const unsigned short* __restrict__ Abuf,
    const unsigned short* __restrict__ W2T,
    int kbeg, int kend,
    float* __restrict__ outp)
{
    __shared__ __align__(16) unsigned short smem[15360];
    // lA: 0 / 5120 (128x40); lB: 10240 / 12800 (64x40)
    const int t = threadIdx.x;
    const int n0 = blockIdx.x * 128;
    const int d0 = blockIdx.y * 64;
    const int ksp = (kend - kbeg) / gridDim.z;
    const int kb = kbeg + blockIdx.z * ksp;
    const int lane = t & 63, w = t >> 6;
    const int wm = w * 32;
    const int l15 = lane & 15, q = lane >> 4;
    const int row = t >> 2, kg = (t & 3) * 8;
    const int row2 = (t + 256) >> 2;

    f32x4 acc[2][4] = {};
    u16x8 cA0, cA1, cB;
    fin_load(Abuf, W2T, n0, d0, t, kb, cA0, cA1, cB);
    {
        *(u16x8*)(&smem[row * 40 + kg]) = cA0;
        *(u16x8*)(&smem[10240 + row * 40 + kg]) = cB;
        *(u16x8*)(&smem[row2 * 40 + kg]) = cA1;
    }
    const int nst = ksp >> 5;
    if (nst > 1) fin_load(Abuf, W2T, n0, d0, t, kb + 32, cA0, cA1, cB);
    __syncthreads();

    for (int s = 0; s < nst; ++s) {
        const int b = s & 1;
        unsigned short* la = smem + (b ? 5120 : 0);
        unsigned short* lb = smem + (b ? 12800 : 10240);
        bf16x8 af[2], bfr[4];
#pragma unroll
        for (int i = 0; i < 2; ++i)
            af[i] = *(const bf16x8*)(&la[(wm + i * 16 + l15) * 40 + q * 8]);
#pragma unroll
        for (int j = 0; j < 4; ++j)
            bfr[j] = *(const bf16x8*)(&lb[(j * 16 + l15) * 40 + q * 8]);
#pragma unroll
        for (int i = 0; i < 2; ++i)
#pragma unroll
            for (int j = 0; j < 4; ++j)
                acc[i][j] = __builtin_amdgcn_mfma_f32_16x16x32_bf16(af[i], bfr[j], acc[i][j], 0, 0, 0);
        if (s + 1 < nst) {
            unsigned short* la2 = smem + (b ? 0 : 5120);
            unsigned short* lb2 = smem + (b ? 10240 : 12800);
            *(u16x8*)(&la2[row * 40 + kg]) = cA0;
            *(u16x8*)(&lb2[row * 40 + kg]) = cB;
            *(u16x8*)(&la2[row2 * 40 + kg]) = cA1;
            if (s + 2 < nst)
                fin_load(Abuf, W2T, n0, d0, t, kb + (s + 2) * 32, cA0, cA1, cB);
        }
        __syncthreads();
    }
#pragma unroll
    for (int i = 0; i < 2; ++i)
#pragma unroll
        for (int j = 0; j < 4; ++j)
#pragma unroll
            for (int r = 0; r < 4; ++r) {
                const int n = n0 + wm + i * 16 + q * 4 + r;
                const int d = d0 + j * 16 + l15;
                atomicAdd(&outp[(size_t)n * 257 + 1 + d], acc[i][j][r]);
            }
}

// ---------------- W2T upper = ktv_h @ F_h^T (bf16) ----------------
__global__ __launch_bounds__(256) void w2u_kernel(
    const float* __restrict__ ktv,
    const float* __restrict__ fw,
    unsigned short* __restrict__ W2T)
{
    const int t = threadIdx.x;
    const int h = blockIdx.x >> 3;
    const int m0 = (blockIdx.x & 7) * 32;

    __shared__ __align__(16) float xlds[16][40];
    __shared__ float wlds[256][17];

    float acc[32];
#pragma unroll
    for (int r = 0; r < 32; ++r) acc[r] = 0.f;

    const int ar = t >> 3;
    const int ak = (t & 7) * 2;
    const int wk = t & 15;
    const int wo = (t >> 4) * 16;

    for (int d0 = 0; d0 < 256; d0 += 16) {
        {
            const float* src = ktv + (size_t)(h * 256 + m0 + ar) * 256 + d0 + ak;
            xlds[ak][ar]     = src[0];
            xlds[ak + 1][ar] = src[1];
        }
#pragma unroll
        for (int j = 0; j < 16; ++j)
            wlds[wo + j][wk] = fw[(size_t)(wo + j) * 2048 + h * 256 + d0 + wk];
        __syncthreads();
#pragma unroll
        for (int kk = 0; kk < 16; ++kk) {
            float bv = wlds[t][kk];
            const float4* xr = (const float4*)(&xlds[kk][0]);
#pragma unroll
            for (int g = 0; g < 8; ++g) {
                float4 xv = xr[g];
                acc[g * 4 + 0] = fmaf(xv.x, bv, acc[g * 4 + 0]);
                acc[g * 4 + 1] = fmaf(xv.y, bv, acc[g * 4 + 1]);
                acc[g * 4 + 2] = fmaf(xv.z, bv, acc[g * 4 + 2]);
                acc[g * 4 + 3] = fmaf(xv.w, bv, acc[g * 4 + 3]);
            }
        }
        __syncthreads();
    }
#pragma unroll
    for (int r = 0; r < 32; ++r)
        W2T[(size_t)t * 4096 + h * 256 + m0 + r] = f2b(acc[r]);
}

// ---------------- epilogue: bias + Lorentz lift ----------------
__global__ __launch_bounds__(256) void lift_kernel(
    const float* __restrict__ bias2, float* __restrict__ outp)
{
    const int t = threadIdx.x;
    const int lane = t & 63;
    const int w = t >> 6;
    const int n0 = blockIdx.x * 64 + w * 16;
    float b[4];
#pragma unroll
    for (int j = 0; j < 4; ++j) b[j] = bias2[lane + j * 64];
    for (int r = 0; r < 16; ++r) {
        float* row = outp + (size_t)(n0 + r) * 257;
        float v[4];
        float s = 0.f;
#pragma unroll
        for (int j = 0; j < 4; ++j) {
            v[j] = row[1 + lane + j * 64] + b[j];
            s = fmaf(v[j], v[j], s);
        }
#pragma unroll
        for (int off = 32; off > 0; off >>= 1) s += __shfl_down(s, off, 64);
#pragma unroll
        for (int j = 0; j < 4; ++j) row[1 + lane + j * 64] = v[j];
        if (lane == 0) row[0] = sqrtf(s + 1.0f);
    }
}

extern "C" void kernel_launch(void* const* d_in, const int* in_sizes, int n_in,
                              void* d_out, int out_size, void* d_ws, size_t ws_size,
                              hipStream_t stream)
{
    const float* xq  = (const float*)d_in[0];
    const float* xs  = (const float*)d_in[1];
    const float* Wq  = (const float*)d_in[2];
    const float* Bq  = (const float*)d_in[3];
    const float* Wk  = (const float*)d_in[4];
    const float* Bk  = (const float*)d_in[5];
    const float* Wv  = (const float*)d_in[6];
    const float* Bv  = (const float*)d_in[7];
    const float* nsc = (const float*)d_in[8];
    const float* vmw = (const float*)d_in[9];
    const float* vmb = (const float*)d_in[10];
    const float* fw  = (const float*)d_in[11];
    const float* fb  = (const float*)d_in[12];
    float* outp = (float*)d_out;

    char* ws = (char*)d_ws;
    float* ktv          = (float*)(ws + 0);                 // 2,097,152
    float* colrep       = (float*)(ws + 2097152);           //    65,536
    float* Mf32         = (float*)(ws + 2162688);           //   294,912
    float* colsum       = (float*)(ws + 2457600);           //     8,192
    float* bias2        = (float*)(ws + 2465792);           //     1,024
    float* biasAll      = (float*)(ws + 2466816);           //    24,576
    unsigned short* W2T = (unsigned short*)(ws + 2491392);  // 2,097,152
    unsigned short* Wbf = (unsigned short*)(ws + 4588544);  // 3,538,944
    float* G32          = (float*)(ws + 8127488);           // 2,097,152
    unsigned short* Mbf = (unsigned short*)(ws + 10224640); //   147,456
    const size_t fixedBytes = 10372096;

    int CH = 2048;
    if (ws_size >= fixedBytes + (size_t)8192 * 8192) CH = 8192;
    else if (ws_size >= fixedBytes + (size_t)4096 * 8192) CH = 4096;
    const int NCHK = 32768 / CH;
    unsigned short* phibuf = (unsigned short*)(ws + fixedBytes);
    unsigned short* vsT    = (unsigned short*)(ws + fixedBytes + (size_t)CH * 4096);

    // zero ktv + colrep + Mf32 (contiguous 614400 floats)
    zero_kernel<<<dim3(2400), 256, 0, stream>>>(ktv, 614400);
    wconv_kernel<<<dim3(6168), 256, 0, stream>>>(Wq, Wk, Wv, Bq, Bk, Bv, Wbf, biasAll);
    w2g_kernel<<<dim3(64), 256, 0, stream>>>(vmw, fw, G32);
    bias2_kernel<<<dim3(256), 256, 0, stream>>>(vmb, fw, fb, Bv, G32, bias2);
    gm_kernel<<<dim3(4, 9, 8), 256, 0, stream>>>(Wv, G32, Mf32);
    gmcvt_kernel<<<dim3(288), 256, 0, stream>>>(Mf32, Mbf);

    // Pass A: merged K/V/xm per chunk, then ktv
    for (int c = 0; c < NCHK; ++c) {
        const float* xs_c = xs + (size_t)c * CH * 257;
        float* out_c = outp + (size_t)c * CH * 257;
        proj_all<<<dim3(CH / 64, 17), 256, 0, stream>>>(
            0, xs_c, Wbf, Mbf, biasAll, phibuf, vsT, out_c,
            nsc, nullptr, colrep, CH);
        ktv_mfma<<<dim3((CH / 512) * 4, 8), 256, 0, stream>>>(phibuf, vsT, ktv, CH);
    }

    // merge colsum replicas; ktv-dependent weights
    merge_colsum<<<dim3(8), 256, 0, stream>>>(colrep, colsum);
    w2u_kernel<<<dim3(64), 256, 0, stream>>>(ktv, fw, W2T);

    // Pass B: Q proj (dbuf) + final (dbuf, split-K 4)
    for (int c = 0; c < NCHK; ++c) {
        const float* xq_c = xq + (size_t)c * CH * 257;
        float* out_c = outp + (size_t)c * CH * 257;
        proj_all<<<dim3(CH / 64, 8), 256, 0, stream>>>(
            1, xq_c, Wbf, Mbf, biasAll, phibuf, vsT, out_c,
            nsc, colsum, nullptr, CH);
        final_mfma<<<dim3(CH / 128, 4, 4), 256, 0, stream>>>(phibuf, W2T, 0, 2048, out_c);
    }

    // bias + Lorentz lift
    lift_kernel<<<dim3(512), 256, 0, stream>>>(bias2, outp);
}

// Round 8
// 1055.050 us; speedup vs baseline: 1.2152x; 1.1052x over previous
//
#include <hip/hip_runtime.h>
#include <hip/hip_bf16.h>

// DHHT round 15: R12 base + TILED transposed layouts (HBM locality fix).
//  - Diagnosis: phiT/vsT [2048][CH] col-major writes = 128-B chunks at 16-KB
//    stride -> ~0.5 TB/s effective HBM write BW -> the stubborn ~60us floor
//    on proj kernels (R12 proj_phi: 33MB writes, 727 GB/s agg). ktv reads had
//    the same pattern (1.5 TB/s, R11).
//  - phiT/vsT now tiled [CH/64][2048][64]: producers write contiguous 32-KB
//    runs per block; ktv reads contiguous 4-KB runs. Same bytes, sequential.
//  - Q-mode phi output routed through padded LDS transpose -> 512-B
//    contiguous row-major stores (was per-lane 2-B scatter).
//  - Everything else identical to round 12 (1045us verified).
// W2T bf16 [256][4096]: cols 0..2047 = W2u (ktv@F^T). G lives in G32 (f32).

#define EPSF 1e-6f

typedef __attribute__((ext_vector_type(8))) short bf16x8;
typedef __attribute__((ext_vector_type(8))) unsigned short u16x8;
typedef __attribute__((ext_vector_type(4))) float f32x4;
typedef float f32x4a __attribute__((ext_vector_type(4), aligned(4)));

#define STRIPE 131072  // 2048 cols * 64 n (u16 elements) = 256 KB per stripe

__device__ __forceinline__ float b2f(unsigned short u) {
    union { unsigned int i; float f; } c;
    c.i = ((unsigned int)u) << 16;
    return c.f;
}
__device__ __forceinline__ unsigned short f2b(float f) {
    __hip_bfloat16 h = __float2bfloat16(f);
    union { __hip_bfloat16 h; unsigned short u; } c;
    c.h = h;
    return c.u;
}

__global__ void zero_kernel(float* __restrict__ p, int n) {
    int i = blockIdx.x * 256 + threadIdx.x;
    if (i < n) p[i] = 0.f;
}

// ---------------- weight convert: Wbf [6144][288] bf16 + biasAll[6144] ----------------
__global__ __launch_bounds__(256) void wconv_kernel(
    const float* __restrict__ Wq, const float* __restrict__ Wk, const float* __restrict__ Wv,
    const float* __restrict__ Bq, const float* __restrict__ Bk, const float* __restrict__ Bv,
    unsigned short* __restrict__ Wbf, float* __restrict__ biasAll)
{
    const int t = threadIdx.x;
    const int b = blockIdx.x;
    if (b < 6144) {
        const int mat = b >> 11, lr = b & 2047;
        const float* Ws = (mat == 0 ? Wq : mat == 1 ? Wk : Wv) + (size_t)lr * 257;
        Wbf[(size_t)b * 288 + t] = f2b(Ws[t]);
        if (t < 32) {
            float v = (t == 0) ? Ws[256] : 0.f;
            Wbf[(size_t)b * 288 + 256 + t] = f2b(v);
        }
    } else {
        const int e = (b - 6144) * 256 + t;
        const int mat = e >> 11, r = e & 2047;
        biasAll[e] = (mat == 0 ? Bq : mat == 1 ? Bk : Bv)[r];
    }
}

// ---------------- G32[o][hk] ----------------
__global__ __launch_bounds__(256) void w2g_kernel(
    const float* __restrict__ vmw,
    const float* __restrict__ fw,
    float* __restrict__ G32)
{
    const int t = threadIdx.x;
    const int h = blockIdx.x >> 3;
    const int i0 = (blockIdx.x & 7) * 32;

    __shared__ __align__(16) float xlds[16][40];
    __shared__ float wlds[256][17];

    float acc[32];
#pragma unroll
    for (int r = 0; r < 32; ++r) acc[r] = 0.f;

    const int ar = t >> 3;
    const int ak = (t & 7) * 2;
    const int wk = t & 15;
    const int wo = (t >> 4) * 16;

    for (int d0 = 0; d0 < 256; d0 += 16) {
        xlds[ak][ar]     = vmw[(size_t)(d0 + ak) * 256 + i0 + ar];
        xlds[ak + 1][ar] = vmw[(size_t)(d0 + ak + 1) * 256 + i0 + ar];
#pragma unroll
        for (int j = 0; j < 16; ++j)
            wlds[wo + j][wk] = fw[(size_t)(wo + j) * 2048 + h * 256 + d0 + wk];
        __syncthreads();
#pragma unroll
        for (int kk = 0; kk < 16; ++kk) {
            float bv = wlds[t][kk];
            const float4* xr = (const float4*)(&xlds[kk][0]);
#pragma unroll
            for (int g = 0; g < 8; ++g) {
                float4 xv = xr[g];
                acc[g * 4 + 0] = fmaf(xv.x, bv, acc[g * 4 + 0]);
                acc[g * 4 + 1] = fmaf(xv.y, bv, acc[g * 4 + 1]);
                acc[g * 4 + 2] = fmaf(xv.z, bv, acc[g * 4 + 2]);
                acc[g * 4 + 3] = fmaf(xv.w, bv, acc[g * 4 + 3]);
            }
        }
        __syncthreads();
    }
#pragma unroll
    for (int r = 0; r < 32; ++r)
        G32[(size_t)t * 2048 + h * 256 + i0 + r] = acc[r];
}

// ---------------- bias2 ----------------
__global__ __launch_bounds__(256) void bias2_kernel(
    const float* __restrict__ vmb, const float* __restrict__ fw,
    const float* __restrict__ fb, const float* __restrict__ Bv,
    const float* __restrict__ G32, float* __restrict__ bias2)
{
    const int o = blockIdx.x;
    const int t = threadIdx.x;
    float s = 0.f, sb = 0.f;
#pragma unroll
    for (int i = 0; i < 8; ++i) {
        const int j = t + i * 256;
        s += fw[(size_t)o * 2048 + j];
        sb += Bv[j] * G32[(size_t)o * 2048 + j];
    }
    s = s * vmb[t] + sb;
#pragma unroll
    for (int off = 32; off > 0; off >>= 1) s += __shfl_down(s, off, 64);
    __shared__ float r4[4];
    if ((t & 63) == 0) r4[t >> 6] = s;
    __syncthreads();
    if (t == 0) bias2[o] = fb[o] + r4[0] + r4[1] + r4[2] + r4[3];
}

// ---------------- Mf32[o][i] += sum_k G32[o][k] Wv[k][i] ----------------
__global__ __launch_bounds__(256) void gm_kernel(
    const float* __restrict__ Wv, const float* __restrict__ G32,
    float* __restrict__ Mf32)
{
    __shared__ float Gt[64][33];
    __shared__ float Wt[32][33];
    const int t = threadIdx.x;
    const int o0 = blockIdx.x * 64, i0 = blockIdx.y * 32, k0 = blockIdx.z * 256;
    const int ii = t & 31, og = t >> 5;
    float acc[8] = {};
    for (int kk0 = k0; kk0 < k0 + 256; kk0 += 32) {
#pragma unroll
        for (int r = 0; r < 8; ++r) {
            const int e = t + r * 256;
            Gt[e >> 5][e & 31] = G32[(size_t)(o0 + (e >> 5)) * 2048 + kk0 + (e & 31)];
        }
#pragma unroll
        for (int r = 0; r < 4; ++r) {
            const int e = t + r * 256;
            const int kk = e >> 5, i = i0 + (e & 31);
            Wt[kk][e & 31] = (i < 257) ? Wv[(size_t)(kk0 + kk) * 257 + i] : 0.f;
        }
        __syncthreads();
#pragma unroll
        for (int kk = 0; kk < 32; ++kk) {
            float wv_ = Wt[kk][ii];
#pragma unroll
            for (int r = 0; r < 8; ++r)
                acc[r] = fmaf(Gt[og * 8 + r][kk], wv_, acc[r]);
        }
        __syncthreads();
    }
#pragma unroll
    for (int r = 0; r < 8; ++r)
        atomicAdd(&Mf32[(size_t)(o0 + og * 8 + r) * 288 + i0 + ii], acc[r]);
}

__global__ void gmcvt_kernel(const float* __restrict__ Mf32, unsigned short* __restrict__ Mbf) {
    const int i = blockIdx.x * 256 + threadIdx.x;
    Mbf[i] = f2b(Mf32[i]);
}

// ---------------- projection (V): writes vsT (tiled) ----------------
__global__ __launch_bounds__(256) void proj_mfma(
    const float* __restrict__ X,
    const unsigned short* __restrict__ Wbase,
    const float* __restrict__ biasBase,
    unsigned short* __restrict__ outT,    // tiled [CH/64][2048][64]
    int CH)
{
    __shared__ __align__(16) unsigned short smem[10240];
    __shared__ float rowx[128];
    unsigned short* lA = smem;
    unsigned short* lB = smem + 128 * 40;
    const int t = threadIdx.x;
    const int m0 = blockIdx.x * 128;
    const int c0 = blockIdx.y * 128;
    const int lane = t & 63, w = t >> 6;
    const int wm = (w >> 1) * 64, wn = (w & 1) * 64;
    const int l15 = lane & 15, q = lane >> 4;
    const int ar = t >> 2, akg = (t & 3) * 8;

    f32x4 acc[4][4] = {};
    const float* XA = X + (size_t)(m0 + ar) * 257 + akg;
    const unsigned short* WB = Wbase + (size_t)(c0 + ar) * 288 + akg;

    f32x4a cx[2][2];
    u16x8 cw[2];
#pragma unroll
    for (int qq = 0; qq < 2; ++qq) {
        cx[qq][0] = *(const f32x4a*)(XA + (size_t)qq * 64 * 257);
        cx[qq][1] = *(const f32x4a*)(XA + (size_t)qq * 64 * 257 + 4);
        cw[qq]    = *(const u16x8*)(WB + (size_t)qq * 64 * 288);
    }

    for (int ks = 0; ks < 8; ++ks) {
#pragma unroll
        for (int qq = 0; qq < 2; ++qq) {
            u16x8 pk;
            pk[0] = f2b(cx[qq][0][0]); pk[1] = f2b(cx[qq][0][1]);
            pk[2] = f2b(cx[qq][0][2]); pk[3] = f2b(cx[qq][0][3]);
            pk[4] = f2b(cx[qq][1][0]); pk[5] = f2b(cx[qq][1][1]);
            pk[6] = f2b(cx[qq][1][2]); pk[7] = f2b(cx[qq][1][3]);
            *(u16x8*)(&lA[(ar + qq * 64) * 40 + akg]) = pk;
            *(u16x8*)(&lB[(ar + qq * 64) * 40 + akg]) = cw[qq];
        }
        if (ks < 7) {
            const int k1 = (ks + 1) * 32;
#pragma unroll
            for (int qq = 0; qq < 2; ++qq) {
                cx[qq][0] = *(const f32x4a*)(XA + (size_t)qq * 64 * 257 + k1);
                cx[qq][1] = *(const f32x4a*)(XA + (size_t)qq * 64 * 257 + k1 + 4);
                cw[qq]    = *(const u16x8*)(WB + (size_t)qq * 64 * 288 + k1);
            }
        }
        __syncthreads();
        bf16x8 af[4], bfr[4];
#pragma unroll
        for (int i = 0; i < 4; ++i)
            af[i] = *(const bf16x8*)(&lA[(wm + i * 16 + l15) * 40 + q * 8]);
#pragma unroll
        for (int j = 0; j < 4; ++j)
            bfr[j] = *(const bf16x8*)(&lB[(wn + j * 16 + l15) * 40 + q * 8]);
#pragma unroll
        for (int i = 0; i < 4; ++i)
#pragma unroll
            for (int j = 0; j < 4; ++j)
                acc[i][j] = __builtin_amdgcn_mfma_f32_16x16x32_bf16(af[i], bfr[j], acc[i][j], 0, 0, 0);
        __syncthreads();
    }

    if (t < 128) rowx[t] = b2f(f2b(X[(size_t)(m0 + t) * 257 + 256]));
    __syncthreads();

    // rank-1 Lorentz column + bias
#pragma unroll
    for (int j = 0; j < 4; ++j) {
        const int cg = c0 + wn + j * 16 + l15;
        const float w256 = b2f(Wbase[(size_t)cg * 288 + 256]);
        const float bias = biasBase[cg];
#pragma unroll
        for (int i = 0; i < 4; ++i)
#pragma unroll
            for (int r = 0; r < 4; ++r)
                acc[i][j][r] += rowx[wm + i * 16 + q * 4 + r] * w256 + bias;
    }

    // tiled transposed store: two 64-row stripes, contiguous 16-KB runs
#pragma unroll
    for (int p = 0; p < 2; ++p) {
        __syncthreads();
        if ((w >> 1) == p) {
#pragma unroll
            for (int i = 0; i < 4; ++i)
#pragma unroll
                for (int j = 0; j < 4; ++j) {
                    const int cl = wn + j * 16 + l15;
#pragma unroll
                    for (int r2 = 0; r2 < 4; r2 += 2) {
                        const int nl = i * 16 + q * 4 + r2;
                        const unsigned int pk =
                            (unsigned int)f2b(acc[i][j][r2]) |
                            ((unsigned int)f2b(acc[i][j][r2 + 1]) << 16);
                        *(unsigned int*)(&smem[cl * 64 + (((nl >> 3) ^ (cl & 7)) << 3) + (nl & 7)]) = pk;
                    }
                }
        }
        __syncthreads();
#pragma unroll
        for (int k = 0; k < 4; ++k) {
            const int task = k * 256 + t;
            const int cl = task >> 3, nq = task & 7;
            *(u16x8*)(outT + (size_t)(blockIdx.x * 2 + p) * STRIPE +
                      (size_t)(c0 + cl) * 64 + nq * 8) =
                *(const u16x8*)(&smem[cl * 64 + ((nq ^ (cl & 7)) << 3)]);
        }
    }
}

// ---------------- xm: out[n][1+o] = Xs@M (f32 out) ----------------
__global__ __launch_bounds__(256) void xm_mfma(
    const float* __restrict__ X,
    const unsigned short* __restrict__ Mbf,
    float* __restrict__ outp)
{
    __shared__ __align__(16) unsigned short smem[10240];
    __shared__ float rowx[128];
    unsigned short* lA = smem;
    unsigned short* lB = smem + 128 * 40;
    const int t = threadIdx.x;
    const int m0 = blockIdx.x * 128;
    const int c0 = blockIdx.y * 128;
    const int lane = t & 63, w = t >> 6;
    const int wm = (w >> 1) * 64, wn = (w & 1) * 64;
    const int l15 = lane & 15, q = lane >> 4;
    const int ar = t >> 2, akg = (t & 3) * 8;

    f32x4 acc[4][4] = {};
    const float* XA = X + (size_t)(m0 + ar) * 257 + akg;
    const unsigned short* WB = Mbf + (size_t)(c0 + ar) * 288 + akg;

    f32x4a cx[2][2];
    u16x8 cw[2];
#pragma unroll
    for (int qq = 0; qq < 2; ++qq) {
        cx[qq][0] = *(const f32x4a*)(XA + (size_t)qq * 64 * 257);
        cx[qq][1] = *(const f32x4a*)(XA + (size_t)qq * 64 * 257 + 4);
        cw[qq]    = *(const u16x8*)(WB + (size_t)qq * 64 * 288);
    }

    for (int ks = 0; ks < 8; ++ks) {
#pragma unroll
        for (int qq = 0; qq < 2; ++qq) {
            u16x8 pk;
            pk[0] = f2b(cx[qq][0][0]); pk[1] = f2b(cx[qq][0][1]);
            pk[2] = f2b(cx[qq][0][2]); pk[3] = f2b(cx[qq][0][3]);
            pk[4] = f2b(cx[qq][1][0]); pk[5] = f2b(cx[qq][1][1]);
            pk[6] = f2b(cx[qq][1][2]); pk[7] = f2b(cx[qq][1][3]);
            *(u16x8*)(&lA[(ar + qq * 64) * 40 + akg]) = pk;
            *(u16x8*)(&lB[(ar + qq * 64) * 40 + akg]) = cw[qq];
        }
        if (ks < 7) {
            const int k1 = (ks + 1) * 32;
#pragma unroll
            for (int qq = 0; qq < 2; ++qq) {
                cx[qq][0] = *(const f32x4a*)(XA + (size_t)qq * 64 * 257 + k1);
                cx[qq][1] = *(const f32x4a*)(XA + (size_t)qq * 64 * 257 + k1 + 4);
                cw[qq]    = *(const u16x8*)(WB + (size_t)qq * 64 * 288 + k1);
            }
        }
        __syncthreads();
        bf16x8 af[4], bfr[4];
#pragma unroll
        for (int i = 0; i < 4; ++i)
            af[i] = *(const bf16x8*)(&lA[(wm + i * 16 + l15) * 40 + q * 8]);
#pragma unroll
        for (int j = 0; j < 4; ++j)
            bfr[j] = *(const bf16x8*)(&lB[(wn + j * 16 + l15) * 40 + q * 8]);
#pragma unroll
        for (int i = 0; i < 4; ++i)
#pragma unroll
            for (int j = 0; j < 4; ++j)
                acc[i][j] = __builtin_amdgcn_mfma_f32_16x16x32_bf16(af[i], bfr[j], acc[i][j], 0, 0, 0);
        __syncthreads();
    }

    if (t < 128) rowx[t] = b2f(f2b(X[(size_t)(m0 + t) * 257 + 256]));
    __syncthreads();

#pragma unroll
    for (int j = 0; j < 4; ++j) {
        const int cg = c0 + wn + j * 16 + l15;
        const float w256 = b2f(Mbf[(size_t)cg * 288 + 256]);
#pragma unroll
        for (int i = 0; i < 4; ++i)
#pragma unroll
            for (int r = 0; r < 4; ++r) {
                const int n = m0 + wm + i * 16 + q * 4 + r;
                outp[(size_t)n * 257 + 1 + cg] =
                    acc[i][j][r] + rowx[wm + i * 16 + q * 4 + r] * w256;
            }
    }
}

// ---------------- projection + fused phi (one head / block) ----------------
// mode 0 (K): write phi TILED-TRANSPOSED + colsum replica atomics.
// mode 1 (Q): write phi * invden row-major via LDS transpose (coalesced).
__global__ __launch_bounds__(256) void proj_phi(
    const float* __restrict__ X,
    const unsigned short* __restrict__ Wbase,
    const float* __restrict__ biasBase,
    unsigned short* __restrict__ outbuf,
    const float* __restrict__ nsc,
    const float* __restrict__ colsum_in,
    float* __restrict__ colsum_rep,
    int mode, int CH)
{
    __shared__ __align__(16) unsigned short smem[16896]; // staging 12800; K-tstore 16384; Q [64][264]=16896
    __shared__ float reds2[4][64];
    __shared__ float reds4[4][64];
    __shared__ float rowv[64];
    __shared__ float rowx[64];
    unsigned short* lA = smem;
    unsigned short* lB = smem + 64 * 40;

    const int t = threadIdx.x;
    const int m0 = blockIdx.x * 64;
    const int h  = blockIdx.y;
    const int lane = t & 63, w = t >> 6;
    const int wn = w * 64;
    const int l15 = lane & 15, q = lane >> 4;
    const int ar = t >> 2, akg = (t & 3) * 8;

    f32x4 acc[4][4] = {};
    const float* XA = X + (size_t)(m0 + ar) * 257 + akg;
    const unsigned short* WB = Wbase + (size_t)(h * 256 + ar) * 288 + akg;

    f32x4a cx0, cx1;
    u16x8 cw[4];
    cx0 = *(const f32x4a*)(XA);
    cx1 = *(const f32x4a*)(XA + 4);
#pragma unroll
    for (int qq = 0; qq < 4; ++qq)
        cw[qq] = *(const u16x8*)(WB + (size_t)qq * 64 * 288);

    for (int ks = 0; ks < 8; ++ks) {
        {
            u16x8 pk;
            pk[0] = f2b(cx0[0]); pk[1] = f2b(cx0[1]);
            pk[2] = f2b(cx0[2]); pk[3] = f2b(cx0[3]);
            pk[4] = f2b(cx1[0]); pk[5] = f2b(cx1[1]);
            pk[6] = f2b(cx1[2]); pk[7] = f2b(cx1[3]);
            *(u16x8*)(&lA[ar * 40 + akg]) = pk;
        }
#pragma unroll
        for (int qq = 0; qq < 4; ++qq)
            *(u16x8*)(&lB[(ar + qq * 64) * 40 + akg]) = cw[qq];
        if (ks < 7) {
            const int k1 = (ks + 1) * 32;
            cx0 = *(const f32x4a*)(XA + k1);
            cx1 = *(const f32x4a*)(XA + k1 + 4);
#pragma unroll
            for (int qq = 0; qq < 4; ++qq)
                cw[qq] = *(const u16x8*)(WB + (size_t)qq * 64 * 288 + k1);
        }
        __syncthreads();
        bf16x8 af[4], bfr[4];
#pragma unroll
        for (int i = 0; i < 4; ++i)
            af[i] = *(const bf16x8*)(&lA[(i * 16 + l15) * 40 + q * 8]);
#pragma unroll
        for (int j = 0; j < 4; ++j)
            bfr[j] = *(const bf16x8*)(&lB[(wn + j * 16 + l15) * 40 + q * 8]);
#pragma unroll
        for (int i = 0; i < 4; ++i)
#pragma unroll
            for (int j = 0; j < 4; ++j)
                acc[i][j] = __builtin_amdgcn_mfma_f32_16x16x32_bf16(af[i], bfr[j], acc[i][j], 0, 0, 0);
        __syncthreads();
    }

    if (t < 64) rowx[t] = b2f(f2b(X[(size_t)(m0 + t) * 257 + 256]));
    __syncthreads();

    // rank-1 Lorentz column
    {
        float w256[4];
#pragma unroll
        for (int j = 0; j < 4; ++j)
            w256[j] = b2f(Wbase[(size_t)(h * 256 + wn + j * 16 + l15) * 288 + 256]);
#pragma unroll
        for (int i = 0; i < 4; ++i)
#pragma unroll
            for (int r = 0; r < 4; ++r) {
                const float xv = rowx[i * 16 + q * 4 + r];
#pragma unroll
                for (int j = 0; j < 4; ++j)
                    acc[i][j][r] += xv * w256[j];
            }
    }

    // ---- fused phi epilogue ----
    const float c = fabsf(nsc[0]) + EPSF;
    float bias[4];
#pragma unroll
    for (int j = 0; j < 4; ++j) bias[j] = biasBase[h * 256 + wn + j * 16 + l15];

    float a2[4][4], a4[4][4];
#pragma unroll
    for (int i = 0; i < 4; ++i)
#pragma unroll
        for (int r = 0; r < 4; ++r) { a2[i][r] = 0.f; a4[i][r] = 0.f; }
#pragma unroll
    for (int i = 0; i < 4; ++i)
#pragma unroll
        for (int j = 0; j < 4; ++j)
#pragma unroll
            for (int r = 0; r < 4; ++r) {
                float uu = fmaxf(acc[i][j][r] + bias[j], 0.f) + EPSF;
                float q2 = uu * uu;
                acc[i][j][r] = q2;
                a2[i][r] += q2;
                a4[i][r] += q2 * q2;
            }
#pragma unroll
    for (int m = 1; m <= 8; m <<= 1) {
#pragma unroll
        for (int i = 0; i < 4; ++i)
#pragma unroll
            for (int r = 0; r < 4; ++r) {
                a2[i][r] += __shfl_xor(a2[i][r], m, 64);
                a4[i][r] += __shfl_xor(a4[i][r], m, 64);
            }
    }
    if (l15 == 0) {
#pragma unroll
        for (int i = 0; i < 4; ++i)
#pragma unroll
            for (int r = 0; r < 4; ++r) {
                reds2[w][i * 16 + q * 4 + r] = a2[i][r];
                reds4[w][i * 16 + q * 4 + r] = a4[i][r];
            }
    }
    __syncthreads();
    if (t < 64) {
        float s2t = reds2[0][t] + reds2[1][t] + reds2[2][t] + reds2[3][t];
        float s4t = reds4[0][t] + reds4[1][t] + reds4[2][t] + reds4[3][t];
        rowv[t] = sqrtf(s2t) / (c * sqrtf(s4t));
    }
    __syncthreads();
    float sc_[4][4];
#pragma unroll
    for (int i = 0; i < 4; ++i)
#pragma unroll
        for (int r = 0; r < 4; ++r) sc_[i][r] = rowv[i * 16 + q * 4 + r];

    if (mode == 0) {
        float colp[4];
#pragma unroll
        for (int j = 0; j < 4; ++j) colp[j] = 0.f;
#pragma unroll
        for (int i = 0; i < 4; ++i)
#pragma unroll
            for (int j = 0; j < 4; ++j)
#pragma unroll
                for (int r = 0; r < 4; ++r) {
                    float ph = acc[i][j][r] * sc_[i][r];
                    acc[i][j][r] = ph;
                    colp[j] += ph;
                }
        // tiled transposed store: contiguous 32-KB run for this block
#pragma unroll
        for (int i = 0; i < 4; ++i)
#pragma unroll
            for (int j = 0; j < 4; ++j) {
                const int cl = wn + j * 16 + l15;
#pragma unroll
                for (int r2 = 0; r2 < 4; r2 += 2) {
                    const int nl = i * 16 + q * 4 + r2;
                    const unsigned int pk =
                        (unsigned int)f2b(acc[i][j][r2]) |
                        ((unsigned int)f2b(acc[i][j][r2 + 1]) << 16);
                    *(unsigned int*)(&smem[cl * 64 + (((nl >> 3) ^ (cl & 7)) << 3) + (nl & 7)]) = pk;
                }
            }
        __syncthreads();
#pragma unroll
        for (int k = 0; k < 8; ++k) {
            const int task = k * 256 + t;
            const int cl = task >> 3, nq = task & 7;
            *(u16x8*)(outbuf + (size_t)blockIdx.x * STRIPE +
                      (size_t)(h * 256 + cl) * 64 + nq * 8) =
                *(const u16x8*)(&smem[cl * 64 + ((nq ^ (cl & 7)) << 3)]);
        }
        // colsum replicas
#pragma unroll
        for (int j = 0; j < 4; ++j) {
            colp[j] += __shfl_xor(colp[j], 16, 64);
            colp[j] += __shfl_xor(colp[j], 32, 64);
        }
        if (q == 0) {
            float* dst = colsum_rep + (size_t)(blockIdx.x & 7) * 2048;
#pragma unroll
            for (int j = 0; j < 4; ++j)
                atomicAdd(&dst[h * 256 + wn + j * 16 + l15], colp[j]);
        }
    } else {
        float cs[4];
#pragma unroll
        for (int j = 0; j < 4; ++j) cs[j] = colsum_in[h * 256 + wn + j * 16 + l15];
        float dp[4][4];
#pragma unroll
        for (int i = 0; i < 4; ++i)
#pragma unroll
            for (int r = 0; r < 4; ++r) dp[i][r] = 0.f;
#pragma unroll
        for (int i = 0; i < 4; ++i)
#pragma unroll
            for (int j = 0; j < 4; ++j)
#pragma unroll
                for (int r = 0; r < 4; ++r) {
                    float ph = acc[i][j][r] * sc_[i][r];
                    acc[i][j][r] = ph;
                    dp[i][r] += ph * cs[j];
                }
#pragma unroll
        for (int m = 1; m <= 8; m <<= 1) {
#pragma unroll
            for (int i = 0; i < 4; ++i)
#pragma unroll
                for (int r = 0; r < 4; ++r)
                    dp[i][r] += __shfl_xor(dp[i][r], m, 64);
        }
        if (l15 == 0) {
#pragma unroll
            for (int i = 0; i < 4; ++i)
#pragma unroll
                for (int r = 0; r < 4; ++r)
                    reds2[w][i * 16 + q * 4 + r] = dp[i][r];
        }
        __syncthreads();
        if (t < 64) {
            float dt = reds2[0][t] + reds2[1][t] + reds2[2][t] + reds2[3][t];
            rowv[t] = 1.f / (dt + EPSF);
        }
        __syncthreads();
#pragma unroll
        for (int i = 0; i < 4; ++i)
#pragma unroll
            for (int r = 0; r < 4; ++r) sc_[i][r] = rowv[i * 16 + q * 4 + r];
        // LDS transpose -> coalesced row-major store (512-B runs per row)
#pragma unroll
        for (int i = 0; i < 4; ++i)
#pragma unroll
            for (int j = 0; j < 4; ++j) {
                const int cl = wn + j * 16 + l15;
#pragma unroll
                for (int r = 0; r < 4; ++r) {
                    const int nl = i * 16 + q * 4 + r;
                    smem[nl * 264 + cl] = f2b(acc[i][j][r] * sc_[i][r]);
                }
            }
        __syncthreads();
#pragma unroll
        for (int k = 0; k < 8; ++k) {
            const int task = k * 256 + t;
            const int rowl = task >> 5, ck = (task & 31) * 8;
            *(u16x8*)(outbuf + (size_t)(m0 + rowl) * 2048 + h * 256 + ck) =
                *(const u16x8*)(&smem[rowl * 264 + ck]);
        }
    }
}

// ---------------- merge colsum replicas ----------------
__global__ __launch_bounds__(256) void merge_colsum(
    const float* __restrict__ rep, float* __restrict__ out)
{
    const int cidx = blockIdx.x * 256 + threadIdx.x;
    float s = 0.f;
#pragma unroll
    for (int r = 0; r < 8; ++r) s += rep[(size_t)r * 2048 + cidx];
    out[cidx] = s;
}

// ---------------- ktv MFMA: tiled reads (contiguous 4-KB runs) ----------------
__global__ __launch_bounds__(256) void ktv_mfma(
    const unsigned short* __restrict__ phiT,   // tiled [CH/64][2048][64]
    const unsigned short* __restrict__ vsT,
    float* __restrict__ ktv, int CH)
{
    __shared__ __align__(16) unsigned short lAT[128 * 64];
    __shared__ __align__(16) unsigned short lBT[128 * 64];
    const int t = threadIdx.x;
    const int h = blockIdx.y;
    const int split = blockIdx.x >> 2;
    const int tile = blockIdx.x & 3;
    const int m0 = (tile >> 1) * 128, d0 = (tile & 1) * 128;
    const int chh = h * 256;
    const int lane = t & 63, w = t >> 6;
    const int wm = (w >> 1) * 64, wn = (w & 1) * 64;
    const int l15 = lane & 15, q = lane >> 4;
    const int sl7 = l15 & 7;

    const int scg  = t >> 3;
    const int snq  = t & 7;
    const int sbase = scg * 64 + ((snq ^ (scg & 7)) << 3);

    f32x4 acc[4][4] = {};
    const int st0 = split * 8;   // first n-stripe index

    const unsigned short* pA = phiT + (size_t)(chh + m0 + scg) * 64 + snq * 8;
    const unsigned short* pB = vsT  + (size_t)(chh + d0 + scg) * 64 + snq * 8;

    u16x8 cA[4], cB[4], nA[4], nB[4];
#pragma unroll
    for (int k = 0; k < 4; ++k) {
        cA[k] = *(const u16x8*)(pA + (size_t)st0 * STRIPE + k * 2048);
        cB[k] = *(const u16x8*)(pB + (size_t)st0 * STRIPE + k * 2048);
    }

    for (int it = 0; it < 8; ++it) {
#pragma unroll
        for (int k = 0; k < 4; ++k) {
            *(u16x8*)(&lAT[k * 2048 + sbase]) = cA[k];
            *(u16x8*)(&lBT[k * 2048 + sbase]) = cB[k];
        }
        if (it < 7) {
            const size_t so = (size_t)(st0 + it + 1) * STRIPE;
#pragma unroll
            for (int k = 0; k < 4; ++k) {
                nA[k] = *(const u16x8*)(pA + so + k * 2048);
                nB[k] = *(const u16x8*)(pB + so + k * 2048);
            }
        }
        __syncthreads();
#pragma unroll
        for (int sub = 0; sub < 2; ++sub) {
            const int slot = ((sub * 4 + q) ^ sl7) << 3;
            bf16x8 af[4], bfr[4];
#pragma unroll
            for (int i = 0; i < 4; ++i)
                af[i] = *(const bf16x8*)(&lAT[(wm + i * 16 + l15) * 64 + slot]);
#pragma unroll
            for (int j = 0; j < 4; ++j)
                bfr[j] = *(const bf16x8*)(&lBT[(wn + j * 16 + l15) * 64 + slot]);
#pragma unroll
            for (int i = 0; i < 4; ++i)
#pragma unroll
                for (int j = 0; j < 4; ++j)
                    acc[i][j] = __builtin_amdgcn_mfma_f32_16x16x32_bf16(af[i], bfr[j], acc[i][j], 0, 0, 0);
        }
        __syncthreads();
        if (it < 7) {
#pragma unroll
            for (int k = 0; k < 4; ++k) { cA[k] = nA[k]; cB[k] = nB[k]; }
        }
    }
#pragma unroll
    for (int i = 0; i < 4; ++i)
#pragma unroll
        for (int j = 0; j < 4; ++j)
#pragma unroll
            for (int r = 0; r < 4; ++r) {
                const int m = m0 + wm + i * 16 + q * 4 + r;
                const int d = d0 + wn + j * 16 + l15;
                atomicAdd(&ktv[((size_t)chh + m) * 256 + d], acc[i][j][r]);
            }
}

// ---------------- final staging load ----------------
__device__ __forceinline__ void fin_load(
    const unsigned short* __restrict__ Abuf, const unsigned short* __restrict__ W2T,
    int n0, int d0, int t, int k0,
    u16x8& A0, u16x8& A1, u16x8& B)
{
    {
        const int row = t >> 2, kg = (t & 3) * 8;
        A0 = *(const u16x8*)(Abuf + (size_t)(n0 + row) * 2048 + ((k0 + kg) & 2047));
    }
    {
        const int e = t + 256;
        const int row = e >> 2, kg = (e & 3) * 8;
        A1 = *(const u16x8*)(Abuf + (size_t)(n0 + row) * 2048 + ((k0 + kg) & 2047));
    }
    {
        const int row = t >> 2, kg = (t & 3) * 8;
        B = *(const u16x8*)(W2T + (size_t)(d0 + row) * 4096 + k0 + kg);
    }
}

// ---------------- final MFMA GEMM 128x64 (reg-prefetch, split-K x2, atomic) ----------------
__global__ __launch_bounds__(256) void final_mfma(
    const unsigned short* __restrict__ Abuf,
    const unsigned short* __restrict__ W2T,
    int kbeg, int kend,
    float* __restrict__ outp)
{
    __shared__ __align__(16) unsigned short lA[128 * 40];
    __shared__ __align__(16) unsigned short lB[64 * 40];
    const int t = threadIdx.x;
    const int n0 = blockIdx.x * 128;
    const int d0 = blockIdx.y * 64;
    const int khalf = (kend - kbeg) >> 1;
    const int kb = kbeg + blockIdx.z * khalf;
    const int ke = kb + khalf;
    const int lane = t & 63, w = t >> 6;
    const int wm = w * 32;
    const int l15 = lane & 15, q = lane >> 4;

    f32x4 acc[2][4] = {};
    u16x8 cA0, cA1, cB, nA0, nA1, nB;
    fin_load(Abuf, W2T, n0, d0, t, kb, cA0, cA1, cB);

    for (int k0 = kb; k0 < ke; k0 += 32) {
        {
            const int row = t >> 2, kg = (t & 3) * 8;
            *(u16x8*)(&lA[row * 40 + kg]) = cA0;
            *(u16x8*)(&lB[row * 40 + kg]) = cB;
        }
        {
            const int e = t + 256;
            const int row = e >> 2, kg = (e & 3) * 8;
            *(u16x8*)(&lA[row * 40 + kg]) = cA1;
        }
        if (k0 + 32 < ke)
            fin_load(Abuf, W2T, n0, d0, t, k0 + 32, nA0, nA1, nB);
        __syncthreads();
        bf16x8 af[2], bfr[4];
#pragma unroll
        for (int i = 0; i < 2; ++i)
            af[i] = *(const bf16x8*)(&lA[(wm + i * 16 + l15) * 40 + q * 8]);
#pragma unroll
        for (int j = 0; j < 4; ++j)
            bfr[j] = *(const bf16x8*)(&lB[(j * 16 + l15) * 40 + q * 8]);
#pragma unroll
        for (int i = 0; i < 2; ++i)
#pragma unroll
            for (int j = 0; j < 4; ++j)
                acc[i][j] = __builtin_amdgcn_mfma_f32_16x16x32_bf16(af[i], bfr[j], acc[i][j], 0, 0, 0);
        __syncthreads();
        if (k0 + 32 < ke) { cA0 = nA0; cA1 = nA1; cB = nB; }
    }
#pragma unroll
    for (int i = 0; i < 2; ++i)
#pragma unroll
        for (int j = 0; j < 4; ++j)
#pragma unroll
            for (int r = 0; r < 4; ++r) {
                const int n = n0 + wm + i * 16 + q * 4 + r;
                const int d = d0 + j * 16 + l15;
                atomicAdd(&outp[(size_t)n * 257 + 1 + d], acc[i][j][r]);
            }
}

// ---------------- W2T upper = ktv_h @ F_h^T (bf16) ----------------
__global__ __launch_bounds__(256) void w2u_kernel(
    const float* __restrict__ ktv,
    const float* __restrict__ fw,
    unsigned short* __restrict__ W2T)
{
    const int t = threadIdx.x;
    const int h = blockIdx.x >> 3;
    const int m0 = (blockIdx.x & 7) * 32;

    __shared__ __align__(16) float xlds[16][40];
    __shared__ float wlds[256][17];

    float acc[32];
#pragma unroll
    for (int r = 0; r < 32; ++r) acc[r] = 0.f;

    const int ar = t >> 3;
    const int ak = (t & 7) * 2;
    const int wk = t & 15;
    const int wo = (t >> 4) * 16;

    for (int d0 = 0; d0 < 256; d0 += 16) {
        {
            const float* src = ktv + (size_t)(h * 256 + m0 + ar) * 256 + d0 + ak;
            xlds[ak][ar]     = src[0];
            xlds[ak + 1][ar] = src[1];
        }
#pragma unroll
        for (int j = 0; j < 16; ++j)
            wlds[wo + j][wk] = fw[(size_t)(wo + j) * 2048 + h * 256 + d0 + wk];
        __syncthreads();
#pragma unroll
        for (int kk = 0; kk < 16; ++kk) {
            float bv = wlds[t][kk];
            const float4* xr = (const float4*)(&xlds[kk][0]);
#pragma unroll
            for (int g = 0; g < 8; ++g) {
                float4 xv = xr[g];
                acc[g * 4 + 0] = fmaf(xv.x, bv, acc[g * 4 + 0]);
                acc[g * 4 + 1] = fmaf(xv.y, bv, acc[g * 4 + 1]);
                acc[g * 4 + 2] = fmaf(xv.z, bv, acc[g * 4 + 2]);
                acc[g * 4 + 3] = fmaf(xv.w, bv, acc[g * 4 + 3]);
            }
        }
        __syncthreads();
    }
#pragma unroll
    for (int r = 0; r < 32; ++r)
        W2T[(size_t)t * 4096 + h * 256 + m0 + r] = f2b(acc[r]);
}

// ---------------- epilogue: bias + Lorentz lift ----------------
__global__ __launch_bounds__(256) void lift_kernel(
    const float* __restrict__ bias2, float* __restrict__ outp)
{
    const int t = threadIdx.x;
    const int lane = t & 63;
    const int w = t >> 6;
    const int n0 = blockIdx.x * 64 + w * 16;
    float b[4];
#pragma unroll
    for (int j = 0; j < 4; ++j) b[j] = bias2[lane + j * 64];
    for (int r = 0; r < 16; ++r) {
        float* row = outp + (size_t)(n0 + r) * 257;
        float v[4];
        float s = 0.f;
#pragma unroll
        for (int j = 0; j < 4; ++j) {
            v[j] = row[1 + lane + j * 64] + b[j];
            s = fmaf(v[j], v[j], s);
        }
#pragma unroll
        for (int off = 32; off > 0; off >>= 1) s += __shfl_down(s, off, 64);
#pragma unroll
        for (int j = 0; j < 4; ++j) row[1 + lane + j * 64] = v[j];
        if (lane == 0) row[0] = sqrtf(s + 1.0f);
    }
}

extern "C" void kernel_launch(void* const* d_in, const int* in_sizes, int n_in,
                              void* d_out, int out_size, void* d_ws, size_t ws_size,
                              hipStream_t stream)
{
    const float* xq  = (const float*)d_in[0];
    const float* xs  = (const float*)d_in[1];
    const float* Wq  = (const float*)d_in[2];
    const float* Bq  = (const float*)d_in[3];
    const float* Wk  = (const float*)d_in[4];
    const float* Bk  = (const float*)d_in[5];
    const float* Wv  = (const float*)d_in[6];
    const float* Bv  = (const float*)d_in[7];
    const float* nsc = (const float*)d_in[8];
    const float* vmw = (const float*)d_in[9];
    const float* vmb = (const float*)d_in[10];
    const float* fw  = (const float*)d_in[11];
    const float* fb  = (const float*)d_in[12];
    float* outp = (float*)d_out;

    char* ws = (char*)d_ws;
    float* ktv          = (float*)(ws + 0);                 // 2,097,152
    float* colrep       = (float*)(ws + 2097152);           //    65,536
    float* Mf32         = (float*)(ws + 2162688);           //   294,912
    float* colsum       = (float*)(ws + 2457600);           //     8,192
    float* bias2        = (float*)(ws + 2465792);           //     1,024
    float* biasAll      = (float*)(ws + 2466816);           //    24,576
    unsigned short* W2T = (unsigned short*)(ws + 2491392);  // 2,097,152
    unsigned short* Wbf = (unsigned short*)(ws + 4588544);  // 3,538,944
    float* G32          = (float*)(ws + 8127488);           // 2,097,152
    unsigned short* Mbf = (unsigned short*)(ws + 10224640); //   147,456
    const size_t fixedBytes = 10372096;

    int CH = 2048;
    if (ws_size >= fixedBytes + (size_t)8192 * 8192) CH = 8192;
    else if (ws_size >= fixedBytes + (size_t)4096 * 8192) CH = 4096;
    const int NCHK = 32768 / CH;
    unsigned short* phibuf = (unsigned short*)(ws + fixedBytes);
    unsigned short* vsT    = (unsigned short*)(ws + fixedBytes + (size_t)CH * 4096);

    // zero ktv + colrep + Mf32 (contiguous 614400 floats)
    zero_kernel<<<dim3(2400), 256, 0, stream>>>(ktv, 614400);
    wconv_kernel<<<dim3(6168), 256, 0, stream>>>(Wq, Wk, Wv, Bq, Bk, Bv, Wbf, biasAll);
    w2g_kernel<<<dim3(64), 256, 0, stream>>>(vmw, fw, G32);
    bias2_kernel<<<dim3(256), 256, 0, stream>>>(vmb, fw, fb, Bv, G32, bias2);
    gm_kernel<<<dim3(4, 9, 8), 256, 0, stream>>>(Wv, G32, Mf32);
    gmcvt_kernel<<<dim3(288), 256, 0, stream>>>(Mf32, Mbf);

    // Pass A: K/V chunks -> phiT (tiled), colsum replicas, ktv, out = Xs@M
    for (int c = 0; c < NCHK; ++c) {
        const float* xs_c = xs + (size_t)c * CH * 257;
        float* out_c = outp + (size_t)c * CH * 257;
        proj_phi<<<dim3(CH / 64, 8), 256, 0, stream>>>(
            xs_c, Wbf + (size_t)2048 * 288, biasAll + 2048, phibuf,
            nsc, nullptr, colrep, 0, CH);
        proj_mfma<<<dim3(CH / 128, 16), 256, 0, stream>>>(
            xs_c, Wbf + (size_t)4096 * 288, biasAll + 4096, vsT, CH);
        xm_mfma<<<dim3(CH / 128, 2), 256, 0, stream>>>(xs_c, Mbf, out_c);
        ktv_mfma<<<dim3((CH / 512) * 4, 8), 256, 0, stream>>>(phibuf, vsT, ktv, CH);
    }

    // merge colsum replicas; ktv-dependent weights
    merge_colsum<<<dim3(8), 256, 0, stream>>>(colrep, colsum);
    w2u_kernel<<<dim3(64), 256, 0, stream>>>(ktv, fw, W2T);

    // Pass B: Q chunks -> phiQ*invden (coalesced row-major), out += phiQs @ W2u
    for (int c = 0; c < NCHK; ++c) {
        const float* xq_c = xq + (size_t)c * CH * 257;
        float* out_c = outp + (size_t)c * CH * 257;
        proj_phi<<<dim3(CH / 64, 8), 256, 0, stream>>>(
            xq_c, Wbf, biasAll, phibuf,
            nsc, colsum, nullptr, 1, CH);
        final_mfma<<<dim3(CH / 128, 4, 2), 256, 0, stream>>>(phibuf, W2T, 0, 2048, out_c);
    }

    // bias + Lorentz lift
    lift_kernel<<<dim3(512), 256, 0, stream>>>(bias2, outp);
}

// Round 9
// 1049.021 us; speedup vs baseline: 1.2222x; 1.0057x over previous
//
#include <hip/hip_runtime.h>
#include <hip/hip_bf16.h>

// DHHT round 16: R15 verified cores + R14's merge, minus R14's bugs.
//  - Evidence: R14 merged proj_all = 42us/unit-of-work vs R15 serial 51.6,
//    DESPITE 2.4x write amplification (untiled scatter, WRITE 179MB vs 75)
//    and dbuf-halved occupancy. Merge with R15's tiled stores keeps the
//    structural win and kills the amplification.
//  - proj_all: single kernel, 4 modes (K-phi / V / xm / Q-phi). Pass A is ONE
//    dispatch (y=17), pass B proj is one dispatch (y=8). Single-buffered
//    2-barrier K-loop + tiled transposed stores, all byte-identical to R15's
//    verified paths. 38.4 KB LDS -> 4 blocks/CU.
//  - CH ladder extended to 32768/16384 (fallback 8192 proven).
// W2T bf16 [256][4096]: cols 0..2047 = W2u (ktv@F^T). G lives in G32 (f32).

#define EPSF 1e-6f

typedef __attribute__((ext_vector_type(8))) short bf16x8;
typedef __attribute__((ext_vector_type(8))) unsigned short u16x8;
typedef __attribute__((ext_vector_type(4))) float f32x4;
typedef float f32x4a __attribute__((ext_vector_type(4), aligned(4)));

#define STRIPE 131072  // 2048 cols * 64 n (u16) = 256 KB per n-stripe

__device__ __forceinline__ float b2f(unsigned short u) {
    union { unsigned int i; float f; } c;
    c.i = ((unsigned int)u) << 16;
    return c.f;
}
__device__ __forceinline__ unsigned short f2b(float f) {
    __hip_bfloat16 h = __float2bfloat16(f);
    union { __hip_bfloat16 h; unsigned short u; } c;
    c.h = h;
    return c.u;
}

__global__ void zero_kernel(float* __restrict__ p, int n) {
    int i = blockIdx.x * 256 + threadIdx.x;
    if (i < n) p[i] = 0.f;
}

// ---------------- weight convert: Wbf [6144][288] bf16 + biasAll[6144] ----------------
__global__ __launch_bounds__(256) void wconv_kernel(
    const float* __restrict__ Wq, const float* __restrict__ Wk, const float* __restrict__ Wv,
    const float* __restrict__ Bq, const float* __restrict__ Bk, const float* __restrict__ Bv,
    unsigned short* __restrict__ Wbf, float* __restrict__ biasAll)
{
    const int t = threadIdx.x;
    const int b = blockIdx.x;
    if (b < 6144) {
        const int mat = b >> 11, lr = b & 2047;
        const float* Ws = (mat == 0 ? Wq : mat == 1 ? Wk : Wv) + (size_t)lr * 257;
        Wbf[(size_t)b * 288 + t] = f2b(Ws[t]);
        if (t < 32) {
            float v = (t == 0) ? Ws[256] : 0.f;
            Wbf[(size_t)b * 288 + 256 + t] = f2b(v);
        }
    } else {
        const int e = (b - 6144) * 256 + t;
        const int mat = e >> 11, r = e & 2047;
        biasAll[e] = (mat == 0 ? Bq : mat == 1 ? Bk : Bv)[r];
    }
}

// ---------------- G32[o][hk] ----------------
__global__ __launch_bounds__(256) void w2g_kernel(
    const float* __restrict__ vmw,
    const float* __restrict__ fw,
    float* __restrict__ G32)
{
    const int t = threadIdx.x;
    const int h = blockIdx.x >> 3;
    const int i0 = (blockIdx.x & 7) * 32;

    __shared__ __align__(16) float xlds[16][40];
    __shared__ float wlds[256][17];

    float acc[32];
#pragma unroll
    for (int r = 0; r < 32; ++r) acc[r] = 0.f;

    const int ar = t >> 3;
    const int ak = (t & 7) * 2;
    const int wk = t & 15;
    const int wo = (t >> 4) * 16;

    for (int d0 = 0; d0 < 256; d0 += 16) {
        xlds[ak][ar]     = vmw[(size_t)(d0 + ak) * 256 + i0 + ar];
        xlds[ak + 1][ar] = vmw[(size_t)(d0 + ak + 1) * 256 + i0 + ar];
#pragma unroll
        for (int j = 0; j < 16; ++j)
            wlds[wo + j][wk] = fw[(size_t)(wo + j) * 2048 + h * 256 + d0 + wk];
        __syncthreads();
#pragma unroll
        for (int kk = 0; kk < 16; ++kk) {
            float bv = wlds[t][kk];
            const float4* xr = (const float4*)(&xlds[kk][0]);
#pragma unroll
            for (int g = 0; g < 8; ++g) {
                float4 xv = xr[g];
                acc[g * 4 + 0] = fmaf(xv.x, bv, acc[g * 4 + 0]);
                acc[g * 4 + 1] = fmaf(xv.y, bv, acc[g * 4 + 1]);
                acc[g * 4 + 2] = fmaf(xv.z, bv, acc[g * 4 + 2]);
                acc[g * 4 + 3] = fmaf(xv.w, bv, acc[g * 4 + 3]);
            }
        }
        __syncthreads();
    }
#pragma unroll
    for (int r = 0; r < 32; ++r)
        G32[(size_t)t * 2048 + h * 256 + i0 + r] = acc[r];
}

// ---------------- bias2 ----------------
__global__ __launch_bounds__(256) void bias2_kernel(
    const float* __restrict__ vmb, const float* __restrict__ fw,
    const float* __restrict__ fb, const float* __restrict__ Bv,
    const float* __restrict__ G32, float* __restrict__ bias2)
{
    const int o = blockIdx.x;
    const int t = threadIdx.x;
    float s = 0.f, sb = 0.f;
#pragma unroll
    for (int i = 0; i < 8; ++i) {
        const int j = t + i * 256;
        s += fw[(size_t)o * 2048 + j];
        sb += Bv[j] * G32[(size_t)o * 2048 + j];
    }
    s = s * vmb[t] + sb;
#pragma unroll
    for (int off = 32; off > 0; off >>= 1) s += __shfl_down(s, off, 64);
    __shared__ float r4[4];
    if ((t & 63) == 0) r4[t >> 6] = s;
    __syncthreads();
    if (t == 0) bias2[o] = fb[o] + r4[0] + r4[1] + r4[2] + r4[3];
}

// ---------------- Mf32[o][i] += sum_k G32[o][k] Wv[k][i] ----------------
__global__ __launch_bounds__(256) void gm_kernel(
    const float* __restrict__ Wv, const float* __restrict__ G32,
    float* __restrict__ Mf32)
{
    __shared__ float Gt[64][33];
    __shared__ float Wt[32][33];
    const int t = threadIdx.x;
    const int o0 = blockIdx.x * 64, i0 = blockIdx.y * 32, k0 = blockIdx.z * 256;
    const int ii = t & 31, og = t >> 5;
    float acc[8] = {};
    for (int kk0 = k0; kk0 < k0 + 256; kk0 += 32) {
#pragma unroll
        for (int r = 0; r < 8; ++r) {
            const int e = t + r * 256;
            Gt[e >> 5][e & 31] = G32[(size_t)(o0 + (e >> 5)) * 2048 + kk0 + (e & 31)];
        }
#pragma unroll
        for (int r = 0; r < 4; ++r) {
            const int e = t + r * 256;
            const int kk = e >> 5, i = i0 + (e & 31);
            Wt[kk][e & 31] = (i < 257) ? Wv[(size_t)(kk0 + kk) * 257 + i] : 0.f;
        }
        __syncthreads();
#pragma unroll
        for (int kk = 0; kk < 32; ++kk) {
            float wv_ = Wt[kk][ii];
#pragma unroll
            for (int r = 0; r < 8; ++r)
                acc[r] = fmaf(Gt[og * 8 + r][kk], wv_, acc[r]);
        }
        __syncthreads();
    }
#pragma unroll
    for (int r = 0; r < 8; ++r)
        atomicAdd(&Mf32[(size_t)(o0 + og * 8 + r) * 288 + i0 + ii], acc[r]);
}

__global__ void gmcvt_kernel(const float* __restrict__ Mf32, unsigned short* __restrict__ Mbf) {
    const int i = blockIdx.x * 256 + threadIdx.x;
    Mbf[i] = f2b(Mf32[i]);
}

// ---------------- merged projection kernel (single-buf, tiled stores) ----------------
// pass 0 (A): y<8 -> K-head (phi, tiled-transposed + colrep); y<16 -> V-head
//             (tiled-transposed vsT); y==16 -> xm (f32 rows into out).
// pass 1 (B): y<8 -> Q-head (phi*invden, coalesced row-major via LDS transpose).
__global__ __launch_bounds__(256) void proj_all(
    int pass,
    const float* __restrict__ X,
    const unsigned short* __restrict__ Wbf,
    const unsigned short* __restrict__ Mbf,
    const float* __restrict__ biasAll,
    unsigned short* __restrict__ phiOut,
    unsigned short* __restrict__ vsOut,
    float* __restrict__ xOut,
    const float* __restrict__ nsc,
    const float* __restrict__ colsum_in,
    float* __restrict__ colrep,
    int CH)
{
    __shared__ __align__(16) unsigned short smem[16896]; // staging 12800 | tstore 16384 | Q-xp 16896
    __shared__ float reds2[4][64];
    __shared__ float reds4[4][64];
    __shared__ float rowv[64];
    __shared__ float rowx[64];
    unsigned short* lA = smem;
    unsigned short* lB = smem + 64 * 40;

    const int t = threadIdx.x;
    const int m0 = blockIdx.x * 64;
    const int y  = blockIdx.y;
    const int lane = t & 63, w = t >> 6;
    const int wn = w * 64;
    const int l15 = lane & 15, q = lane >> 4;
    const int ar = t >> 2, akg = (t & 3) * 8;

    // mode: 0=K-phi 1=V 2=xm 3=Q-phi
    int mode, hcol;
    const unsigned short* Wb;
    const float* bb;
    if (pass == 1)   { mode = 3; hcol = y * 256; Wb = Wbf + (size_t)hcol * 288;                bb = biasAll + hcol; }
    else if (y < 8)  { mode = 0; hcol = y * 256; Wb = Wbf + (size_t)(2048 + hcol) * 288;       bb = biasAll + 2048 + hcol; }
    else if (y < 16) { mode = 1; hcol = (y - 8) * 256; Wb = Wbf + (size_t)(4096 + hcol) * 288; bb = biasAll + 4096 + hcol; }
    else             { mode = 2; hcol = 0; Wb = Mbf; bb = nullptr; }

    f32x4 acc[4][4] = {};
    const float* XA = X + (size_t)(m0 + ar) * 257 + akg;
    const unsigned short* WB = Wb + (size_t)ar * 288 + akg;

    f32x4a cx0, cx1;
    u16x8 cw[4];
    cx0 = *(const f32x4a*)(XA);
    cx1 = *(const f32x4a*)(XA + 4);
#pragma unroll
    for (int qq = 0; qq < 4; ++qq)
        cw[qq] = *(const u16x8*)(WB + (size_t)qq * 64 * 288);

    for (int ks = 0; ks < 8; ++ks) {
        {
            u16x8 pk;
            pk[0] = f2b(cx0[0]); pk[1] = f2b(cx0[1]);
            pk[2] = f2b(cx0[2]); pk[3] = f2b(cx0[3]);
            pk[4] = f2b(cx1[0]); pk[5] = f2b(cx1[1]);
            pk[6] = f2b(cx1[2]); pk[7] = f2b(cx1[3]);
            *(u16x8*)(&lA[ar * 40 + akg]) = pk;
        }
#pragma unroll
        for (int qq = 0; qq < 4; ++qq)
            *(u16x8*)(&lB[(ar + qq * 64) * 40 + akg]) = cw[qq];
        if (ks < 7) {
            const int k1 = (ks + 1) * 32;
            cx0 = *(const f32x4a*)(XA + k1);
            cx1 = *(const f32x4a*)(XA + k1 + 4);
#pragma unroll
            for (int qq = 0; qq < 4; ++qq)
                cw[qq] = *(const u16x8*)(WB + (size_t)qq * 64 * 288 + k1);
        }
        __syncthreads();
        bf16x8 af[4], bfr[4];
#pragma unroll
        for (int i = 0; i < 4; ++i)
            af[i] = *(const bf16x8*)(&lA[(i * 16 + l15) * 40 + q * 8]);
#pragma unroll
        for (int j = 0; j < 4; ++j)
            bfr[j] = *(const bf16x8*)(&lB[(wn + j * 16 + l15) * 40 + q * 8]);
#pragma unroll
        for (int i = 0; i < 4; ++i)
#pragma unroll
            for (int j = 0; j < 4; ++j)
                acc[i][j] = __builtin_amdgcn_mfma_f32_16x16x32_bf16(af[i], bfr[j], acc[i][j], 0, 0, 0);
        __syncthreads();
    }

    if (t < 64) rowx[t] = b2f(f2b(X[(size_t)(m0 + t) * 257 + 256]));
    __syncthreads();

    // rank-1 Lorentz column (all modes; xm's w256 lives in Mbf col 256)
    {
        float w256[4];
#pragma unroll
        for (int j = 0; j < 4; ++j)
            w256[j] = b2f(Wb[(size_t)(wn + j * 16 + l15) * 288 + 256]);
#pragma unroll
        for (int i = 0; i < 4; ++i)
#pragma unroll
            for (int r = 0; r < 4; ++r) {
                const float xv = rowx[i * 16 + q * 4 + r];
#pragma unroll
                for (int j = 0; j < 4; ++j)
                    acc[i][j][r] += xv * w256[j];
            }
    }

    if (mode == 2) {
        // xm: f32 row store (no bias; final_mfma accumulates on top later)
#pragma unroll
        for (int j = 0; j < 4; ++j) {
            const int cg = wn + j * 16 + l15;
#pragma unroll
            for (int i = 0; i < 4; ++i)
#pragma unroll
                for (int r = 0; r < 4; ++r) {
                    const int n = m0 + i * 16 + q * 4 + r;
                    xOut[(size_t)n * 257 + 1 + cg] = acc[i][j][r];
                }
        }
        return;
    }

    if (mode == 1) {
        // V: bias, then tiled transposed store into stripe blockIdx.x
#pragma unroll
        for (int j = 0; j < 4; ++j) {
            const float bias = bb[wn + j * 16 + l15];
#pragma unroll
            for (int i = 0; i < 4; ++i)
#pragma unroll
                for (int r = 0; r < 4; ++r)
                    acc[i][j][r] += bias;
        }
#pragma unroll
        for (int i = 0; i < 4; ++i)
#pragma unroll
            for (int j = 0; j < 4; ++j) {
                const int cl = wn + j * 16 + l15;
#pragma unroll
                for (int r2 = 0; r2 < 4; r2 += 2) {
                    const int nl = i * 16 + q * 4 + r2;
                    const unsigned int pk =
                        (unsigned int)f2b(acc[i][j][r2]) |
                        ((unsigned int)f2b(acc[i][j][r2 + 1]) << 16);
                    *(unsigned int*)(&smem[cl * 64 + (((nl >> 3) ^ (cl & 7)) << 3) + (nl & 7)]) = pk;
                }
            }
        __syncthreads();
#pragma unroll
        for (int k = 0; k < 8; ++k) {
            const int task = k * 256 + t;
            const int cl = task >> 3, nq = task & 7;
            *(u16x8*)(vsOut + (size_t)blockIdx.x * STRIPE +
                      (size_t)(hcol + cl) * 64 + nq * 8) =
                *(const u16x8*)(&smem[cl * 64 + ((nq ^ (cl & 7)) << 3)]);
        }
        return;
    }

    // K-phi or Q-phi
    const float c = fabsf(nsc[0]) + EPSF;
    float bias[4];
#pragma unroll
    for (int j = 0; j < 4; ++j) bias[j] = bb[wn + j * 16 + l15];

    float a2[4][4], a4[4][4];
#pragma unroll
    for (int i = 0; i < 4; ++i)
#pragma unroll
        for (int r = 0; r < 4; ++r) { a2[i][r] = 0.f; a4[i][r] = 0.f; }
#pragma unroll
    for (int i = 0; i < 4; ++i)
#pragma unroll
        for (int j = 0; j < 4; ++j)
#pragma unroll
            for (int r = 0; r < 4; ++r) {
                float uu = fmaxf(acc[i][j][r] + bias[j], 0.f) + EPSF;
                float q2 = uu * uu;
                acc[i][j][r] = q2;
                a2[i][r] += q2;
                a4[i][r] += q2 * q2;
            }
#pragma unroll
    for (int m = 1; m <= 8; m <<= 1) {
#pragma unroll
        for (int i = 0; i < 4; ++i)
#pragma unroll
            for (int r = 0; r < 4; ++r) {
                a2[i][r] += __shfl_xor(a2[i][r], m, 64);
                a4[i][r] += __shfl_xor(a4[i][r], m, 64);
            }
    }
    if (l15 == 0) {
#pragma unroll
        for (int i = 0; i < 4; ++i)
#pragma unroll
            for (int r = 0; r < 4; ++r) {
                reds2[w][i * 16 + q * 4 + r] = a2[i][r];
                reds4[w][i * 16 + q * 4 + r] = a4[i][r];
            }
    }
    __syncthreads();
    if (t < 64) {
        float s2t = reds2[0][t] + reds2[1][t] + reds2[2][t] + reds2[3][t];
        float s4t = reds4[0][t] + reds4[1][t] + reds4[2][t] + reds4[3][t];
        rowv[t] = sqrtf(s2t) / (c * sqrtf(s4t));
    }
    __syncthreads();
    float sc_[4][4];
#pragma unroll
    for (int i = 0; i < 4; ++i)
#pragma unroll
        for (int r = 0; r < 4; ++r) sc_[i][r] = rowv[i * 16 + q * 4 + r];

    if (mode == 0) {
        float colp[4];
#pragma unroll
        for (int j = 0; j < 4; ++j) colp[j] = 0.f;
#pragma unroll
        for (int i = 0; i < 4; ++i)
#pragma unroll
            for (int j = 0; j < 4; ++j)
#pragma unroll
                for (int r = 0; r < 4; ++r) {
                    float ph = acc[i][j][r] * sc_[i][r];
                    acc[i][j][r] = ph;
                    colp[j] += ph;
                }
        // tiled transposed store: contiguous 32-KB run for this (block, head)
#pragma unroll
        for (int i = 0; i < 4; ++i)
#pragma unroll
            for (int j = 0; j < 4; ++j) {
                const int cl = wn + j * 16 + l15;
#pragma unroll
                for (int r2 = 0; r2 < 4; r2 += 2) {
                    const int nl = i * 16 + q * 4 + r2;
                    const unsigned int pk =
                        (unsigned int)f2b(acc[i][j][r2]) |
                        ((unsigned int)f2b(acc[i][j][r2 + 1]) << 16);
                    *(unsigned int*)(&smem[cl * 64 + (((nl >> 3) ^ (cl & 7)) << 3) + (nl & 7)]) = pk;
                }
            }
        __syncthreads();
#pragma unroll
        for (int k = 0; k < 8; ++k) {
            const int task = k * 256 + t;
            const int cl = task >> 3, nq = task & 7;
            *(u16x8*)(phiOut + (size_t)blockIdx.x * STRIPE +
                      (size_t)(hcol + cl) * 64 + nq * 8) =
                *(const u16x8*)(&smem[cl * 64 + ((nq ^ (cl & 7)) << 3)]);
        }
        // colsum replicas
#pragma unroll
        for (int j = 0; j < 4; ++j) {
            colp[j] += __shfl_xor(colp[j], 16, 64);
            colp[j] += __shfl_xor(colp[j], 32, 64);
        }
        if (q == 0) {
            float* dst = colrep + (size_t)(blockIdx.x & 7) * 2048;
#pragma unroll
            for (int j = 0; j < 4; ++j)
                atomicAdd(&dst[hcol + wn + j * 16 + l15], colp[j]);
        }
    } else {
        // Q: invden, then coalesced row-major store via padded LDS transpose
        float cs[4];
#pragma unroll
        for (int j = 0; j < 4; ++j) cs[j] = colsum_in[hcol + wn + j * 16 + l15];
        float dp[4][4];
#pragma unroll
        for (int i = 0; i < 4; ++i)
#pragma unroll
            for (int r = 0; r < 4; ++r) dp[i][r] = 0.f;
#pragma unroll
        for (int i = 0; i < 4; ++i)
#pragma unroll
            for (int j = 0; j < 4; ++j)
#pragma unroll
                for (int r = 0; r < 4; ++r) {
                    float ph = acc[i][j][r] * sc_[i][r];
                    acc[i][j][r] = ph;
                    dp[i][r] += ph * cs[j];
                }
#pragma unroll
        for (int m = 1; m <= 8; m <<= 1) {
#pragma unroll
            for (int i = 0; i < 4; ++i)
#pragma unroll
                for (int r = 0; r < 4; ++r)
                    dp[i][r] += __shfl_xor(dp[i][r], m, 64);
        }
        if (l15 == 0) {
#pragma unroll
            for (int i = 0; i < 4; ++i)
#pragma unroll
                for (int r = 0; r < 4; ++r)
                    reds2[w][i * 16 + q * 4 + r] = dp[i][r];
        }
        __syncthreads();
        if (t < 64) {
            float dt = reds2[0][t] + reds2[1][t] + reds2[2][t] + reds2[3][t];
            rowv[t] = 1.f / (dt + EPSF);
        }
        __syncthreads();
#pragma unroll
        for (int i = 0; i < 4; ++i)
#pragma unroll
            for (int r = 0; r < 4; ++r) sc_[i][r] = rowv[i * 16 + q * 4 + r];
#pragma unroll
        for (int i = 0; i < 4; ++i)
#pragma unroll
            for (int j = 0; j < 4; ++j) {
                const int cl = wn + j * 16 + l15;
#pragma unroll
                for (int r = 0; r < 4; ++r) {
                    const int nl = i * 16 + q * 4 + r;
                    smem[nl * 264 + cl] = f2b(acc[i][j][r] * sc_[i][r]);
                }
            }
        __syncthreads();
#pragma unroll
        for (int k = 0; k < 8; ++k) {
            const int task = k * 256 + t;
            const int rowl = task >> 5, ck = (task & 31) * 8;
            *(u16x8*)(phiOut + (size_t)(m0 + rowl) * 2048 + hcol + ck) =
                *(const u16x8*)(&smem[rowl * 264 + ck]);
        }
    }
}

// ---------------- merge colsum replicas ----------------
__global__ __launch_bounds__(256) void merge_colsum(
    const float* __restrict__ rep, float* __restrict__ out)
{
    const int cidx = blockIdx.x * 256 + threadIdx.x;
    float s = 0.f;
#pragma unroll
    for (int r = 0; r < 8; ++r) s += rep[(size_t)r * 2048 + cidx];
    out[cidx] = s;
}

// ---------------- ktv MFMA: tiled reads (contiguous runs), prefetched ----------------
__global__ __launch_bounds__(256) void ktv_mfma(
    const unsigned short* __restrict__ phiT,   // tiled [CH/64][2048][64]
    const unsigned short* __restrict__ vsT,
    float* __restrict__ ktv, int CH)
{
    __shared__ __align__(16) unsigned short lAT[128 * 64];
    __shared__ __align__(16) unsigned short lBT[128 * 64];
    const int t = threadIdx.x;
    const int h = blockIdx.y;
    const int split = blockIdx.x >> 2;
    const int tile = blockIdx.x & 3;
    const int m0 = (tile >> 1) * 128, d0 = (tile & 1) * 128;
    const int chh = h * 256;
    const int lane = t & 63, w = t >> 6;
    const int wm = (w >> 1) * 64, wn = (w & 1) * 64;
    const int l15 = lane & 15, q = lane >> 4;
    const int sl7 = l15 & 7;

    const int scg  = t >> 3;
    const int snq  = t & 7;
    const int sbase = scg * 64 + ((snq ^ (scg & 7)) << 3);

    f32x4 acc[4][4] = {};
    const int st0 = split * 8;

    const unsigned short* pA = phiT + (size_t)(chh + m0 + scg) * 64 + snq * 8;
    const unsigned short* pB = vsT  + (size_t)(chh + d0 + scg) * 64 + snq * 8;

    u16x8 cA[4], cB[4], nA[4], nB[4];
#pragma unroll
    for (int k = 0; k < 4; ++k) {
        cA[k] = *(const u16x8*)(pA + (size_t)st0 * STRIPE + k * 2048);
        cB[k] = *(const u16x8*)(pB + (size_t)st0 * STRIPE + k * 2048);
    }

    for (int it = 0; it < 8; ++it) {
#pragma unroll
        for (int k = 0; k < 4; ++k) {
            *(u16x8*)(&lAT[k * 2048 + sbase]) = cA[k];
            *(u16x8*)(&lBT[k * 2048 + sbase]) = cB[k];
        }
        if (it < 7) {
            const size_t so = (size_t)(st0 + it + 1) * STRIPE;
#pragma unroll
            for (int k = 0; k < 4; ++k) {
                nA[k] = *(const u16x8*)(pA + so + k * 2048);
                nB[k] = *(const u16x8*)(pB + so + k * 2048);
            }
        }
        __syncthreads();
#pragma unroll
        for (int sub = 0; sub < 2; ++sub) {
            const int slot = ((sub * 4 + q) ^ sl7) << 3;
            bf16x8 af[4], bfr[4];
#pragma unroll
            for (int i = 0; i < 4; ++i)
                af[i] = *(const bf16x8*)(&lAT[(wm + i * 16 + l15) * 64 + slot]);
#pragma unroll
            for (int j = 0; j < 4; ++j)
                bfr[j] = *(const bf16x8*)(&lBT[(wn + j * 16 + l15) * 64 + slot]);
#pragma unroll
            for (int i = 0; i < 4; ++i)
#pragma unroll
                for (int j = 0; j < 4; ++j)
                    acc[i][j] = __builtin_amdgcn_mfma_f32_16x16x32_bf16(af[i], bfr[j], acc[i][j], 0, 0, 0);
        }
        __syncthreads();
        if (it < 7) {
#pragma unroll
            for (int k = 0; k < 4; ++k) { cA[k] = nA[k]; cB[k] = nB[k]; }
        }
    }
#pragma unroll
    for (int i = 0; i < 4; ++i)
#pragma unroll
        for (int j = 0; j < 4; ++j)
#pragma unroll
            for (int r = 0; r < 4; ++r) {
                const int m = m0 + wm + i * 16 + q * 4 + r;
                const int d = d0 + wn + j * 16 + l15;
                atomicAdd(&ktv[((size_t)chh + m) * 256 + d], acc[i][j][r]);
            }
}

// ---------------- final staging load ----------------
__device__ __forceinline__ void fin_load(
    const unsigned short* __restrict__ Abuf, const unsigned short* __restrict__ W2T,
    int n0, int d0, int t, int k0,
    u16x8& A0, u16x8& A1, u16x8& B)
{
    {
        const int row = t >> 2, kg = (t & 3) * 8;
        A0 = *(const u16x8*)(Abuf + (size_t)(n0 + row) * 2048 + ((k0 + kg) & 2047));
    }
    {
        const int e = t + 256;
        const int row = e >> 2, kg = (e & 3) * 8;
        A1 = *(const u16x8*)(Abuf + (size_t)(n0 + row) * 2048 + ((k0 + kg) & 2047));
    }
    {
        const int row = t >> 2, kg = (t & 3) * 8;
        B = *(const u16x8*)(W2T + (size_t)(d0 + row) * 4096 + k0 + kg);
    }
}

// ---------------- final MFMA GEMM 128x64 (reg-prefetch, split-K x2, atomic) ----------------
__global__ __launch_bounds__(256) void final_mfma(
    const unsigned short* __restrict__ Abuf,
    const unsigned short* __restrict__ W2T,
    int kbeg, int kend,
    float* __restrict__ outp)
{
    __shared__ __align__(16) unsigned short lA[128 * 40];
    __shared__ __align__(16) unsigned short lB[64 * 40];
    const int t = threadIdx.x;
    const int n0 = blockIdx.x * 128;
    const int d0 = blockIdx.y * 64;
    const int khalf = (kend - kbeg) >> 1;
    const int kb = kbeg + blockIdx.z * khalf;
    const int ke = kb + khalf;
    const int lane = t & 63, w = t >> 6;
    const int wm = w * 32;
    const int l15 = lane & 15, q = lane >> 4;

    f32x4 acc[2][4] = {};
    u16x8 cA0, cA1, cB, nA0, nA1, nB;
    fin_load(Abuf, W2T, n0, d0, t, kb, cA0, cA1, cB);

    for (int k0 = kb; k0 < ke; k0 += 32) {
        {
            const int row = t >> 2, kg = (t & 3) * 8;
            *(u16x8*)(&lA[row * 40 + kg]) = cA0;
            *(u16x8*)(&lB[row * 40 + kg]) = cB;
        }
        {
            const int e = t + 256;
            const int row = e >> 2, kg = (e & 3) * 8;
            *(u16x8*)(&lA[row * 40 + kg]) = cA1;
        }
        if (k0 + 32 < ke)
            fin_load(Abuf, W2T, n0, d0, t, k0 + 32, nA0, nA1, nB);
        __syncthreads();
        bf16x8 af[2], bfr[4];
#pragma unroll
        for (int i = 0; i < 2; ++i)
            af[i] = *(const bf16x8*)(&lA[(wm + i * 16 + l15) * 40 + q * 8]);
#pragma unroll
        for (int j = 0; j < 4; ++j)
            bfr[j] = *(const bf16x8*)(&lB[(j * 16 + l15) * 40 + q * 8]);
#pragma unroll
        for (int i = 0; i < 2; ++i)
#pragma unroll
            for (int j = 0; j < 4; ++j)
                acc[i][j] = __builtin_amdgcn_mfma_f32_16x16x32_bf16(af[i], bfr[j], acc[i][j], 0, 0, 0);
        __syncthreads();
        if (k0 + 32 < ke) { cA0 = nA0; cA1 = nA1; cB = nB; }
    }
#pragma unroll
    for (int i = 0; i < 2; ++i)
#pragma unroll
        for (int j = 0; j < 4; ++j)
#pragma unroll
            for (int r = 0; r < 4; ++r) {
                const int n = n0 + wm + i * 16 + q * 4 + r;
                const int d = d0 + j * 16 + l15;
                atomicAdd(&outp[(size_t)n * 257 + 1 + d], acc[i][j][r]);
            }
}

// ---------------- W2T upper = ktv_h @ F_h^T (bf16) ----------------
__global__ __launch_bounds__(256) void w2u_kernel(
    const float* __restrict__ ktv,
    const float* __restrict__ fw,
    unsigned short* __restrict__ W2T)
{
    const int t = threadIdx.x;
    const int h = blockIdx.x >> 3;
    const int m0 = (blockIdx.x & 7) * 32;

    __shared__ __align__(16) float xlds[16][40];
    __shared__ float wlds[256][17];

    float acc[32];
#pragma unroll
    for (int r = 0; r < 32; ++r) acc[r] = 0.f;

    const int ar = t >> 3;
    const int ak = (t & 7) * 2;
    const int wk = t & 15;
    const int wo = (t >> 4) * 16;

    for (int d0 = 0; d0 < 256; d0 += 16) {
        {
            const float* src = ktv + (size_t)(h * 256 + m0 + ar) * 256 + d0 + ak;
            xlds[ak][ar]     = src[0];
            xlds[ak + 1][ar] = src[1];
        }
#pragma unroll
        for (int j = 0; j < 16; ++j)
            wlds[wo + j][wk] = fw[(size_t)(wo + j) * 2048 + h * 256 + d0 + wk];
        __syncthreads();
#pragma unroll
        for (int kk = 0; kk < 16; ++kk) {
            float bv = wlds[t][kk];
            const float4* xr = (const float4*)(&xlds[kk][0]);
#pragma unroll
            for (int g = 0; g < 8; ++g) {
                float4 xv = xr[g];
                acc[g * 4 + 0] = fmaf(xv.x, bv, acc[g * 4 + 0]);
                acc[g * 4 + 1] = fmaf(xv.y, bv, acc[g * 4 + 1]);
                acc[g * 4 + 2] = fmaf(xv.z, bv, acc[g * 4 + 2]);
                acc[g * 4 + 3] = fmaf(xv.w, bv, acc[g * 4 + 3]);
            }
        }
        __syncthreads();
    }
#pragma unroll
    for (int r = 0; r < 32; ++r)
        W2T[(size_t)t * 4096 + h * 256 + m0 + r] = f2b(acc[r]);
}

// ---------------- epilogue: bias + Lorentz lift ----------------
__global__ __launch_bounds__(256) void lift_kernel(
    const float* __restrict__ bias2, float* __restrict__ outp)
{
    const int t = threadIdx.x;
    const int lane = t & 63;
    const int w = t >> 6;
    const int n0 = blockIdx.x * 64 + w * 16;
    float b[4];
#pragma unroll
    for (int j = 0; j < 4; ++j) b[j] = bias2[lane + j * 64];
    for (int r = 0; r < 16; ++r) {
        float* row = outp + (size_t)(n0 + r) * 257;
        float v[4];
        float s = 0.f;
#pragma unroll
        for (int j = 0; j < 4; ++j) {
            v[j] = row[1 + lane + j * 64] + b[j];
            s = fmaf(v[j], v[j], s);
        }
#pragma unroll
        for (int off = 32; off > 0; off >>= 1) s += __shfl_down(s, off, 64);
#pragma unroll
        for (int j = 0; j < 4; ++j) row[1 + lane + j * 64] = v[j];
        if (lane == 0) row[0] = sqrtf(s + 1.0f);
    }
}

extern "C" void kernel_launch(void* const* d_in, const int* in_sizes, int n_in,
                              void* d_out, int out_size, void* d_ws, size_t ws_size,
                              hipStream_t stream)
{
    const float* xq  = (const float*)d_in[0];
    const float* xs  = (const float*)d_in[1];
    const float* Wq  = (const float*)d_in[2];
    const float* Bq  = (const float*)d_in[3];
    const float* Wk  = (const float*)d_in[4];
    const float* Bk  = (const float*)d_in[5];
    const float* Wv  = (const float*)d_in[6];
    const float* Bv  = (const float*)d_in[7];
    const float* nsc = (const float*)d_in[8];
    const float* vmw = (const float*)d_in[9];
    const float* vmb = (const float*)d_in[10];
    const float* fw  = (const float*)d_in[11];
    const float* fb  = (const float*)d_in[12];
    float* outp = (float*)d_out;

    char* ws = (char*)d_ws;
    float* ktv          = (float*)(ws + 0);                 // 2,097,152
    float* colrep       = (float*)(ws + 2097152);           //    65,536
    float* Mf32         = (float*)(ws + 2162688);           //   294,912
    float* colsum       = (float*)(ws + 2457600);           //     8,192
    float* bias2        = (float*)(ws + 2465792);           //     1,024
    float* biasAll      = (float*)(ws + 2466816);           //    24,576
    unsigned short* W2T = (unsigned short*)(ws + 2491392);  // 2,097,152
    unsigned short* Wbf = (unsigned short*)(ws + 4588544);  // 3,538,944
    float* G32          = (float*)(ws + 8127488);           // 2,097,152
    unsigned short* Mbf = (unsigned short*)(ws + 10224640); //   147,456
    const size_t fixedBytes = 10372096;

    int CH = 2048;
    if      (ws_size >= fixedBytes + (size_t)32768 * 8192) CH = 32768;
    else if (ws_size >= fixedBytes + (size_t)16384 * 8192) CH = 16384;
    else if (ws_size >= fixedBytes + (size_t)8192 * 8192)  CH = 8192;
    else if (ws_size >= fixedBytes + (size_t)4096 * 8192)  CH = 4096;
    const int NCHK = 32768 / CH;
    unsigned short* phibuf = (unsigned short*)(ws + fixedBytes);
    unsigned short* vsT    = (unsigned short*)(ws + fixedBytes + (size_t)CH * 4096);

    // zero ktv + colrep + Mf32 (contiguous 614400 floats)
    zero_kernel<<<dim3(2400), 256, 0, stream>>>(ktv, 614400);
    wconv_kernel<<<dim3(6168), 256, 0, stream>>>(Wq, Wk, Wv, Bq, Bk, Bv, Wbf, biasAll);
    w2g_kernel<<<dim3(64), 256, 0, stream>>>(vmw, fw, G32);
    bias2_kernel<<<dim3(256), 256, 0, stream>>>(vmb, fw, fb, Bv, G32, bias2);
    gm_kernel<<<dim3(4, 9, 8), 256, 0, stream>>>(Wv, G32, Mf32);
    gmcvt_kernel<<<dim3(288), 256, 0, stream>>>(Mf32, Mbf);

    // Pass A: merged K-phi / V / xm in ONE dispatch per chunk, then ktv
    for (int c = 0; c < NCHK; ++c) {
        const float* xs_c = xs + (size_t)c * CH * 257;
        float* out_c = outp + (size_t)c * CH * 257;
        proj_all<<<dim3(CH / 64, 17), 256, 0, stream>>>(
            0, xs_c, Wbf, Mbf, biasAll, phibuf, vsT, out_c,
            nsc, nullptr, colrep, CH);
        ktv_mfma<<<dim3((CH / 512) * 4, 8), 256, 0, stream>>>(phibuf, vsT, ktv, CH);
    }

    // merge colsum replicas; ktv-dependent weights
    merge_colsum<<<dim3(8), 256, 0, stream>>>(colrep, colsum);
    w2u_kernel<<<dim3(64), 256, 0, stream>>>(ktv, fw, W2T);

    // Pass B: Q-phi (one dispatch per chunk) + final (split-K x2)
    for (int c = 0; c < NCHK; ++c) {
        const float* xq_c = xq + (size_t)c * CH * 257;
        float* out_c = outp + (size_t)c * CH * 257;
        proj_all<<<dim3(CH / 64, 8), 256, 0, stream>>>(
            1, xq_c, Wbf, Mbf, biasAll, phibuf, vsT, out_c,
            nsc, colsum, nullptr, CH);
        final_mfma<<<dim3(CH / 128, 4, 2), 256, 0, stream>>>(phibuf, W2T, 0, 2048, out_c);
    }

    // bias + Lorentz lift
    lift_kernel<<<dim3(512), 256, 0, stream>>>(bias2, outp);
}

// Round 10
// 943.416 us; speedup vs baseline: 1.3590x; 1.1119x over previous
//
#include <hip/hip_runtime.h>
#include <hip/hip_bf16.h>

// DHHT round 17: evidence-isolated recombination.
//   R14 (dbuf 1-barrier merged proj): pass-A = 90us  | lost on Q-scatter+untiled-ktv
//   R16 (single-buf merged, tiled):   pass-A = 173us | barrier count doubled -> 2x
//   => proj kernels are barrier-drain-bound; dbuf is the lever.
// This round: proj_all = R14's dbuf K-loop + R16's tiled epilogues, LDS
// overlaid to 50KB -> 3 blocks/CU, launch_bounds(256,3) (R14's 84-VGPR cfg).
// Pass B uses R15's verified proj_phi (51.6us) + R16 final. ktv tiled reads.
// W2T bf16 [256][4096]: cols 0..2047 = W2u (ktv@F^T). G lives in G32 (f32).

#define EPSF 1e-6f

typedef __attribute__((ext_vector_type(8))) short bf16x8;
typedef __attribute__((ext_vector_type(8))) unsigned short u16x8;
typedef __attribute__((ext_vector_type(4))) float f32x4;
typedef float f32x4a __attribute__((ext_vector_type(4), aligned(4)));

#define STRIPE 131072  // 2048 cols * 64 n (u16) = 256 KB per n-stripe

__device__ __forceinline__ float b2f(unsigned short u) {
    union { unsigned int i; float f; } c;
    c.i = ((unsigned int)u) << 16;
    return c.f;
}
__device__ __forceinline__ unsigned short f2b(float f) {
    __hip_bfloat16 h = __float2bfloat16(f);
    union { __hip_bfloat16 h; unsigned short u; } c;
    c.h = h;
    return c.u;
}

__global__ void zero_kernel(float* __restrict__ p, int n) {
    int i = blockIdx.x * 256 + threadIdx.x;
    if (i < n) p[i] = 0.f;
}

// ---------------- weight convert: Wbf [6144][288] bf16 + biasAll[6144] ----------------
__global__ __launch_bounds__(256) void wconv_kernel(
    const float* __restrict__ Wq, const float* __restrict__ Wk, const float* __restrict__ Wv,
    const float* __restrict__ Bq, const float* __restrict__ Bk, const float* __restrict__ Bv,
    unsigned short* __restrict__ Wbf, float* __restrict__ biasAll)
{
    const int t = threadIdx.x;
    const int b = blockIdx.x;
    if (b < 6144) {
        const int mat = b >> 11, lr = b & 2047;
        const float* Ws = (mat == 0 ? Wq : mat == 1 ? Wk : Wv) + (size_t)lr * 257;
        Wbf[(size_t)b * 288 + t] = f2b(Ws[t]);
        if (t < 32) {
            float v = (t == 0) ? Ws[256] : 0.f;
            Wbf[(size_t)b * 288 + 256 + t] = f2b(v);
        }
    } else {
        const int e = (b - 6144) * 256 + t;
        const int mat = e >> 11, r = e & 2047;
        biasAll[e] = (mat == 0 ? Bq : mat == 1 ? Bk : Bv)[r];
    }
}

// ---------------- G32[o][hk] ----------------
__global__ __launch_bounds__(256) void w2g_kernel(
    const float* __restrict__ vmw,
    const float* __restrict__ fw,
    float* __restrict__ G32)
{
    const int t = threadIdx.x;
    const int h = blockIdx.x >> 3;
    const int i0 = (blockIdx.x & 7) * 32;

    __shared__ __align__(16) float xlds[16][40];
    __shared__ float wlds[256][17];

    float acc[32];
#pragma unroll
    for (int r = 0; r < 32; ++r) acc[r] = 0.f;

    const int ar = t >> 3;
    const int ak = (t & 7) * 2;
    const int wk = t & 15;
    const int wo = (t >> 4) * 16;

    for (int d0 = 0; d0 < 256; d0 += 16) {
        xlds[ak][ar]     = vmw[(size_t)(d0 + ak) * 256 + i0 + ar];
        xlds[ak + 1][ar] = vmw[(size_t)(d0 + ak + 1) * 256 + i0 + ar];
#pragma unroll
        for (int j = 0; j < 16; ++j)
            wlds[wo + j][wk] = fw[(size_t)(wo + j) * 2048 + h * 256 + d0 + wk];
        __syncthreads();
#pragma unroll
        for (int kk = 0; kk < 16; ++kk) {
            float bv = wlds[t][kk];
            const float4* xr = (const float4*)(&xlds[kk][0]);
#pragma unroll
            for (int g = 0; g < 8; ++g) {
                float4 xv = xr[g];
                acc[g * 4 + 0] = fmaf(xv.x, bv, acc[g * 4 + 0]);
                acc[g * 4 + 1] = fmaf(xv.y, bv, acc[g * 4 + 1]);
                acc[g * 4 + 2] = fmaf(xv.z, bv, acc[g * 4 + 2]);
                acc[g * 4 + 3] = fmaf(xv.w, bv, acc[g * 4 + 3]);
            }
        }
        __syncthreads();
    }
#pragma unroll
    for (int r = 0; r < 32; ++r)
        G32[(size_t)t * 2048 + h * 256 + i0 + r] = acc[r];
}

// ---------------- bias2 ----------------
__global__ __launch_bounds__(256) void bias2_kernel(
    const float* __restrict__ vmb, const float* __restrict__ fw,
    const float* __restrict__ fb, const float* __restrict__ Bv,
    const float* __restrict__ G32, float* __restrict__ bias2)
{
    const int o = blockIdx.x;
    const int t = threadIdx.x;
    float s = 0.f, sb = 0.f;
#pragma unroll
    for (int i = 0; i < 8; ++i) {
        const int j = t + i * 256;
        s += fw[(size_t)o * 2048 + j];
        sb += Bv[j] * G32[(size_t)o * 2048 + j];
    }
    s = s * vmb[t] + sb;
#pragma unroll
    for (int off = 32; off > 0; off >>= 1) s += __shfl_down(s, off, 64);
    __shared__ float r4[4];
    if ((t & 63) == 0) r4[t >> 6] = s;
    __syncthreads();
    if (t == 0) bias2[o] = fb[o] + r4[0] + r4[1] + r4[2] + r4[3];
}

// ---------------- Mf32[o][i] += sum_k G32[o][k] Wv[k][i] ----------------
__global__ __launch_bounds__(256) void gm_kernel(
    const float* __restrict__ Wv, const float* __restrict__ G32,
    float* __restrict__ Mf32)
{
    __shared__ float Gt[64][33];
    __shared__ float Wt[32][33];
    const int t = threadIdx.x;
    const int o0 = blockIdx.x * 64, i0 = blockIdx.y * 32, k0 = blockIdx.z * 256;
    const int ii = t & 31, og = t >> 5;
    float acc[8] = {};
    for (int kk0 = k0; kk0 < k0 + 256; kk0 += 32) {
#pragma unroll
        for (int r = 0; r < 8; ++r) {
            const int e = t + r * 256;
            Gt[e >> 5][e & 31] = G32[(size_t)(o0 + (e >> 5)) * 2048 + kk0 + (e & 31)];
        }
#pragma unroll
        for (int r = 0; r < 4; ++r) {
            const int e = t + r * 256;
            const int kk = e >> 5, i = i0 + (e & 31);
            Wt[kk][e & 31] = (i < 257) ? Wv[(size_t)(kk0 + kk) * 257 + i] : 0.f;
        }
        __syncthreads();
#pragma unroll
        for (int kk = 0; kk < 32; ++kk) {
            float wv_ = Wt[kk][ii];
#pragma unroll
            for (int r = 0; r < 8; ++r)
                acc[r] = fmaf(Gt[og * 8 + r][kk], wv_, acc[r]);
        }
        __syncthreads();
    }
#pragma unroll
    for (int r = 0; r < 8; ++r)
        atomicAdd(&Mf32[(size_t)(o0 + og * 8 + r) * 288 + i0 + ii], acc[r]);
}

__global__ void gmcvt_kernel(const float* __restrict__ Mf32, unsigned short* __restrict__ Mbf) {
    const int i = blockIdx.x * 256 + threadIdx.x;
    Mbf[i] = f2b(Mf32[i]);
}

// ---------------- staging helpers (R14 dbuf pattern) ----------------
__device__ __forceinline__ void stage_load(
    const float* __restrict__ XA, const unsigned short* __restrict__ WB, int k,
    f32x4a& cx0, f32x4a& cx1, u16x8 cw[4])
{
    cx0 = *(const f32x4a*)(XA + k);
    cx1 = *(const f32x4a*)(XA + k + 4);
#pragma unroll
    for (int qq = 0; qq < 4; ++qq)
        cw[qq] = *(const u16x8*)(WB + (size_t)qq * 64 * 288 + k);
}

__device__ __forceinline__ void stage_write(
    unsigned short* __restrict__ la, unsigned short* __restrict__ lb,
    int ar, int akg, f32x4a cx0, f32x4a cx1, const u16x8 cw[4])
{
    u16x8 pk;
    pk[0] = f2b(cx0[0]); pk[1] = f2b(cx0[1]); pk[2] = f2b(cx0[2]); pk[3] = f2b(cx0[3]);
    pk[4] = f2b(cx1[0]); pk[5] = f2b(cx1[1]); pk[6] = f2b(cx1[2]); pk[7] = f2b(cx1[3]);
    *(u16x8*)(&la[ar * 40 + akg]) = pk;
#pragma unroll
    for (int qq = 0; qq < 4; ++qq)
        *(u16x8*)(&lb[(ar + qq * 64) * 40 + akg]) = cw[qq];
}

// ---------------- merged pass-A projection (DBUF, 1 barrier/K-step) ----------------
// y<8 -> K-head (phi, tiled-transposed + colrep); y<16 -> V-head (tiled vsT);
// y==16 -> xm (f32 rows into out).
__global__ __launch_bounds__(256, 3) void proj_all(
    const float* __restrict__ X,
    const unsigned short* __restrict__ Wbf,
    const unsigned short* __restrict__ Mbf,
    const float* __restrict__ biasAll,
    unsigned short* __restrict__ phiOut,
    unsigned short* __restrict__ vsOut,
    float* __restrict__ xOut,
    const float* __restrict__ nsc,
    float* __restrict__ colrep,
    int CH)
{
    // staging: lA0 @0 (2560), lA1 @2560, lB0 @5120 (10240), lB1 @15360..25600
    // epilogue overlays (post K-loop): tstore/Q-xp @0..16896; reds @16896..
    __shared__ __align__(16) unsigned short smem[25600];
    float* reds2 = (float*)(smem + 16896);  // 256 f
    float* reds4 = reds2 + 256;             // 256 f
    float* rowv  = reds4 + 256;             // 64 f
    float* rowx  = rowv + 64;               // 64 f

    const int t = threadIdx.x;
    const int m0 = blockIdx.x * 64;
    const int y  = blockIdx.y;
    const int lane = t & 63, w = t >> 6;
    const int wn = w * 64;
    const int l15 = lane & 15, q = lane >> 4;
    const int ar = t >> 2, akg = (t & 3) * 8;

    // mode: 0=K-phi 1=V 2=xm
    int mode, hcol;
    const unsigned short* Wb;
    const float* bb;
    if (y < 8)       { mode = 0; hcol = y * 256; Wb = Wbf + (size_t)(2048 + hcol) * 288;       bb = biasAll + 2048 + hcol; }
    else if (y < 16) { mode = 1; hcol = (y - 8) * 256; Wb = Wbf + (size_t)(4096 + hcol) * 288; bb = biasAll + 4096 + hcol; }
    else             { mode = 2; hcol = 0; Wb = Mbf; bb = nullptr; }

    f32x4 acc[4][4] = {};
    const float* XA = X + (size_t)(m0 + ar) * 257 + akg;
    const unsigned short* WB = Wb + (size_t)ar * 288 + akg;

    f32x4a cx0, cx1;
    u16x8 cw[4];

    stage_load(XA, WB, 0, cx0, cx1, cw);
    stage_write(smem, smem + 5120, ar, akg, cx0, cx1, cw);
    stage_load(XA, WB, 32, cx0, cx1, cw);
    __syncthreads();

#pragma unroll
    for (int ks = 0; ks < 8; ++ks) {
        const int b = ks & 1;
        unsigned short* la = smem + (b ? 2560 : 0);
        unsigned short* lb = smem + (b ? 15360 : 5120);
        bf16x8 af[4], bfr[4];
#pragma unroll
        for (int i = 0; i < 4; ++i)
            af[i] = *(const bf16x8*)(&la[(i * 16 + l15) * 40 + q * 8]);
#pragma unroll
        for (int j = 0; j < 4; ++j)
            bfr[j] = *(const bf16x8*)(&lb[(wn + j * 16 + l15) * 40 + q * 8]);
#pragma unroll
        for (int i = 0; i < 4; ++i)
#pragma unroll
            for (int j = 0; j < 4; ++j)
                acc[i][j] = __builtin_amdgcn_mfma_f32_16x16x32_bf16(af[i], bfr[j], acc[i][j], 0, 0, 0);
        if (ks < 7) {
            unsigned short* la2 = smem + (b ? 0 : 2560);
            unsigned short* lb2 = smem + (b ? 5120 : 15360);
            stage_write(la2, lb2, ar, akg, cx0, cx1, cw);
            if (ks < 6) stage_load(XA, WB, (ks + 2) * 32, cx0, cx1, cw);
        }
        __syncthreads();
    }

    if (t < 64) rowx[t] = b2f(f2b(X[(size_t)(m0 + t) * 257 + 256]));
    __syncthreads();

    // rank-1 Lorentz column
    {
        float w256[4];
#pragma unroll
        for (int j = 0; j < 4; ++j)
            w256[j] = b2f(Wb[(size_t)(wn + j * 16 + l15) * 288 + 256]);
#pragma unroll
        for (int i = 0; i < 4; ++i)
#pragma unroll
            for (int r = 0; r < 4; ++r) {
                const float xv = rowx[i * 16 + q * 4 + r];
#pragma unroll
                for (int j = 0; j < 4; ++j)
                    acc[i][j][r] += xv * w256[j];
            }
    }

    if (mode == 2) {
        // xm: f32 row store
#pragma unroll
        for (int j = 0; j < 4; ++j) {
            const int cg = wn + j * 16 + l15;
#pragma unroll
            for (int i = 0; i < 4; ++i)
#pragma unroll
                for (int r = 0; r < 4; ++r) {
                    const int n = m0 + i * 16 + q * 4 + r;
                    xOut[(size_t)n * 257 + 1 + cg] = acc[i][j][r];
                }
        }
        return;
    }

    if (mode == 1) {
        // V: bias, then tiled transposed store
#pragma unroll
        for (int j = 0; j < 4; ++j) {
            const float bias = bb[wn + j * 16 + l15];
#pragma unroll
            for (int i = 0; i < 4; ++i)
#pragma unroll
                for (int r = 0; r < 4; ++r)
                    acc[i][j][r] += bias;
        }
        __syncthreads();
#pragma unroll
        for (int i = 0; i < 4; ++i)
#pragma unroll
            for (int j = 0; j < 4; ++j) {
                const int cl = wn + j * 16 + l15;
#pragma unroll
                for (int r2 = 0; r2 < 4; r2 += 2) {
                    const int nl = i * 16 + q * 4 + r2;
                    const unsigned int pk =
                        (unsigned int)f2b(acc[i][j][r2]) |
                        ((unsigned int)f2b(acc[i][j][r2 + 1]) << 16);
                    *(unsigned int*)(&smem[cl * 64 + (((nl >> 3) ^ (cl & 7)) << 3) + (nl & 7)]) = pk;
                }
            }
        __syncthreads();
#pragma unroll
        for (int k = 0; k < 8; ++k) {
            const int task = k * 256 + t;
            const int cl = task >> 3, nq = task & 7;
            *(u16x8*)(vsOut + (size_t)blockIdx.x * STRIPE +
                      (size_t)(hcol + cl) * 64 + nq * 8) =
                *(const u16x8*)(&smem[cl * 64 + ((nq ^ (cl & 7)) << 3)]);
        }
        return;
    }

    // K-phi
    const float c = fabsf(nsc[0]) + EPSF;
    float bias[4];
#pragma unroll
    for (int j = 0; j < 4; ++j) bias[j] = bb[wn + j * 16 + l15];

    float a2[4][4], a4[4][4];
#pragma unroll
    for (int i = 0; i < 4; ++i)
#pragma unroll
        for (int r = 0; r < 4; ++r) { a2[i][r] = 0.f; a4[i][r] = 0.f; }
#pragma unroll
    for (int i = 0; i < 4; ++i)
#pragma unroll
        for (int j = 0; j < 4; ++j)
#pragma unroll
            for (int r = 0; r < 4; ++r) {
                float uu = fmaxf(acc[i][j][r] + bias[j], 0.f) + EPSF;
                float q2 = uu * uu;
                acc[i][j][r] = q2;
                a2[i][r] += q2;
                a4[i][r] += q2 * q2;
            }
#pragma unroll
    for (int m = 1; m <= 8; m <<= 1) {
#pragma unroll
        for (int i = 0; i < 4; ++i)
#pragma unroll
            for (int r = 0; r < 4; ++r) {
                a2[i][r] += __shfl_xor(a2[i][r], m, 64);
                a4[i][r] += __shfl_xor(a4[i][r], m, 64);
            }
    }
    __syncthreads();   // staging region now free for reds overlay
    if (l15 == 0) {
#pragma unroll
        for (int i = 0; i < 4; ++i)
#pragma unroll
            for (int r = 0; r < 4; ++r) {
                reds2[w * 64 + i * 16 + q * 4 + r] = a2[i][r];
                reds4[w * 64 + i * 16 + q * 4 + r] = a4[i][r];
            }
    }
    __syncthreads();
    if (t < 64) {
        float s2t = reds2[t] + reds2[64 + t] + reds2[128 + t] + reds2[192 + t];
        float s4t = reds4[t] + reds4[64 + t] + reds4[128 + t] + reds4[192 + t];
        rowv[t] = sqrtf(s2t) / (c * sqrtf(s4t));
    }
    __syncthreads();
    float sc_[4][4];
#pragma unroll
    for (int i = 0; i < 4; ++i)
#pragma unroll
        for (int r = 0; r < 4; ++r) sc_[i][r] = rowv[i * 16 + q * 4 + r];

    float colp[4];
#pragma unroll
    for (int j = 0; j < 4; ++j) colp[j] = 0.f;
#pragma unroll
    for (int i = 0; i < 4; ++i)
#pragma unroll
        for (int j = 0; j < 4; ++j)
#pragma unroll
            for (int r = 0; r < 4; ++r) {
                float ph = acc[i][j][r] * sc_[i][r];
                acc[i][j][r] = ph;
                colp[j] += ph;
            }
    // tiled transposed store
#pragma unroll
    for (int i = 0; i < 4; ++i)
#pragma unroll
        for (int j = 0; j < 4; ++j) {
            const int cl = wn + j * 16 + l15;
#pragma unroll
            for (int r2 = 0; r2 < 4; r2 += 2) {
                const int nl = i * 16 + q * 4 + r2;
                const unsigned int pk =
                    (unsigned int)f2b(acc[i][j][r2]) |
                    ((unsigned int)f2b(acc[i][j][r2 + 1]) << 16);
                *(unsigned int*)(&smem[cl * 64 + (((nl >> 3) ^ (cl & 7)) << 3) + (nl & 7)]) = pk;
            }
        }
    __syncthreads();
#pragma unroll
    for (int k = 0; k < 8; ++k) {
        const int task = k * 256 + t;
        const int cl = task >> 3, nq = task & 7;
        *(u16x8*)(phiOut + (size_t)blockIdx.x * STRIPE +
                  (size_t)(hcol + cl) * 64 + nq * 8) =
            *(const u16x8*)(&smem[cl * 64 + ((nq ^ (cl & 7)) << 3)]);
    }
    // colsum replicas
#pragma unroll
    for (int j = 0; j < 4; ++j) {
        colp[j] += __shfl_xor(colp[j], 16, 64);
        colp[j] += __shfl_xor(colp[j], 32, 64);
    }
    if (q == 0) {
        float* dst = colrep + (size_t)(blockIdx.x & 7) * 2048;
#pragma unroll
        for (int j = 0; j < 4; ++j)
            atomicAdd(&dst[hcol + wn + j * 16 + l15], colp[j]);
    }
}

// ---------------- pass-B Q projection + fused phi (R15 verbatim, mode 1) ----------------
__global__ __launch_bounds__(256) void proj_phi(
    const float* __restrict__ X,
    const unsigned short* __restrict__ Wbase,
    const float* __restrict__ biasBase,
    unsigned short* __restrict__ outbuf,
    const float* __restrict__ nsc,
    const float* __restrict__ colsum_in,
    int CH)
{
    __shared__ __align__(16) unsigned short smem[16896];
    __shared__ float reds2[4][64];
    __shared__ float reds4[4][64];
    __shared__ float rowv[64];
    __shared__ float rowx[64];
    unsigned short* lA = smem;
    unsigned short* lB = smem + 64 * 40;

    const int t = threadIdx.x;
    const int m0 = blockIdx.x * 64;
    const int h  = blockIdx.y;
    const int lane = t & 63, w = t >> 6;
    const int wn = w * 64;
    const int l15 = lane & 15, q = lane >> 4;
    const int ar = t >> 2, akg = (t & 3) * 8;

    f32x4 acc[4][4] = {};
    const float* XA = X + (size_t)(m0 + ar) * 257 + akg;
    const unsigned short* WB = Wbase + (size_t)(h * 256 + ar) * 288 + akg;

    f32x4a cx0, cx1;
    u16x8 cw[4];
    cx0 = *(const f32x4a*)(XA);
    cx1 = *(const f32x4a*)(XA + 4);
#pragma unroll
    for (int qq = 0; qq < 4; ++qq)
        cw[qq] = *(const u16x8*)(WB + (size_t)qq * 64 * 288);

    for (int ks = 0; ks < 8; ++ks) {
        {
            u16x8 pk;
            pk[0] = f2b(cx0[0]); pk[1] = f2b(cx0[1]);
            pk[2] = f2b(cx0[2]); pk[3] = f2b(cx0[3]);
            pk[4] = f2b(cx1[0]); pk[5] = f2b(cx1[1]);
            pk[6] = f2b(cx1[2]); pk[7] = f2b(cx1[3]);
            *(u16x8*)(&lA[ar * 40 + akg]) = pk;
        }
#pragma unroll
        for (int qq = 0; qq < 4; ++qq)
            *(u16x8*)(&lB[(ar + qq * 64) * 40 + akg]) = cw[qq];
        if (ks < 7) {
            const int k1 = (ks + 1) * 32;
            cx0 = *(const f32x4a*)(XA + k1);
            cx1 = *(const f32x4a*)(XA + k1 + 4);
#pragma unroll
            for (int qq = 0; qq < 4; ++qq)
                cw[qq] = *(const u16x8*)(WB + (size_t)qq * 64 * 288 + k1);
        }
        __syncthreads();
        bf16x8 af[4], bfr[4];
#pragma unroll
        for (int i = 0; i < 4; ++i)
            af[i] = *(const bf16x8*)(&lA[(i * 16 + l15) * 40 + q * 8]);
#pragma unroll
        for (int j = 0; j < 4; ++j)
            bfr[j] = *(const bf16x8*)(&lB[(wn + j * 16 + l15) * 40 + q * 8]);
#pragma unroll
        for (int i = 0; i < 4; ++i)
#pragma unroll
            for (int j = 0; j < 4; ++j)
                acc[i][j] = __builtin_amdgcn_mfma_f32_16x16x32_bf16(af[i], bfr[j], acc[i][j], 0, 0, 0);
        __syncthreads();
    }

    if (t < 64) rowx[t] = b2f(f2b(X[(size_t)(m0 + t) * 257 + 256]));
    __syncthreads();

    {
        float w256[4];
#pragma unroll
        for (int j = 0; j < 4; ++j)
            w256[j] = b2f(Wbase[(size_t)(h * 256 + wn + j * 16 + l15) * 288 + 256]);
#pragma unroll
        for (int i = 0; i < 4; ++i)
#pragma unroll
            for (int r = 0; r < 4; ++r) {
                const float xv = rowx[i * 16 + q * 4 + r];
#pragma unroll
                for (int j = 0; j < 4; ++j)
                    acc[i][j][r] += xv * w256[j];
            }
    }

    const float c = fabsf(nsc[0]) + EPSF;
    float bias[4];
#pragma unroll
    for (int j = 0; j < 4; ++j) bias[j] = biasBase[h * 256 + wn + j * 16 + l15];

    float a2[4][4], a4[4][4];
#pragma unroll
    for (int i = 0; i < 4; ++i)
#pragma unroll
        for (int r = 0; r < 4; ++r) { a2[i][r] = 0.f; a4[i][r] = 0.f; }
#pragma unroll
    for (int i = 0; i < 4; ++i)
#pragma unroll
        for (int j = 0; j < 4; ++j)
#pragma unroll
            for (int r = 0; r < 4; ++r) {
                float uu = fmaxf(acc[i][j][r] + bias[j], 0.f) + EPSF;
                float q2 = uu * uu;
                acc[i][j][r] = q2;
                a2[i][r] += q2;
                a4[i][r] += q2 * q2;
            }
#pragma unroll
    for (int m = 1; m <= 8; m <<= 1) {
#pragma unroll
        for (int i = 0; i < 4; ++i)
#pragma unroll
            for (int r = 0; r < 4; ++r) {
                a2[i][r] += __shfl_xor(a2[i][r], m, 64);
                a4[i][r] += __shfl_xor(a4[i][r], m, 64);
            }
    }
    if (l15 == 0) {
#pragma unroll
        for (int i = 0; i < 4; ++i)
#pragma unroll
            for (int r = 0; r < 4; ++r) {
                reds2[w][i * 16 + q * 4 + r] = a2[i][r];
                reds4[w][i * 16 + q * 4 + r] = a4[i][r];
            }
    }
    __syncthreads();
    if (t < 64) {
        float s2t = reds2[0][t] + reds2[1][t] + reds2[2][t] + reds2[3][t];
        float s4t = reds4[0][t] + reds4[1][t] + reds4[2][t] + reds4[3][t];
        rowv[t] = sqrtf(s2t) / (c * sqrtf(s4t));
    }
    __syncthreads();
    float sc_[4][4];
#pragma unroll
    for (int i = 0; i < 4; ++i)
#pragma unroll
        for (int r = 0; r < 4; ++r) sc_[i][r] = rowv[i * 16 + q * 4 + r];

    float cs[4];
#pragma unroll
    for (int j = 0; j < 4; ++j) cs[j] = colsum_in[h * 256 + wn + j * 16 + l15];
    float dp[4][4];
#pragma unroll
    for (int i = 0; i < 4; ++i)
#pragma unroll
        for (int r = 0; r < 4; ++r) dp[i][r] = 0.f;
#pragma unroll
    for (int i = 0; i < 4; ++i)
#pragma unroll
        for (int j = 0; j < 4; ++j)
#pragma unroll
            for (int r = 0; r < 4; ++r) {
                float ph = acc[i][j][r] * sc_[i][r];
                acc[i][j][r] = ph;
                dp[i][r] += ph * cs[j];
            }
#pragma unroll
    for (int m = 1; m <= 8; m <<= 1) {
#pragma unroll
        for (int i = 0; i < 4; ++i)
#pragma unroll
            for (int r = 0; r < 4; ++r)
                dp[i][r] += __shfl_xor(dp[i][r], m, 64);
    }
    if (l15 == 0) {
#pragma unroll
        for (int i = 0; i < 4; ++i)
#pragma unroll
            for (int r = 0; r < 4; ++r)
                reds2[w][i * 16 + q * 4 + r] = dp[i][r];
    }
    __syncthreads();
    if (t < 64) {
        float dt = reds2[0][t] + reds2[1][t] + reds2[2][t] + reds2[3][t];
        rowv[t] = 1.f / (dt + EPSF);
    }
    __syncthreads();
#pragma unroll
    for (int i = 0; i < 4; ++i)
#pragma unroll
        for (int r = 0; r < 4; ++r) sc_[i][r] = rowv[i * 16 + q * 4 + r];
    // coalesced row-major store via padded LDS transpose
#pragma unroll
    for (int i = 0; i < 4; ++i)
#pragma unroll
        for (int j = 0; j < 4; ++j) {
            const int cl = wn + j * 16 + l15;
#pragma unroll
            for (int r = 0; r < 4; ++r) {
                const int nl = i * 16 + q * 4 + r;
                smem[nl * 264 + cl] = f2b(acc[i][j][r] * sc_[i][r]);
            }
        }
    __syncthreads();
#pragma unroll
    for (int k = 0; k < 8; ++k) {
        const int task = k * 256 + t;
        const int rowl = task >> 5, ck = (task & 31) * 8;
        *(u16x8*)(outbuf + (size_t)(m0 + rowl) * 2048 + h * 256 + ck) =
            *(const u16x8*)(&smem[rowl * 264 + ck]);
    }
}

// ---------------- merge colsum replicas ----------------
__global__ __launch_bounds__(256) void merge_colsum(
    const float* __restrict__ rep, float* __restrict__ out)
{
    const int cidx = blockIdx.x * 256 + threadIdx.x;
    float s = 0.f;
#pragma unroll
    for (int r = 0; r < 8; ++r) s += rep[(size_t)r * 2048 + cidx];
    out[cidx] = s;
}

// ---------------- ktv MFMA: tiled reads, prefetched ----------------
__global__ __launch_bounds__(256) void ktv_mfma(
    const unsigned short* __restrict__ phiT,   // tiled [CH/64][2048][64]
    const unsigned short* __restrict__ vsT,
    float* __restrict__ ktv, int CH)
{
    __shared__ __align__(16) unsigned short lAT[128 * 64];
    __shared__ __align__(16) unsigned short lBT[128 * 64];
    const int t = threadIdx.x;
    const int h = blockIdx.y;
    const int split = blockIdx.x >> 2;
    const int tile = blockIdx.x & 3;
    const int m0 = (tile >> 1) * 128, d0 = (tile & 1) * 128;
    const int chh = h * 256;
    const int lane = t & 63, w = t >> 6;
    const int wm = (w >> 1) * 64, wn = (w & 1) * 64;
    const int l15 = lane & 15, q = lane >> 4;
    const int sl7 = l15 & 7;

    const int scg  = t >> 3;
    const int snq  = t & 7;
    const int sbase = scg * 64 + ((snq ^ (scg & 7)) << 3);

    f32x4 acc[4][4] = {};
    const int st0 = split * 8;

    const unsigned short* pA = phiT + (size_t)(chh + m0 + scg) * 64 + snq * 8;
    const unsigned short* pB = vsT  + (size_t)(chh + d0 + scg) * 64 + snq * 8;

    u16x8 cA[4], cB[4], nA[4], nB[4];
#pragma unroll
    for (int k = 0; k < 4; ++k) {
        cA[k] = *(const u16x8*)(pA + (size_t)st0 * STRIPE + k * 2048);
        cB[k] = *(const u16x8*)(pB + (size_t)st0 * STRIPE + k * 2048);
    }

    for (int it = 0; it < 8; ++it) {
#pragma unroll
        for (int k = 0; k < 4; ++k) {
            *(u16x8*)(&lAT[k * 2048 + sbase]) = cA[k];
            *(u16x8*)(&lBT[k * 2048 + sbase]) = cB[k];
        }
        if (it < 7) {
            const size_t so = (size_t)(st0 + it + 1) * STRIPE;
#pragma unroll
            for (int k = 0; k < 4; ++k) {
                nA[k] = *(const u16x8*)(pA + so + k * 2048);
                nB[k] = *(const u16x8*)(pB + so + k * 2048);
            }
        }
        __syncthreads();
#pragma unroll
        for (int sub = 0; sub < 2; ++sub) {
            const int slot = ((sub * 4 + q) ^ sl7) << 3;
            bf16x8 af[4], bfr[4];
#pragma unroll
            for (int i = 0; i < 4; ++i)
                af[i] = *(const bf16x8*)(&lAT[(wm + i * 16 + l15) * 64 + slot]);
#pragma unroll
            for (int j = 0; j < 4; ++j)
                bfr[j] = *(const bf16x8*)(&lBT[(wn + j * 16 + l15) * 64 + slot]);
#pragma unroll
            for (int i = 0; i < 4; ++i)
#pragma unroll
                for (int j = 0; j < 4; ++j)
                    acc[i][j] = __builtin_amdgcn_mfma_f32_16x16x32_bf16(af[i], bfr[j], acc[i][j], 0, 0, 0);
        }
        __syncthreads();
        if (it < 7) {
#pragma unroll
            for (int k = 0; k < 4; ++k) { cA[k] = nA[k]; cB[k] = nB[k]; }
        }
    }
#pragma unroll
    for (int i = 0; i < 4; ++i)
#pragma unroll
        for (int j = 0; j < 4; ++j)
#pragma unroll
            for (int r = 0; r < 4; ++r) {
                const int m = m0 + wm + i * 16 + q * 4 + r;
                const int d = d0 + wn + j * 16 + l15;
                atomicAdd(&ktv[((size_t)chh + m) * 256 + d], acc[i][j][r]);
            }
}

// ---------------- final staging load ----------------
__device__ __forceinline__ void fin_load(
    const unsigned short* __restrict__ Abuf, const unsigned short* __restrict__ W2T,
    int n0, int d0, int t, int k0,
    u16x8& A0, u16x8& A1, u16x8& B)
{
    {
        const int row = t >> 2, kg = (t & 3) * 8;
        A0 = *(const u16x8*)(Abuf + (size_t)(n0 + row) * 2048 + ((k0 + kg) & 2047));
    }
    {
        const int e = t + 256;
        const int row = e >> 2, kg = (e & 3) * 8;
        A1 = *(const u16x8*)(Abuf + (size_t)(n0 + row) * 2048 + ((k0 + kg) & 2047));
    }
    {
        const int row = t >> 2, kg = (t & 3) * 8;
        B = *(const u16x8*)(W2T + (size_t)(d0 + row) * 4096 + k0 + kg);
    }
}

// ---------------- final MFMA GEMM 128x64 (reg-prefetch, split-K x2, atomic) ----------------
__global__ __launch_bounds__(256) void final_mfma(
    const unsigned short* __restrict__ Abuf,
    const unsigned short* __restrict__ W2T,
    int kbeg, int kend,
    float* __restrict__ outp)
{
    __shared__ __align__(16) unsigned short lA[128 * 40];
    __shared__ __align__(16) unsigned short lB[64 * 40];
    const int t = threadIdx.x;
    const int n0 = blockIdx.x * 128;
    const int d0 = blockIdx.y * 64;
    const int khalf = (kend - kbeg) >> 1;
    const int kb = kbeg + blockIdx.z * khalf;
    const int ke = kb + khalf;
    const int lane = t & 63, w = t >> 6;
    const int wm = w * 32;
    const int l15 = lane & 15, q = lane >> 4;

    f32x4 acc[2][4] = {};
    u16x8 cA0, cA1, cB, nA0, nA1, nB;
    fin_load(Abuf, W2T, n0, d0, t, kb, cA0, cA1, cB);

    for (int k0 = kb; k0 < ke; k0 += 32) {
        {
            const int row = t >> 2, kg = (t & 3) * 8;
            *(u16x8*)(&lA[row * 40 + kg]) = cA0;
            *(u16x8*)(&lB[row * 40 + kg]) = cB;
        }
        {
            const int e = t + 256;
            const int row = e >> 2, kg = (e & 3) * 8;
            *(u16x8*)(&lA[row * 40 + kg]) = cA1;
        }
        if (k0 + 32 < ke)
            fin_load(Abuf, W2T, n0, d0, t, k0 + 32, nA0, nA1, nB);
        __syncthreads();
        bf16x8 af[2], bfr[4];
#pragma unroll
        for (int i = 0; i < 2; ++i)
            af[i] = *(const bf16x8*)(&lA[(wm + i * 16 + l15) * 40 + q * 8]);
#pragma unroll
        for (int j = 0; j < 4; ++j)
            bfr[j] = *(const bf16x8*)(&lB[(j * 16 + l15) * 40 + q * 8]);
#pragma unroll
        for (int i = 0; i < 2; ++i)
#pragma unroll
            for (int j = 0; j < 4; ++j)
                acc[i][j] = __builtin_amdgcn_mfma_f32_16x16x32_bf16(af[i], bfr[j], acc[i][j], 0, 0, 0);
        __syncthreads();
        if (k0 + 32 < ke) { cA0 = nA0; cA1 = nA1; cB = nB; }
    }
#pragma unroll
    for (int i = 0; i < 2; ++i)
#pragma unroll
        for (int j = 0; j < 4; ++j)
#pragma unroll
            for (int r = 0; r < 4; ++r) {
                const int n = n0 + wm + i * 16 + q * 4 + r;
                const int d = d0 + j * 16 + l15;
                atomicAdd(&outp[(size_t)n * 257 + 1 + d], acc[i][j][r]);
            }
}

// ---------------- W2T upper = ktv_h @ F_h^T (bf16) ----------------
__global__ __launch_bounds__(256) void w2u_kernel(
    const float* __restrict__ ktv,
    const float* __restrict__ fw,
    unsigned short* __restrict__ W2T)
{
    const int t = threadIdx.x;
    const int h = blockIdx.x >> 3;
    const int m0 = (blockIdx.x & 7) * 32;

    __shared__ __align__(16) float xlds[16][40];
    __shared__ float wlds[256][17];

    float acc[32];
#pragma unroll
    for (int r = 0; r < 32; ++r) acc[r] = 0.f;

    const int ar = t >> 3;
    const int ak = (t & 7) * 2;
    const int wk = t & 15;
    const int wo = (t >> 4) * 16;

    for (int d0 = 0; d0 < 256; d0 += 16) {
        {
            const float* src = ktv + (size_t)(h * 256 + m0 + ar) * 256 + d0 + ak;
            xlds[ak][ar]     = src[0];
            xlds[ak + 1][ar] = src[1];
        }
#pragma unroll
        for (int j = 0; j < 16; ++j)
            wlds[wo + j][wk] = fw[(size_t)(wo + j) * 2048 + h * 256 + d0 + wk];
        __syncthreads();
#pragma unroll
        for (int kk = 0; kk < 16; ++kk) {
            float bv = wlds[t][kk];
            const float4* xr = (const float4*)(&xlds[kk][0]);
#pragma unroll
            for (int g = 0; g < 8; ++g) {
                float4 xv = xr[g];
                acc[g * 4 + 0] = fmaf(xv.x, bv, acc[g * 4 + 0]);
                acc[g * 4 + 1] = fmaf(xv.y, bv, acc[g * 4 + 1]);
                acc[g * 4 + 2] = fmaf(xv.z, bv, acc[g * 4 + 2]);
                acc[g * 4 + 3] = fmaf(xv.w, bv, acc[g * 4 + 3]);
            }
        }
        __syncthreads();
    }
#pragma unroll
    for (int r = 0; r < 32; ++r)
        W2T[(size_t)t * 4096 + h * 256 + m0 + r] = f2b(acc[r]);
}

// ---------------- epilogue: bias + Lorentz lift ----------------
__global__ __launch_bounds__(256) void lift_kernel(
    const float* __restrict__ bias2, float* __restrict__ outp)
{
    const int t = threadIdx.x;
    const int lane = t & 63;
    const int w = t >> 6;
    const int n0 = blockIdx.x * 64 + w * 16;
    float b[4];
#pragma unroll
    for (int j = 0; j < 4; ++j) b[j] = bias2[lane + j * 64];
    for (int r = 0; r < 16; ++r) {
        float* row = outp + (size_t)(n0 + r) * 257;
        float v[4];
        float s = 0.f;
#pragma unroll
        for (int j = 0; j < 4; ++j) {
            v[j] = row[1 + lane + j * 64] + b[j];
            s = fmaf(v[j], v[j], s);
        }
#pragma unroll
        for (int off = 32; off > 0; off >>= 1) s += __shfl_down(s, off, 64);
#pragma unroll
        for (int j = 0; j < 4; ++j) row[1 + lane + j * 64] = v[j];
        if (lane == 0) row[0] = sqrtf(s + 1.0f);
    }
}

extern "C" void kernel_launch(void* const* d_in, const int* in_sizes, int n_in,
                              void* d_out, int out_size, void* d_ws, size_t ws_size,
                              hipStream_t stream)
{
    const float* xq  = (const float*)d_in[0];
    const float* xs  = (const float*)d_in[1];
    const float* Wq  = (const float*)d_in[2];
    const float* Bq  = (const float*)d_in[3];
    const float* Wk  = (const float*)d_in[4];
    const float* Bk  = (const float*)d_in[5];
    const float* Wv  = (const float*)d_in[6];
    const float* Bv  = (const float*)d_in[7];
    const float* nsc = (const float*)d_in[8];
    const float* vmw = (const float*)d_in[9];
    const float* vmb = (const float*)d_in[10];
    const float* fw  = (const float*)d_in[11];
    const float* fb  = (const float*)d_in[12];
    float* outp = (float*)d_out;

    char* ws = (char*)d_ws;
    float* ktv          = (float*)(ws + 0);                 // 2,097,152
    float* colrep       = (float*)(ws + 2097152);           //    65,536
    float* Mf32         = (float*)(ws + 2162688);           //   294,912
    float* colsum       = (float*)(ws + 2457600);           //     8,192
    float* bias2        = (float*)(ws + 2465792);           //     1,024
    float* biasAll      = (float*)(ws + 2466816);           //    24,576
    unsigned short* W2T = (unsigned short*)(ws + 2491392);  // 2,097,152
    unsigned short* Wbf = (unsigned short*)(ws + 4588544);  // 3,538,944
    float* G32          = (float*)(ws + 8127488);           // 2,097,152
    unsigned short* Mbf = (unsigned short*)(ws + 10224640); //   147,456
    const size_t fixedBytes = 10372096;

    int CH = 2048;
    if      (ws_size >= fixedBytes + (size_t)8192 * 8192)  CH = 8192;
    else if (ws_size >= fixedBytes + (size_t)4096 * 8192)  CH = 4096;
    const int NCHK = 32768 / CH;
    unsigned short* phibuf = (unsigned short*)(ws + fixedBytes);
    unsigned short* vsT    = (unsigned short*)(ws + fixedBytes + (size_t)CH * 4096);

    // zero ktv + colrep + Mf32 (contiguous 614400 floats)
    zero_kernel<<<dim3(2400), 256, 0, stream>>>(ktv, 614400);
    wconv_kernel<<<dim3(6168), 256, 0, stream>>>(Wq, Wk, Wv, Bq, Bk, Bv, Wbf, biasAll);
    w2g_kernel<<<dim3(64), 256, 0, stream>>>(vmw, fw, G32);
    bias2_kernel<<<dim3(256), 256, 0, stream>>>(vmb, fw, fb, Bv, G32, bias2);
    gm_kernel<<<dim3(4, 9, 8), 256, 0, stream>>>(Wv, G32, Mf32);
    gmcvt_kernel<<<dim3(288), 256, 0, stream>>>(Mf32, Mbf);

    // Pass A: merged K-phi / V / xm (dbuf) in ONE dispatch per chunk, then ktv
    for (int c = 0; c < NCHK; ++c) {
        const float* xs_c = xs + (size_t)c * CH * 257;
        float* out_c = outp + (size_t)c * CH * 257;
        proj_all<<<dim3(CH / 64, 17), 256, 0, stream>>>(
            xs_c, Wbf, Mbf, biasAll, phibuf, vsT, out_c, nsc, colrep, CH);
        ktv_mfma<<<dim3((CH / 512) * 4, 8), 256, 0, stream>>>(phibuf, vsT, ktv, CH);
    }

    // merge colsum replicas; ktv-dependent weights
    merge_colsum<<<dim3(8), 256, 0, stream>>>(colrep, colsum);
    w2u_kernel<<<dim3(64), 256, 0, stream>>>(ktv, fw, W2T);

    // Pass B: Q-phi (R15 verified kernel) + final (split-K x2)
    for (int c = 0; c < NCHK; ++c) {
        const float* xq_c = xq + (size_t)c * CH * 257;
        float* out_c = outp + (size_t)c * CH * 257;
        proj_phi<<<dim3(CH / 64, 8), 256, 0, stream>>>(
            xq_c, Wbf, biasAll, phibuf, nsc, colsum, CH);
        final_mfma<<<dim3(CH / 128, 4, 2), 256, 0, stream>>>(phibuf, W2T, 0, 2048, out_c);
    }

    // bias + Lorentz lift
    lift_kernel<<<dim3(512), 256, 0, stream>>>(bias2, outp);
}

// Round 11
// 937.480 us; speedup vs baseline: 1.3676x; 1.0063x over previous
//
#include <hip/hip_runtime.h>
#include <hip/hip_bf16.h>

// DHHT round 18: extend the verified dbuf 1-barrier K-loop to pass B.
//  - R17 proved (R14 90us / R16 173us / R17 70.8us): these skinny-K proj
//    GEMMs are barrier-drain-bound; dbuf 1-barrier halves them. Pass A done.
//  - proj_q: pass-B Q projection on proj_all's dbuf skeleton (51KB overlay
//    LDS, launch_bounds(256,3)) + R15's verified Q epilogue (dp/invden,
//    padded-LDS coalesced row-major store).
//  - final_mfma: dbuf 1-barrier (30.7KB LDS), split-K x2 retained.
//  - Everything else byte-identical to R17 (943us verified).
// W2T bf16 [256][4096]: cols 0..2047 = W2u (ktv@F^T). G lives in G32 (f32).

#define EPSF 1e-6f

typedef __attribute__((ext_vector_type(8))) short bf16x8;
typedef __attribute__((ext_vector_type(8))) unsigned short u16x8;
typedef __attribute__((ext_vector_type(4))) float f32x4;
typedef float f32x4a __attribute__((ext_vector_type(4), aligned(4)));

#define STRIPE 131072  // 2048 cols * 64 n (u16) = 256 KB per n-stripe

__device__ __forceinline__ float b2f(unsigned short u) {
    union { unsigned int i; float f; } c;
    c.i = ((unsigned int)u) << 16;
    return c.f;
}
__device__ __forceinline__ unsigned short f2b(float f) {
    __hip_bfloat16 h = __float2bfloat16(f);
    union { __hip_bfloat16 h; unsigned short u; } c;
    c.h = h;
    return c.u;
}

__global__ void zero_kernel(float* __restrict__ p, int n) {
    int i = blockIdx.x * 256 + threadIdx.x;
    if (i < n) p[i] = 0.f;
}

// ---------------- weight convert: Wbf [6144][288] bf16 + biasAll[6144] ----------------
__global__ __launch_bounds__(256) void wconv_kernel(
    const float* __restrict__ Wq, const float* __restrict__ Wk, const float* __restrict__ Wv,
    const float* __restrict__ Bq, const float* __restrict__ Bk, const float* __restrict__ Bv,
    unsigned short* __restrict__ Wbf, float* __restrict__ biasAll)
{
    const int t = threadIdx.x;
    const int b = blockIdx.x;
    if (b < 6144) {
        const int mat = b >> 11, lr = b & 2047;
        const float* Ws = (mat == 0 ? Wq : mat == 1 ? Wk : Wv) + (size_t)lr * 257;
        Wbf[(size_t)b * 288 + t] = f2b(Ws[t]);
        if (t < 32) {
            float v = (t == 0) ? Ws[256] : 0.f;
            Wbf[(size_t)b * 288 + 256 + t] = f2b(v);
        }
    } else {
        const int e = (b - 6144) * 256 + t;
        const int mat = e >> 11, r = e & 2047;
        biasAll[e] = (mat == 0 ? Bq : mat == 1 ? Bk : Bv)[r];
    }
}

// ---------------- G32[o][hk] ----------------
__global__ __launch_bounds__(256) void w2g_kernel(
    const float* __restrict__ vmw,
    const float* __restrict__ fw,
    float* __restrict__ G32)
{
    const int t = threadIdx.x;
    const int h = blockIdx.x >> 3;
    const int i0 = (blockIdx.x & 7) * 32;

    __shared__ __align__(16) float xlds[16][40];
    __shared__ float wlds[256][17];

    float acc[32];
#pragma unroll
    for (int r = 0; r < 32; ++r) acc[r] = 0.f;

    const int ar = t >> 3;
    const int ak = (t & 7) * 2;
    const int wk = t & 15;
    const int wo = (t >> 4) * 16;

    for (int d0 = 0; d0 < 256; d0 += 16) {
        xlds[ak][ar]     = vmw[(size_t)(d0 + ak) * 256 + i0 + ar];
        xlds[ak + 1][ar] = vmw[(size_t)(d0 + ak + 1) * 256 + i0 + ar];
#pragma unroll
        for (int j = 0; j < 16; ++j)
            wlds[wo + j][wk] = fw[(size_t)(wo + j) * 2048 + h * 256 + d0 + wk];
        __syncthreads();
#pragma unroll
        for (int kk = 0; kk < 16; ++kk) {
            float bv = wlds[t][kk];
            const float4* xr = (const float4*)(&xlds[kk][0]);
#pragma unroll
            for (int g = 0; g < 8; ++g) {
                float4 xv = xr[g];
                acc[g * 4 + 0] = fmaf(xv.x, bv, acc[g * 4 + 0]);
                acc[g * 4 + 1] = fmaf(xv.y, bv, acc[g * 4 + 1]);
                acc[g * 4 + 2] = fmaf(xv.z, bv, acc[g * 4 + 2]);
                acc[g * 4 + 3] = fmaf(xv.w, bv, acc[g * 4 + 3]);
            }
        }
        __syncthreads();
    }
#pragma unroll
    for (int r = 0; r < 32; ++r)
        G32[(size_t)t * 2048 + h * 256 + i0 + r] = acc[r];
}

// ---------------- bias2 ----------------
__global__ __launch_bounds__(256) void bias2_kernel(
    const float* __restrict__ vmb, const float* __restrict__ fw,
    const float* __restrict__ fb, const float* __restrict__ Bv,
    const float* __restrict__ G32, float* __restrict__ bias2)
{
    const int o = blockIdx.x;
    const int t = threadIdx.x;
    float s = 0.f, sb = 0.f;
#pragma unroll
    for (int i = 0; i < 8; ++i) {
        const int j = t + i * 256;
        s += fw[(size_t)o * 2048 + j];
        sb += Bv[j] * G32[(size_t)o * 2048 + j];
    }
    s = s * vmb[t] + sb;
#pragma unroll
    for (int off = 32; off > 0; off >>= 1) s += __shfl_down(s, off, 64);
    __shared__ float r4[4];
    if ((t & 63) == 0) r4[t >> 6] = s;
    __syncthreads();
    if (t == 0) bias2[o] = fb[o] + r4[0] + r4[1] + r4[2] + r4[3];
}

// ---------------- Mf32[o][i] += sum_k G32[o][k] Wv[k][i] ----------------
__global__ __launch_bounds__(256) void gm_kernel(
    const float* __restrict__ Wv, const float* __restrict__ G32,
    float* __restrict__ Mf32)
{
    __shared__ float Gt[64][33];
    __shared__ float Wt[32][33];
    const int t = threadIdx.x;
    const int o0 = blockIdx.x * 64, i0 = blockIdx.y * 32, k0 = blockIdx.z * 256;
    const int ii = t & 31, og = t >> 5;
    float acc[8] = {};
    for (int kk0 = k0; kk0 < k0 + 256; kk0 += 32) {
#pragma unroll
        for (int r = 0; r < 8; ++r) {
            const int e = t + r * 256;
            Gt[e >> 5][e & 31] = G32[(size_t)(o0 + (e >> 5)) * 2048 + kk0 + (e & 31)];
        }
#pragma unroll
        for (int r = 0; r < 4; ++r) {
            const int e = t + r * 256;
            const int kk = e >> 5, i = i0 + (e & 31);
            Wt[kk][e & 31] = (i < 257) ? Wv[(size_t)(kk0 + kk) * 257 + i] : 0.f;
        }
        __syncthreads();
#pragma unroll
        for (int kk = 0; kk < 32; ++kk) {
            float wv_ = Wt[kk][ii];
#pragma unroll
            for (int r = 0; r < 8; ++r)
                acc[r] = fmaf(Gt[og * 8 + r][kk], wv_, acc[r]);
        }
        __syncthreads();
    }
#pragma unroll
    for (int r = 0; r < 8; ++r)
        atomicAdd(&Mf32[(size_t)(o0 + og * 8 + r) * 288 + i0 + ii], acc[r]);
}

__global__ void gmcvt_kernel(const float* __restrict__ Mf32, unsigned short* __restrict__ Mbf) {
    const int i = blockIdx.x * 256 + threadIdx.x;
    Mbf[i] = f2b(Mf32[i]);
}

// ---------------- staging helpers (dbuf pattern) ----------------
__device__ __forceinline__ void stage_load(
    const float* __restrict__ XA, const unsigned short* __restrict__ WB, int k,
    f32x4a& cx0, f32x4a& cx1, u16x8 cw[4])
{
    cx0 = *(const f32x4a*)(XA + k);
    cx1 = *(const f32x4a*)(XA + k + 4);
#pragma unroll
    for (int qq = 0; qq < 4; ++qq)
        cw[qq] = *(const u16x8*)(WB + (size_t)qq * 64 * 288 + k);
}

__device__ __forceinline__ void stage_write(
    unsigned short* __restrict__ la, unsigned short* __restrict__ lb,
    int ar, int akg, f32x4a cx0, f32x4a cx1, const u16x8 cw[4])
{
    u16x8 pk;
    pk[0] = f2b(cx0[0]); pk[1] = f2b(cx0[1]); pk[2] = f2b(cx0[2]); pk[3] = f2b(cx0[3]);
    pk[4] = f2b(cx1[0]); pk[5] = f2b(cx1[1]); pk[6] = f2b(cx1[2]); pk[7] = f2b(cx1[3]);
    *(u16x8*)(&la[ar * 40 + akg]) = pk;
#pragma unroll
    for (int qq = 0; qq < 4; ++qq)
        *(u16x8*)(&lb[(ar + qq * 64) * 40 + akg]) = cw[qq];
}

// ---------------- merged pass-A projection (DBUF, 1 barrier/K-step) ----------------
// y<8 -> K-head (phi, tiled-transposed + colrep); y<16 -> V-head (tiled vsT);
// y==16 -> xm (f32 rows into out).
__global__ __launch_bounds__(256, 3) void proj_all(
    const float* __restrict__ X,
    const unsigned short* __restrict__ Wbf,
    const unsigned short* __restrict__ Mbf,
    const float* __restrict__ biasAll,
    unsigned short* __restrict__ phiOut,
    unsigned short* __restrict__ vsOut,
    float* __restrict__ xOut,
    const float* __restrict__ nsc,
    float* __restrict__ colrep,
    int CH)
{
    __shared__ __align__(16) unsigned short smem[25600];
    float* reds2 = (float*)(smem + 16896);
    float* reds4 = reds2 + 256;
    float* rowv  = reds4 + 256;
    float* rowx  = rowv + 64;

    const int t = threadIdx.x;
    const int m0 = blockIdx.x * 64;
    const int y  = blockIdx.y;
    const int lane = t & 63, w = t >> 6;
    const int wn = w * 64;
    const int l15 = lane & 15, q = lane >> 4;
    const int ar = t >> 2, akg = (t & 3) * 8;

    int mode, hcol;
    const unsigned short* Wb;
    const float* bb;
    if (y < 8)       { mode = 0; hcol = y * 256; Wb = Wbf + (size_t)(2048 + hcol) * 288;       bb = biasAll + 2048 + hcol; }
    else if (y < 16) { mode = 1; hcol = (y - 8) * 256; Wb = Wbf + (size_t)(4096 + hcol) * 288; bb = biasAll + 4096 + hcol; }
    else             { mode = 2; hcol = 0; Wb = Mbf; bb = nullptr; }

    f32x4 acc[4][4] = {};
    const float* XA = X + (size_t)(m0 + ar) * 257 + akg;
    const unsigned short* WB = Wb + (size_t)ar * 288 + akg;

    f32x4a cx0, cx1;
    u16x8 cw[4];

    stage_load(XA, WB, 0, cx0, cx1, cw);
    stage_write(smem, smem + 5120, ar, akg, cx0, cx1, cw);
    stage_load(XA, WB, 32, cx0, cx1, cw);
    __syncthreads();

#pragma unroll
    for (int ks = 0; ks < 8; ++ks) {
        const int b = ks & 1;
        unsigned short* la = smem + (b ? 2560 : 0);
        unsigned short* lb = smem + (b ? 15360 : 5120);
        bf16x8 af[4], bfr[4];
#pragma unroll
        for (int i = 0; i < 4; ++i)
            af[i] = *(const bf16x8*)(&la[(i * 16 + l15) * 40 + q * 8]);
#pragma unroll
        for (int j = 0; j < 4; ++j)
            bfr[j] = *(const bf16x8*)(&lb[(wn + j * 16 + l15) * 40 + q * 8]);
#pragma unroll
        for (int i = 0; i < 4; ++i)
#pragma unroll
            for (int j = 0; j < 4; ++j)
                acc[i][j] = __builtin_amdgcn_mfma_f32_16x16x32_bf16(af[i], bfr[j], acc[i][j], 0, 0, 0);
        if (ks < 7) {
            unsigned short* la2 = smem + (b ? 0 : 2560);
            unsigned short* lb2 = smem + (b ? 5120 : 15360);
            stage_write(la2, lb2, ar, akg, cx0, cx1, cw);
            if (ks < 6) stage_load(XA, WB, (ks + 2) * 32, cx0, cx1, cw);
        }
        __syncthreads();
    }

    if (t < 64) rowx[t] = b2f(f2b(X[(size_t)(m0 + t) * 257 + 256]));
    __syncthreads();

    {
        float w256[4];
#pragma unroll
        for (int j = 0; j < 4; ++j)
            w256[j] = b2f(Wb[(size_t)(wn + j * 16 + l15) * 288 + 256]);
#pragma unroll
        for (int i = 0; i < 4; ++i)
#pragma unroll
            for (int r = 0; r < 4; ++r) {
                const float xv = rowx[i * 16 + q * 4 + r];
#pragma unroll
                for (int j = 0; j < 4; ++j)
                    acc[i][j][r] += xv * w256[j];
            }
    }

    if (mode == 2) {
#pragma unroll
        for (int j = 0; j < 4; ++j) {
            const int cg = wn + j * 16 + l15;
#pragma unroll
            for (int i = 0; i < 4; ++i)
#pragma unroll
                for (int r = 0; r < 4; ++r) {
                    const int n = m0 + i * 16 + q * 4 + r;
                    xOut[(size_t)n * 257 + 1 + cg] = acc[i][j][r];
                }
        }
        return;
    }

    if (mode == 1) {
#pragma unroll
        for (int j = 0; j < 4; ++j) {
            const float bias = bb[wn + j * 16 + l15];
#pragma unroll
            for (int i = 0; i < 4; ++i)
#pragma unroll
                for (int r = 0; r < 4; ++r)
                    acc[i][j][r] += bias;
        }
        __syncthreads();
#pragma unroll
        for (int i = 0; i < 4; ++i)
#pragma unroll
            for (int j = 0; j < 4; ++j) {
                const int cl = wn + j * 16 + l15;
#pragma unroll
                for (int r2 = 0; r2 < 4; r2 += 2) {
                    const int nl = i * 16 + q * 4 + r2;
                    const unsigned int pk =
                        (unsigned int)f2b(acc[i][j][r2]) |
                        ((unsigned int)f2b(acc[i][j][r2 + 1]) << 16);
                    *(unsigned int*)(&smem[cl * 64 + (((nl >> 3) ^ (cl & 7)) << 3) + (nl & 7)]) = pk;
                }
            }
        __syncthreads();
#pragma unroll
        for (int k = 0; k < 8; ++k) {
            const int task = k * 256 + t;
            const int cl = task >> 3, nq = task & 7;
            *(u16x8*)(vsOut + (size_t)blockIdx.x * STRIPE +
                      (size_t)(hcol + cl) * 64 + nq * 8) =
                *(const u16x8*)(&smem[cl * 64 + ((nq ^ (cl & 7)) << 3)]);
        }
        return;
    }

    // K-phi
    const float c = fabsf(nsc[0]) + EPSF;
    float bias[4];
#pragma unroll
    for (int j = 0; j < 4; ++j) bias[j] = bb[wn + j * 16 + l15];

    float a2[4][4], a4[4][4];
#pragma unroll
    for (int i = 0; i < 4; ++i)
#pragma unroll
        for (int r = 0; r < 4; ++r) { a2[i][r] = 0.f; a4[i][r] = 0.f; }
#pragma unroll
    for (int i = 0; i < 4; ++i)
#pragma unroll
        for (int j = 0; j < 4; ++j)
#pragma unroll
            for (int r = 0; r < 4; ++r) {
                float uu = fmaxf(acc[i][j][r] + bias[j], 0.f) + EPSF;
                float q2 = uu * uu;
                acc[i][j][r] = q2;
                a2[i][r] += q2;
                a4[i][r] += q2 * q2;
            }
#pragma unroll
    for (int m = 1; m <= 8; m <<= 1) {
#pragma unroll
        for (int i = 0; i < 4; ++i)
#pragma unroll
            for (int r = 0; r < 4; ++r) {
                a2[i][r] += __shfl_xor(a2[i][r], m, 64);
                a4[i][r] += __shfl_xor(a4[i][r], m, 64);
            }
    }
    __syncthreads();
    if (l15 == 0) {
#pragma unroll
        for (int i = 0; i < 4; ++i)
#pragma unroll
            for (int r = 0; r < 4; ++r) {
                reds2[w * 64 + i * 16 + q * 4 + r] = a2[i][r];
                reds4[w * 64 + i * 16 + q * 4 + r] = a4[i][r];
            }
    }
    __syncthreads();
    if (t < 64) {
        float s2t = reds2[t] + reds2[64 + t] + reds2[128 + t] + reds2[192 + t];
        float s4t = reds4[t] + reds4[64 + t] + reds4[128 + t] + reds4[192 + t];
        rowv[t] = sqrtf(s2t) / (c * sqrtf(s4t));
    }
    __syncthreads();
    float sc_[4][4];
#pragma unroll
    for (int i = 0; i < 4; ++i)
#pragma unroll
        for (int r = 0; r < 4; ++r) sc_[i][r] = rowv[i * 16 + q * 4 + r];

    float colp[4];
#pragma unroll
    for (int j = 0; j < 4; ++j) colp[j] = 0.f;
#pragma unroll
    for (int i = 0; i < 4; ++i)
#pragma unroll
        for (int j = 0; j < 4; ++j)
#pragma unroll
            for (int r = 0; r < 4; ++r) {
                float ph = acc[i][j][r] * sc_[i][r];
                acc[i][j][r] = ph;
                colp[j] += ph;
            }
#pragma unroll
    for (int i = 0; i < 4; ++i)
#pragma unroll
        for (int j = 0; j < 4; ++j) {
            const int cl = wn + j * 16 + l15;
#pragma unroll
            for (int r2 = 0; r2 < 4; r2 += 2) {
                const int nl = i * 16 + q * 4 + r2;
                const unsigned int pk =
                    (unsigned int)f2b(acc[i][j][r2]) |
                    ((unsigned int)f2b(acc[i][j][r2 + 1]) << 16);
                *(unsigned int*)(&smem[cl * 64 + (((nl >> 3) ^ (cl & 7)) << 3) + (nl & 7)]) = pk;
            }
        }
    __syncthreads();
#pragma unroll
    for (int k = 0; k < 8; ++k) {
        const int task = k * 256 + t;
        const int cl = task >> 3, nq = task & 7;
        *(u16x8*)(phiOut + (size_t)blockIdx.x * STRIPE +
                  (size_t)(hcol + cl) * 64 + nq * 8) =
            *(const u16x8*)(&smem[cl * 64 + ((nq ^ (cl & 7)) << 3)]);
    }
#pragma unroll
    for (int j = 0; j < 4; ++j) {
        colp[j] += __shfl_xor(colp[j], 16, 64);
        colp[j] += __shfl_xor(colp[j], 32, 64);
    }
    if (q == 0) {
        float* dst = colrep + (size_t)(blockIdx.x & 7) * 2048;
#pragma unroll
        for (int j = 0; j < 4; ++j)
            atomicAdd(&dst[hcol + wn + j * 16 + l15], colp[j]);
    }
}

// ---------------- pass-B Q projection (DBUF, 1 barrier/K-step) ----------------
// phi * invden, coalesced row-major store via padded LDS transpose.
__global__ __launch_bounds__(256, 3) void proj_q(
    const float* __restrict__ X,
    const unsigned short* __restrict__ Wbf,
    const float* __restrict__ biasAll,
    unsigned short* __restrict__ outbuf,
    const float* __restrict__ nsc,
    const float* __restrict__ colsum_in,
    int CH)
{
    __shared__ __align__(16) unsigned short smem[25600];
    float* reds2 = (float*)(smem + 16896);
    float* reds4 = reds2 + 256;
    float* rowv  = reds4 + 256;
    float* rowx  = rowv + 64;

    const int t = threadIdx.x;
    const int m0 = blockIdx.x * 64;
    const int h  = blockIdx.y;
    const int lane = t & 63, w = t >> 6;
    const int wn = w * 64;
    const int l15 = lane & 15, q = lane >> 4;
    const int ar = t >> 2, akg = (t & 3) * 8;
    const int hcol = h * 256;

    const unsigned short* Wb = Wbf + (size_t)hcol * 288;
    const float* bb = biasAll + hcol;

    f32x4 acc[4][4] = {};
    const float* XA = X + (size_t)(m0 + ar) * 257 + akg;
    const unsigned short* WB = Wb + (size_t)ar * 288 + akg;

    f32x4a cx0, cx1;
    u16x8 cw[4];

    stage_load(XA, WB, 0, cx0, cx1, cw);
    stage_write(smem, smem + 5120, ar, akg, cx0, cx1, cw);
    stage_load(XA, WB, 32, cx0, cx1, cw);
    __syncthreads();

#pragma unroll
    for (int ks = 0; ks < 8; ++ks) {
        const int b = ks & 1;
        unsigned short* la = smem + (b ? 2560 : 0);
        unsigned short* lb = smem + (b ? 15360 : 5120);
        bf16x8 af[4], bfr[4];
#pragma unroll
        for (int i = 0; i < 4; ++i)
            af[i] = *(const bf16x8*)(&la[(i * 16 + l15) * 40 + q * 8]);
#pragma unroll
        for (int j = 0; j < 4; ++j)
            bfr[j] = *(const bf16x8*)(&lb[(wn + j * 16 + l15) * 40 + q * 8]);
#pragma unroll
        for (int i = 0; i < 4; ++i)
#pragma unroll
            for (int j = 0; j < 4; ++j)
                acc[i][j] = __builtin_amdgcn_mfma_f32_16x16x32_bf16(af[i], bfr[j], acc[i][j], 0, 0, 0);
        if (ks < 7) {
            unsigned short* la2 = smem + (b ? 0 : 2560);
            unsigned short* lb2 = smem + (b ? 5120 : 15360);
            stage_write(la2, lb2, ar, akg, cx0, cx1, cw);
            if (ks < 6) stage_load(XA, WB, (ks + 2) * 32, cx0, cx1, cw);
        }
        __syncthreads();
    }

    if (t < 64) rowx[t] = b2f(f2b(X[(size_t)(m0 + t) * 257 + 256]));
    __syncthreads();

    {
        float w256[4];
#pragma unroll
        for (int j = 0; j < 4; ++j)
            w256[j] = b2f(Wb[(size_t)(wn + j * 16 + l15) * 288 + 256]);
#pragma unroll
        for (int i = 0; i < 4; ++i)
#pragma unroll
            for (int r = 0; r < 4; ++r) {
                const float xv = rowx[i * 16 + q * 4 + r];
#pragma unroll
                for (int j = 0; j < 4; ++j)
                    acc[i][j][r] += xv * w256[j];
            }
    }

    const float c = fabsf(nsc[0]) + EPSF;
    float bias[4];
#pragma unroll
    for (int j = 0; j < 4; ++j) bias[j] = bb[wn + j * 16 + l15];

    float a2[4][4], a4[4][4];
#pragma unroll
    for (int i = 0; i < 4; ++i)
#pragma unroll
        for (int r = 0; r < 4; ++r) { a2[i][r] = 0.f; a4[i][r] = 0.f; }
#pragma unroll
    for (int i = 0; i < 4; ++i)
#pragma unroll
        for (int j = 0; j < 4; ++j)
#pragma unroll
            for (int r = 0; r < 4; ++r) {
                float uu = fmaxf(acc[i][j][r] + bias[j], 0.f) + EPSF;
                float q2 = uu * uu;
                acc[i][j][r] = q2;
                a2[i][r] += q2;
                a4[i][r] += q2 * q2;
            }
#pragma unroll
    for (int m = 1; m <= 8; m <<= 1) {
#pragma unroll
        for (int i = 0; i < 4; ++i)
#pragma unroll
            for (int r = 0; r < 4; ++r) {
                a2[i][r] += __shfl_xor(a2[i][r], m, 64);
                a4[i][r] += __shfl_xor(a4[i][r], m, 64);
            }
    }
    __syncthreads();
    if (l15 == 0) {
#pragma unroll
        for (int i = 0; i < 4; ++i)
#pragma unroll
            for (int r = 0; r < 4; ++r) {
                reds2[w * 64 + i * 16 + q * 4 + r] = a2[i][r];
                reds4[w * 64 + i * 16 + q * 4 + r] = a4[i][r];
            }
    }
    __syncthreads();
    if (t < 64) {
        float s2t = reds2[t] + reds2[64 + t] + reds2[128 + t] + reds2[192 + t];
        float s4t = reds4[t] + reds4[64 + t] + reds4[128 + t] + reds4[192 + t];
        rowv[t] = sqrtf(s2t) / (c * sqrtf(s4t));
    }
    __syncthreads();
    float sc_[4][4];
#pragma unroll
    for (int i = 0; i < 4; ++i)
#pragma unroll
        for (int r = 0; r < 4; ++r) sc_[i][r] = rowv[i * 16 + q * 4 + r];

    float cs[4];
#pragma unroll
    for (int j = 0; j < 4; ++j) cs[j] = colsum_in[hcol + wn + j * 16 + l15];
    float dp[4][4];
#pragma unroll
    for (int i = 0; i < 4; ++i)
#pragma unroll
        for (int r = 0; r < 4; ++r) dp[i][r] = 0.f;
#pragma unroll
    for (int i = 0; i < 4; ++i)
#pragma unroll
        for (int j = 0; j < 4; ++j)
#pragma unroll
            for (int r = 0; r < 4; ++r) {
                float ph = acc[i][j][r] * sc_[i][r];
                acc[i][j][r] = ph;
                dp[i][r] += ph * cs[j];
            }
#pragma unroll
    for (int m = 1; m <= 8; m <<= 1) {
#pragma unroll
        for (int i = 0; i < 4; ++i)
#pragma unroll
            for (int r = 0; r < 4; ++r)
                dp[i][r] += __shfl_xor(dp[i][r], m, 64);
    }
    if (l15 == 0) {
#pragma unroll
        for (int i = 0; i < 4; ++i)
#pragma unroll
            for (int r = 0; r < 4; ++r)
                reds2[w * 64 + i * 16 + q * 4 + r] = dp[i][r];
    }
    __syncthreads();
    if (t < 64) {
        float dt = reds2[t] + reds2[64 + t] + reds2[128 + t] + reds2[192 + t];
        rowv[t] = 1.f / (dt + EPSF);
    }
    __syncthreads();
#pragma unroll
    for (int i = 0; i < 4; ++i)
#pragma unroll
        for (int r = 0; r < 4; ++r) sc_[i][r] = rowv[i * 16 + q * 4 + r];
    // coalesced row-major store via padded LDS transpose [64][264]
#pragma unroll
    for (int i = 0; i < 4; ++i)
#pragma unroll
        for (int j = 0; j < 4; ++j) {
            const int cl = wn + j * 16 + l15;
#pragma unroll
            for (int r = 0; r < 4; ++r) {
                const int nl = i * 16 + q * 4 + r;
                smem[nl * 264 + cl] = f2b(acc[i][j][r] * sc_[i][r]);
            }
        }
    __syncthreads();
#pragma unroll
    for (int k = 0; k < 8; ++k) {
        const int task = k * 256 + t;
        const int rowl = task >> 5, ck = (task & 31) * 8;
        *(u16x8*)(outbuf + (size_t)(m0 + rowl) * 2048 + hcol + ck) =
            *(const u16x8*)(&smem[rowl * 264 + ck]);
    }
}

// ---------------- merge colsum replicas ----------------
__global__ __launch_bounds__(256) void merge_colsum(
    const float* __restrict__ rep, float* __restrict__ out)
{
    const int cidx = blockIdx.x * 256 + threadIdx.x;
    float s = 0.f;
#pragma unroll
    for (int r = 0; r < 8; ++r) s += rep[(size_t)r * 2048 + cidx];
    out[cidx] = s;
}

// ---------------- ktv MFMA: tiled reads, prefetched ----------------
__global__ __launch_bounds__(256) void ktv_mfma(
    const unsigned short* __restrict__ phiT,   // tiled [CH/64][2048][64]
    const unsigned short* __restrict__ vsT,
    float* __restrict__ ktv, int CH)
{
    __shared__ __align__(16) unsigned short lAT[128 * 64];
    __shared__ __align__(16) unsigned short lBT[128 * 64];
    const int t = threadIdx.x;
    const int h = blockIdx.y;
    const int split = blockIdx.x >> 2;
    const int tile = blockIdx.x & 3;
    const int m0 = (tile >> 1) * 128, d0 = (tile & 1) * 128;
    const int chh = h * 256;
    const int lane = t & 63, w = t >> 6;
    const int wm = (w >> 1) * 64, wn = (w & 1) * 64;
    const int l15 = lane & 15, q = lane >> 4;
    const int sl7 = l15 & 7;

    const int scg  = t >> 3;
    const int snq  = t & 7;
    const int sbase = scg * 64 + ((snq ^ (scg & 7)) << 3);

    f32x4 acc[4][4] = {};
    const int st0 = split * 8;

    const unsigned short* pA = phiT + (size_t)(chh + m0 + scg) * 64 + snq * 8;
    const unsigned short* pB = vsT  + (size_t)(chh + d0 + scg) * 64 + snq * 8;

    u16x8 cA[4], cB[4], nA[4], nB[4];
#pragma unroll
    for (int k = 0; k < 4; ++k) {
        cA[k] = *(const u16x8*)(pA + (size_t)st0 * STRIPE + k * 2048);
        cB[k] = *(const u16x8*)(pB + (size_t)st0 * STRIPE + k * 2048);
    }

    for (int it = 0; it < 8; ++it) {
#pragma unroll
        for (int k = 0; k < 4; ++k) {
            *(u16x8*)(&lAT[k * 2048 + sbase]) = cA[k];
            *(u16x8*)(&lBT[k * 2048 + sbase]) = cB[k];
        }
        if (it < 7) {
            const size_t so = (size_t)(st0 + it + 1) * STRIPE;
#pragma unroll
            for (int k = 0; k < 4; ++k) {
                nA[k] = *(const u16x8*)(pA + so + k * 2048);
                nB[k] = *(const u16x8*)(pB + so + k * 2048);
            }
        }
        __syncthreads();
#pragma unroll
        for (int sub = 0; sub < 2; ++sub) {
            const int slot = ((sub * 4 + q) ^ sl7) << 3;
            bf16x8 af[4], bfr[4];
#pragma unroll
            for (int i = 0; i < 4; ++i)
                af[i] = *(const bf16x8*)(&lAT[(wm + i * 16 + l15) * 64 + slot]);
#pragma unroll
            for (int j = 0; j < 4; ++j)
                bfr[j] = *(const bf16x8*)(&lBT[(wn + j * 16 + l15) * 64 + slot]);
#pragma unroll
            for (int i = 0; i < 4; ++i)
#pragma unroll
                for (int j = 0; j < 4; ++j)
                    acc[i][j] = __builtin_amdgcn_mfma_f32_16x16x32_bf16(af[i], bfr[j], acc[i][j], 0, 0, 0);
        }
        __syncthreads();
        if (it < 7) {
#pragma unroll
            for (int k = 0; k < 4; ++k) { cA[k] = nA[k]; cB[k] = nB[k]; }
        }
    }
#pragma unroll
    for (int i = 0; i < 4; ++i)
#pragma unroll
        for (int j = 0; j < 4; ++j)
#pragma unroll
            for (int r = 0; r < 4; ++r) {
                const int m = m0 + wm + i * 16 + q * 4 + r;
                const int d = d0 + wn + j * 16 + l15;
                atomicAdd(&ktv[((size_t)chh + m) * 256 + d], acc[i][j][r]);
            }
}

// ---------------- final staging load ----------------
__device__ __forceinline__ void fin_load(
    const unsigned short* __restrict__ Abuf, const unsigned short* __restrict__ W2T,
    int n0, int d0, int t, int k0,
    u16x8& A0, u16x8& A1, u16x8& B)
{
    {
        const int row = t >> 2, kg = (t & 3) * 8;
        A0 = *(const u16x8*)(Abuf + (size_t)(n0 + row) * 2048 + ((k0 + kg) & 2047));
    }
    {
        const int e = t + 256;
        const int row = e >> 2, kg = (e & 3) * 8;
        A1 = *(const u16x8*)(Abuf + (size_t)(n0 + row) * 2048 + ((k0 + kg) & 2047));
    }
    {
        const int row = t >> 2, kg = (t & 3) * 8;
        B = *(const u16x8*)(W2T + (size_t)(d0 + row) * 4096 + k0 + kg);
    }
}

// ---------------- final MFMA GEMM 128x64 (DBUF 1-barrier, split-K x2, atomic) ----------------
__global__ __launch_bounds__(256) void final_mfma(
    const unsigned short* __restrict__ Abuf,
    const unsigned short* __restrict__ W2T,
    int kbeg, int kend,
    float* __restrict__ outp)
{
    // lA0 @0 (5120 u16), lA1 @5120, lB0 @10240 (2560), lB1 @12800 -> 15360 u16
    __shared__ __align__(16) unsigned short smem[15360];
    const int t = threadIdx.x;
    const int n0 = blockIdx.x * 128;
    const int d0 = blockIdx.y * 64;
    const int khalf = (kend - kbeg) >> 1;
    const int kb = kbeg + blockIdx.z * khalf;
    const int nst = khalf >> 5;
    const int lane = t & 63, w = t >> 6;
    const int wm = w * 32;
    const int l15 = lane & 15, q = lane >> 4;
    const int row = t >> 2, kg = (t & 3) * 8;
    const int row2 = (t + 256) >> 2;

    f32x4 acc[2][4] = {};
    u16x8 cA0, cA1, cB;
    fin_load(Abuf, W2T, n0, d0, t, kb, cA0, cA1, cB);
    *(u16x8*)(&smem[row * 40 + kg])  = cA0;
    *(u16x8*)(&smem[row2 * 40 + kg]) = cA1;
    *(u16x8*)(&smem[10240 + row * 40 + kg]) = cB;
    if (nst > 1) fin_load(Abuf, W2T, n0, d0, t, kb + 32, cA0, cA1, cB);
    __syncthreads();

    for (int s = 0; s < nst; ++s) {
        const int b = s & 1;
        unsigned short* la = smem + (b ? 5120 : 0);
        unsigned short* lb = smem + 10240 + (b ? 2560 : 0);
        bf16x8 af[2], bfr[4];
#pragma unroll
        for (int i = 0; i < 2; ++i)
            af[i] = *(const bf16x8*)(&la[(wm + i * 16 + l15) * 40 + q * 8]);
#pragma unroll
        for (int j = 0; j < 4; ++j)
            bfr[j] = *(const bf16x8*)(&lb[(j * 16 + l15) * 40 + q * 8]);
#pragma unroll
        for (int i = 0; i < 2; ++i)
#pragma unroll
            for (int j = 0; j < 4; ++j)
                acc[i][j] = __builtin_amdgcn_mfma_f32_16x16x32_bf16(af[i], bfr[j], acc[i][j], 0, 0, 0);
        if (s + 1 < nst) {
            unsigned short* la2 = smem + (b ? 0 : 5120);
            unsigned short* lb2 = smem + 10240 + (b ? 0 : 2560);
            *(u16x8*)(&la2[row * 40 + kg])  = cA0;
            *(u16x8*)(&la2[row2 * 40 + kg]) = cA1;
            *(u16x8*)(&lb2[row * 40 + kg])  = cB;
            if (s + 2 < nst)
                fin_load(Abuf, W2T, n0, d0, t, kb + (s + 2) * 32, cA0, cA1, cB);
        }
        __syncthreads();
    }
#pragma unroll
    for (int i = 0; i < 2; ++i)
#pragma unroll
        for (int j = 0; j < 4; ++j)
#pragma unroll
            for (int r = 0; r < 4; ++r) {
                const int n = n0 + wm + i * 16 + q * 4 + r;
                const int d = d0 + j * 16 + l15;
                atomicAdd(&outp[(size_t)n * 257 + 1 + d], acc[i][j][r]);
            }
}

// ---------------- W2T upper = ktv_h @ F_h^T (bf16) ----------------
__global__ __launch_bounds__(256) void w2u_kernel(
    const float* __restrict__ ktv,
    const float* __restrict__ fw,
    unsigned short* __restrict__ W2T)
{
    const int t = threadIdx.x;
    const int h = blockIdx.x >> 3;
    const int m0 = (blockIdx.x & 7) * 32;

    __shared__ __align__(16) float xlds[16][40];
    __shared__ float wlds[256][17];

    float acc[32];
#pragma unroll
    for (int r = 0; r < 32; ++r) acc[r] = 0.f;

    const int ar = t >> 3;
    const int ak = (t & 7) * 2;
    const int wk = t & 15;
    const int wo = (t >> 4) * 16;

    for (int d0 = 0; d0 < 256; d0 += 16) {
        {
            const float* src = ktv + (size_t)(h * 256 + m0 + ar) * 256 + d0 + ak;
            xlds[ak][ar]     = src[0];
            xlds[ak + 1][ar] = src[1];
        }
#pragma unroll
        for (int j = 0; j < 16; ++j)
            wlds[wo + j][wk] = fw[(size_t)(wo + j) * 2048 + h * 256 + d0 + wk];
        __syncthreads();
#pragma unroll
        for (int kk = 0; kk < 16; ++kk) {
            float bv = wlds[t][kk];
            const float4* xr = (const float4*)(&xlds[kk][0]);
#pragma unroll
            for (int g = 0; g < 8; ++g) {
                float4 xv = xr[g];
                acc[g * 4 + 0] = fmaf(xv.x, bv, acc[g * 4 + 0]);
                acc[g * 4 + 1] = fmaf(xv.y, bv, acc[g * 4 + 1]);
                acc[g * 4 + 2] = fmaf(xv.z, bv, acc[g * 4 + 2]);
                acc[g * 4 + 3] = fmaf(xv.w, bv, acc[g * 4 + 3]);
            }
        }
        __syncthreads();
    }
#pragma unroll
    for (int r = 0; r < 32; ++r)
        W2T[(size_t)t * 4096 + h * 256 + m0 + r] = f2b(acc[r]);
}

// ---------------- epilogue: bias + Lorentz lift ----------------
__global__ __launch_bounds__(256) void lift_kernel(
    const float* __restrict__ bias2, float* __restrict__ outp)
{
    const int t = threadIdx.x;
    const int lane = t & 63;
    const int w = t >> 6;
    const int n0 = blockIdx.x * 64 + w * 16;
    float b[4];
#pragma unroll
    for (int j = 0; j < 4; ++j) b[j] = bias2[lane + j * 64];
    for (int r = 0; r < 16; ++r) {
        float* row = outp + (size_t)(n0 + r) * 257;
        float v[4];
        float s = 0.f;
#pragma unroll
        for (int j = 0; j < 4; ++j) {
            v[j] = row[1 + lane + j * 64] + b[j];
            s = fmaf(v[j], v[j], s);
        }
#pragma unroll
        for (int off = 32; off > 0; off >>= 1) s += __shfl_down(s, off, 64);
#pragma unroll
        for (int j = 0; j < 4; ++j) row[1 + lane + j * 64] = v[j];
        if (lane == 0) row[0] = sqrtf(s + 1.0f);
    }
}

extern "C" void kernel_launch(void* const* d_in, const int* in_sizes, int n_in,
                              void* d_out, int out_size, void* d_ws, size_t ws_size,
                              hipStream_t stream)
{
    const float* xq  = (const float*)d_in[0];
    const float* xs  = (const float*)d_in[1];
    const float* Wq  = (const float*)d_in[2];
    const float* Bq  = (const float*)d_in[3];
    const float* Wk  = (const float*)d_in[4];
    const float* Bk  = (const float*)d_in[5];
    const float* Wv  = (const float*)d_in[6];
    const float* Bv  = (const float*)d_in[7];
    const float* nsc = (const float*)d_in[8];
    const float* vmw = (const float*)d_in[9];
    const float* vmb = (const float*)d_in[10];
    const float* fw  = (const float*)d_in[11];
    const float* fb  = (const float*)d_in[12];
    float* outp = (float*)d_out;

    char* ws = (char*)d_ws;
    float* ktv          = (float*)(ws + 0);                 // 2,097,152
    float* colrep       = (float*)(ws + 2097152);           //    65,536
    float* Mf32         = (float*)(ws + 2162688);           //   294,912
    float* colsum       = (float*)(ws + 2457600);           //     8,192
    float* bias2        = (float*)(ws + 2465792);           //     1,024
    float* biasAll      = (float*)(ws + 2466816);           //    24,576
    unsigned short* W2T = (unsigned short*)(ws + 2491392);  // 2,097,152
    unsigned short* Wbf = (unsigned short*)(ws + 4588544);  // 3,538,944
    float* G32          = (float*)(ws + 8127488);           // 2,097,152
    unsigned short* Mbf = (unsigned short*)(ws + 10224640); //   147,456
    const size_t fixedBytes = 10372096;

    int CH = 2048;
    if      (ws_size >= fixedBytes + (size_t)8192 * 8192)  CH = 8192;
    else if (ws_size >= fixedBytes + (size_t)4096 * 8192)  CH = 4096;
    const int NCHK = 32768 / CH;
    unsigned short* phibuf = (unsigned short*)(ws + fixedBytes);
    unsigned short* vsT    = (unsigned short*)(ws + fixedBytes + (size_t)CH * 4096);

    // zero ktv + colrep + Mf32 (contiguous 614400 floats)
    zero_kernel<<<dim3(2400), 256, 0, stream>>>(ktv, 614400);
    wconv_kernel<<<dim3(6168), 256, 0, stream>>>(Wq, Wk, Wv, Bq, Bk, Bv, Wbf, biasAll);
    w2g_kernel<<<dim3(64), 256, 0, stream>>>(vmw, fw, G32);
    bias2_kernel<<<dim3(256), 256, 0, stream>>>(vmb, fw, fb, Bv, G32, bias2);
    gm_kernel<<<dim3(4, 9, 8), 256, 0, stream>>>(Wv, G32, Mf32);
    gmcvt_kernel<<<dim3(288), 256, 0, stream>>>(Mf32, Mbf);

    // Pass A: merged K-phi / V / xm (dbuf) in ONE dispatch per chunk, then ktv
    for (int c = 0; c < NCHK; ++c) {
        const float* xs_c = xs + (size_t)c * CH * 257;
        float* out_c = outp + (size_t)c * CH * 257;
        proj_all<<<dim3(CH / 64, 17), 256, 0, stream>>>(
            xs_c, Wbf, Mbf, biasAll, phibuf, vsT, out_c, nsc, colrep, CH);
        ktv_mfma<<<dim3((CH / 512) * 4, 8), 256, 0, stream>>>(phibuf, vsT, ktv, CH);
    }

    // merge colsum replicas; ktv-dependent weights
    merge_colsum<<<dim3(8), 256, 0, stream>>>(colrep, colsum);
    w2u_kernel<<<dim3(64), 256, 0, stream>>>(ktv, fw, W2T);

    // Pass B: Q-phi (dbuf) + final (dbuf, split-K x2)
    for (int c = 0; c < NCHK; ++c) {
        const float* xq_c = xq + (size_t)c * CH * 257;
        float* out_c = outp + (size_t)c * CH * 257;
        proj_q<<<dim3(CH / 64, 8), 256, 0, stream>>>(
            xq_c, Wbf, biasAll, phibuf, nsc, colsum, CH);
        final_mfma<<<dim3(CH / 128, 4, 2), 256, 0, stream>>>(phibuf, W2T, 0, 2048, out_c);
    }

    // bias + Lorentz lift
    lift_kernel<<<dim3(512), 256, 0, stream>>>(bias2, outp);
}